// Round 11
// baseline (11364.037 us; speedup 1.0000x reference)
//
#include <hip/hip_runtime.h>
#include <math.h>

#define TWOPI_F 6.283185307179586f
#define LD4(p) (*(const float4*)(p))

__device__ __forceinline__ float gelu_f(float v) {
    float u = 0.7978845608028654f * (v + 0.044715f * v * v * v);
    return 0.5f * v * (1.f + tanhf(u));
}

// ---------------- twiddle tables ----------------
__global__ void init_tables_kernel(float* __restrict__ Wy, float* __restrict__ TWX,
                                   float* __restrict__ WY2) {
    int t = threadIdx.x;
    for (int i = t; i < 1024; i += 256) {
        int y = i >> 4, k = i & 15;
        int m = (k * y) & 63;
        float a = -TWOPI_F * (float)m / 64.f;
        Wy[y * 32 + 2 * k]     = cosf(a);
        Wy[y * 32 + 2 * k + 1] = sinf(a);
    }
    for (int i = t; i < 2048; i += 256) {
        int x = i >> 5, kxm = i & 31;
        int kx = kxm < 16 ? kxm : kxm + 32;
        int m = (kx * x) & 63;
        float a = -TWOPI_F * (float)m / 64.f;
        TWX[x * 64 + 2 * kxm]     = cosf(a);
        TWX[x * 64 + 2 * kxm + 1] = sinf(a);
    }
    for (int i = t; i < 1024; i += 256) {
        int y = i >> 4, k = i & 15;
        int m = (k * y) & 63;
        float a = TWOPI_F * (float)m / 64.f;
        float sc = (k == 0 ? 1.f : 2.f) / 4096.f;
        WY2[y * 32 + 2 * k]     = sc * cosf(a);
        WY2[y * 32 + 2 * k + 1] = sc * sinf(a);
    }
}

// ---------------- router v3: weight-reuse layout (col-group x row-group) ----------------
__global__ __launch_bounds__(512) void router_kernel(
    const float* __restrict__ x, const float* __restrict__ enc_w, const float* __restrict__ enc_b,
    const float* __restrict__ wqkv, const float* __restrict__ bqkv,
    const float* __restrict__ wo, const float* __restrict__ bo,
    const float* __restrict__ ln1g, const float* __restrict__ ln1b,
    const float* __restrict__ w1, const float* __restrict__ b1,
    const float* __restrict__ w2, const float* __restrict__ b2,
    const float* __restrict__ ln2g, const float* __restrict__ ln2b,
    const float* __restrict__ fcw, const float* __restrict__ fcb,
    float* __restrict__ rw)
{
    __shared__ float s[64][65];
    __shared__ float qk[64][193];
    __shared__ float sc[64][65];
    __shared__ float o64[64][65];
    __shared__ float feat[64];
    __shared__ float logits[8];
    int b = blockIdx.x, t = threadIdx.x;

    for (int i = t; i < 4096; i += 512) {
        int w_ = i >> 6, d = i & 63;
        s[w_][d] = x[b * 4096 + w_] * enc_w[d] + enc_b[d];
    }
    __syncthreads();

    for (int l = 0; l < 2; ++l) {
        {
            const float* Wq = wqkv + l * 64 * 192;
            const float* Bq = bqkv + l * 192;
            int c4 = t % 48, rg = t / 48;
            if (rg < 8) {
                const float* wcol = Wq + 4 * c4;
                float4 bq = LD4(Bq + 4 * c4);
                float4 acc[8];
#pragma unroll
                for (int i = 0; i < 8; ++i) acc[i] = bq;
                int r0 = rg * 8;
#pragma unroll 8
                for (int k = 0; k < 64; ++k) {
                    float4 wv = LD4(wcol + k * 192);
#pragma unroll
                    for (int i = 0; i < 8; ++i) {
                        float sv = s[r0 + i][k];
                        acc[i].x += sv * wv.x; acc[i].y += sv * wv.y;
                        acc[i].z += sv * wv.z; acc[i].w += sv * wv.w;
                    }
                }
#pragma unroll
                for (int i = 0; i < 8; ++i) {
                    qk[r0 + i][4 * c4]     = acc[i].x;
                    qk[r0 + i][4 * c4 + 1] = acc[i].y;
                    qk[r0 + i][4 * c4 + 2] = acc[i].z;
                    qk[r0 + i][4 * c4 + 3] = acc[i].w;
                }
            }
        }
        __syncthreads();
        for (int h = 0; h < 4; ++h) {
            for (int i = t; i < 4096; i += 512) {
                int q = i >> 6, kj = i & 63;
                float acc = 0.f;
#pragma unroll
                for (int d = 0; d < 16; ++d)
                    acc += qk[q][h * 16 + d] * qk[kj][64 + h * 16 + d];
                sc[q][kj] = acc * 0.25f;
            }
            __syncthreads();
            if (t < 64) {
                float m = -1e30f;
                for (int j = 0; j < 64; ++j) m = fmaxf(m, sc[t][j]);
                float sum = 0.f;
                for (int j = 0; j < 64; ++j) { float e2 = expf(sc[t][j] - m); sc[t][j] = e2; sum += e2; }
                float inv = 1.f / sum;
                for (int j = 0; j < 64; ++j) sc[t][j] *= inv;
            }
            __syncthreads();
            for (int i = t; i < 1024; i += 512) {
                int q = i >> 4, d = i & 15;
                float acc = 0.f;
#pragma unroll 8
                for (int j = 0; j < 64; ++j) acc += sc[q][j] * qk[j][128 + h * 16 + d];
                o64[q][h * 16 + d] = acc;
            }
            __syncthreads();
        }
        {
            const float* Wo = wo + l * 4096;
            const float* Bo = bo + l * 64;
            int c4 = t & 15, rg = t >> 4;
            const float* wcol = Wo + 4 * c4;
            float4 acc0 = LD4(Bo + 4 * c4), acc1 = acc0;
            int r0 = rg * 2;
#pragma unroll 8
            for (int k = 0; k < 64; ++k) {
                float4 wv = LD4(wcol + k * 64);
                float h0 = o64[r0][k], h1 = o64[r0 + 1][k];
                acc0.x += h0 * wv.x; acc0.y += h0 * wv.y;
                acc0.z += h0 * wv.z; acc0.w += h0 * wv.w;
                acc1.x += h1 * wv.x; acc1.y += h1 * wv.y;
                acc1.z += h1 * wv.z; acc1.w += h1 * wv.w;
            }
            sc[r0][4 * c4]     = s[r0][4 * c4]     + acc0.x;
            sc[r0][4 * c4 + 1] = s[r0][4 * c4 + 1] + acc0.y;
            sc[r0][4 * c4 + 2] = s[r0][4 * c4 + 2] + acc0.z;
            sc[r0][4 * c4 + 3] = s[r0][4 * c4 + 3] + acc0.w;
            sc[r0 + 1][4 * c4]     = s[r0 + 1][4 * c4]     + acc1.x;
            sc[r0 + 1][4 * c4 + 1] = s[r0 + 1][4 * c4 + 1] + acc1.y;
            sc[r0 + 1][4 * c4 + 2] = s[r0 + 1][4 * c4 + 2] + acc1.z;
            sc[r0 + 1][4 * c4 + 3] = s[r0 + 1][4 * c4 + 3] + acc1.w;
        }
        __syncthreads();
        if (t < 64) {
            float m = 0.f;
            for (int j = 0; j < 64; ++j) m += sc[t][j];
            m *= (1.f / 64.f);
            float v = 0.f;
            for (int j = 0; j < 64; ++j) { float d = sc[t][j] - m; v += d * d; }
            v *= (1.f / 64.f);
            float inv = rsqrtf(v + 1e-5f);
            for (int j = 0; j < 64; ++j)
                s[t][j] = (sc[t][j] - m) * inv * ln1g[l * 64 + j] + ln1b[l * 64 + j];
        }
        __syncthreads();
        {
            const float* W1 = w1 + l * 64 * 256;
            const float* B1 = b1 + l * 256;
            int c4 = t & 63, rg = t >> 6;
            const float* wcol = W1 + 4 * c4;
            float4 b1v = LD4(B1 + 4 * c4);
            float4 acc[8];
#pragma unroll
            for (int i = 0; i < 8; ++i) acc[i] = b1v;
            int r0 = rg * 8;
#pragma unroll 4
            for (int k = 0; k < 64; ++k) {
                float4 wv = LD4(wcol + k * 256);
#pragma unroll
                for (int i = 0; i < 8; ++i) {
                    float sv = s[r0 + i][k];
                    acc[i].x += sv * wv.x; acc[i].y += sv * wv.y;
                    acc[i].z += sv * wv.z; acc[i].w += sv * wv.w;
                }
            }
#pragma unroll
            for (int i = 0; i < 8; ++i) {
                float a0 = fmaxf(acc[i].x, 0.f), a1 = fmaxf(acc[i].y, 0.f);
                float a2 = fmaxf(acc[i].z, 0.f), a3 = fmaxf(acc[i].w, 0.f);
                if (c4 < 48) {
                    qk[r0 + i][4 * c4] = a0; qk[r0 + i][4 * c4 + 1] = a1;
                    qk[r0 + i][4 * c4 + 2] = a2; qk[r0 + i][4 * c4 + 3] = a3;
                } else {
                    int c = 4 * c4 - 192;
                    o64[r0 + i][c] = a0; o64[r0 + i][c + 1] = a1;
                    o64[r0 + i][c + 2] = a2; o64[r0 + i][c + 3] = a3;
                }
            }
        }
        __syncthreads();
        {
            const float* W2 = w2 + l * 256 * 64;
            const float* B2 = b2 + l * 64;
            int c4 = t & 15, rg = t >> 4;
            const float* wcol = W2 + 4 * c4;
            float4 acc0 = LD4(B2 + 4 * c4), acc1 = acc0;
            int r0 = rg * 2;
#pragma unroll 8
            for (int k = 0; k < 192; ++k) {
                float4 wv = LD4(wcol + k * 64);
                float h0 = qk[r0][k], h1 = qk[r0 + 1][k];
                acc0.x += h0 * wv.x; acc0.y += h0 * wv.y;
                acc0.z += h0 * wv.z; acc0.w += h0 * wv.w;
                acc1.x += h1 * wv.x; acc1.y += h1 * wv.y;
                acc1.z += h1 * wv.z; acc1.w += h1 * wv.w;
            }
#pragma unroll 8
            for (int k = 192; k < 256; ++k) {
                float4 wv = LD4(wcol + k * 64);
                float h0 = o64[r0][k - 192], h1 = o64[r0 + 1][k - 192];
                acc0.x += h0 * wv.x; acc0.y += h0 * wv.y;
                acc0.z += h0 * wv.z; acc0.w += h0 * wv.w;
                acc1.x += h1 * wv.x; acc1.y += h1 * wv.y;
                acc1.z += h1 * wv.z; acc1.w += h1 * wv.w;
            }
            sc[r0][4 * c4]     = s[r0][4 * c4]     + acc0.x;
            sc[r0][4 * c4 + 1] = s[r0][4 * c4 + 1] + acc0.y;
            sc[r0][4 * c4 + 2] = s[r0][4 * c4 + 2] + acc0.z;
            sc[r0][4 * c4 + 3] = s[r0][4 * c4 + 3] + acc0.w;
            sc[r0 + 1][4 * c4]     = s[r0 + 1][4 * c4]     + acc1.x;
            sc[r0 + 1][4 * c4 + 1] = s[r0 + 1][4 * c4 + 1] + acc1.y;
            sc[r0 + 1][4 * c4 + 2] = s[r0 + 1][4 * c4 + 2] + acc1.z;
            sc[r0 + 1][4 * c4 + 3] = s[r0 + 1][4 * c4 + 3] + acc1.w;
        }
        __syncthreads();
        if (t < 64) {
            float m = 0.f;
            for (int j = 0; j < 64; ++j) m += sc[t][j];
            m *= (1.f / 64.f);
            float v = 0.f;
            for (int j = 0; j < 64; ++j) { float d = sc[t][j] - m; v += d * d; }
            v *= (1.f / 64.f);
            float inv = rsqrtf(v + 1e-5f);
            for (int j = 0; j < 64; ++j)
                s[t][j] = (sc[t][j] - m) * inv * ln2g[l * 64 + j] + ln2b[l * 64 + j];
        }
        __syncthreads();
    }
    if (t < 64) {
        float m = -1e30f;
        for (int r = 0; r < 64; ++r) m = fmaxf(m, s[r][t]);
        feat[t] = m;
    }
    __syncthreads();
    if (t < 8) {
        float acc = fcb[t];
        for (int k = 0; k < 64; ++k) acc += feat[k] * fcw[k * 8 + t];
        logits[t] = acc;
    }
    __syncthreads();
    if (t == 0) {
        int i0 = 0;
        for (int j = 1; j < 8; ++j) if (logits[j] > logits[i0]) i0 = j;
        int i1 = -1;
        for (int j = 0; j < 8; ++j) {
            if (j == i0) continue;
            if (i1 < 0 || logits[j] > logits[i1]) i1 = j;
        }
        float e1 = expf(logits[i1] - logits[i0]);
        float w0 = 1.f / (1.f + e1);
        float w1v = e1 / (1.f + e1);
        for (int j = 0; j < 8; ++j) rw[b * 8 + j] = 0.f;
        rw[b * 8 + i0] = w0;
        rw[b * 8 + i1] = w1v;
    }
}

// ---------------- build compact (b,e) pair list grouped by expert ----------------
__global__ void build_pairs_kernel(const float* __restrict__ rw, int* __restrict__ pair_b,
                                   int* __restrict__ pair_e, float* __restrict__ pair_w,
                                   int* __restrict__ estart) {
    __shared__ float r[256];
    __shared__ int cnt[8], off[9];
    int t = threadIdx.x;
    for (int i = t; i < 256; i += 64) r[i] = rw[i];
    if (t < 64) { pair_b[t] = 0; pair_e[t] = 0; pair_w[t] = 0.f; }
    __syncthreads();
    if (t < 8) {
        int c = 0;
        for (int b = 0; b < 32; ++b) if (r[b * 8 + t] != 0.f) ++c;
        cnt[t] = c;
    }
    __syncthreads();
    if (t == 0) {
        int a = 0;
        for (int e = 0; e < 8; ++e) { off[e] = a; a += cnt[e]; }
        off[8] = a;
        for (int e = 0; e <= 8; ++e) estart[e] = off[e];
    }
    __syncthreads();
    if (t < 8) {
        int n = off[t];
        for (int b = 0; b < 32; ++b) {
            float w = r[b * 8 + t];
            if (w != 0.f) { pair_b[n] = b; pair_e[n] = t; pair_w[n] = w; ++n; }
        }
    }
}

// ---------------- lift ----------------
__global__ __launch_bounds__(256) void lift_kernel(const float* __restrict__ x,
    const float* __restrict__ lw, const float* __restrict__ lb,
    const int* __restrict__ pair_b, const int* __restrict__ pair_e, float* __restrict__ hA) {
    int p = blockIdx.x, tile = blockIdx.y, t = threadIdx.x;
    int b = pair_b[p], e = pair_e[p];
    float* h = hA + (size_t)p * 262144;
    const float* xb = x + (size_t)b * 4096;
    for (int i = tile * 16384 + t; i < (tile + 1) * 16384; i += 256) {
        int co = i >> 12, xy = i & 4095;
        h[i] = xb[xy] * lw[e * 64 + co] + lb[e * 64 + co];
    }
}

// ---------------- fused forward DFT (y then x), one block per (p,ci) ----------------
__global__ __launch_bounds__(256) void fwdft_kernel(const float* __restrict__ h,
    const float* __restrict__ Wy, const float* __restrict__ TWX, float* __restrict__ F) {
    __shared__ float ht[64][68];
    __shared__ float gt[64][36];
    __shared__ float wy[2048];
    __shared__ float twx[4096];
    int bid = blockIdx.x;
    int t = threadIdx.x;
    const float* src = h + (size_t)bid * 4096;
    for (int i = t; i < 1024; i += 256) {
        float4 v = *(const float4*)(src + i * 4);
        int x = (i * 4) >> 6, y = (i * 4) & 63;
        *(float4*)(&ht[x][y]) = v;
    }
    for (int i = t; i < 512; i += 256) *(float4*)(&wy[i * 4]) = *(const float4*)(Wy + i * 4);
    for (int i = t; i < 1024; i += 256) *(float4*)(&twx[i * 4]) = *(const float4*)(TWX + i * 4);
    __syncthreads();
    {
        int xx = t >> 2, kq = t & 3;
        float gr0 = 0.f, gi0 = 0.f, gr1 = 0.f, gi1 = 0.f;
        float gr2 = 0.f, gi2 = 0.f, gr3 = 0.f, gi3 = 0.f;
#pragma unroll 4
        for (int y = 0; y < 64; ++y) {
            float hv = ht[xx][y];
            float4 w0 = *(const float4*)(&wy[y * 32 + kq * 8]);
            float4 w1 = *(const float4*)(&wy[y * 32 + kq * 8 + 4]);
            gr0 += hv * w0.x; gi0 += hv * w0.y;
            gr1 += hv * w0.z; gi1 += hv * w0.w;
            gr2 += hv * w1.x; gi2 += hv * w1.y;
            gr3 += hv * w1.z; gi3 += hv * w1.w;
        }
        *(float4*)(&gt[xx][kq * 8])     = make_float4(gr0, gi0, gr1, gi1);
        *(float4*)(&gt[xx][kq * 8 + 4]) = make_float4(gr2, gi2, gr3, gi3);
    }
    __syncthreads();
    {
        int kxm = t & 31, kyq = t >> 5;
        float ar0 = 0.f, ai0 = 0.f, ar1 = 0.f, ai1 = 0.f;
#pragma unroll 4
        for (int xx = 0; xx < 64; ++xx) {
            float2 tw = *(const float2*)(&twx[xx * 64 + 2 * kxm]);
            float4 g = *(const float4*)(&gt[xx][kyq * 4]);
            ar0 += g.x * tw.x - g.y * tw.y;  ai0 += g.x * tw.y + g.y * tw.x;
            ar1 += g.z * tw.x - g.w * tw.y;  ai1 += g.z * tw.y + g.w * tw.x;
        }
        float* fb = F + (size_t)bid * 1024 + kxm * 32 + kyq * 4;
        *(float4*)(fb) = make_float4(ar0, ai0, ar1, ai1);
    }
}

// ---------------- spectral multiply v9: ci-half split + LDS double-buffer ----------------
// grid (8 e, 2 co-halves, 64 z = wsel + 2*cih + 4*mq), block 256 = 32 co_l x 8 m4.
// Block covers 32 co x 32-float mode slice x 32 ci (cih half) -> partial into FoA/FoB.
// Per pc-chunk(8 pairs): 2 ci-chunks of 16 staged in LDS ping-pong buffers;
// chunk cc+1's 4 loads issued BEFORE computing chunk cc (latency hidden by VALU).
// acc[8] = 32 VGPR + stage regs 16; no launch_bounds min-waves (spill trap R6/R9).
__global__ __launch_bounds__(256) void spectral_kernel(
    const float* __restrict__ F, float* __restrict__ FoA, float* __restrict__ FoB,
    const float* __restrict__ w1, const float* __restrict__ w2,
    const int* __restrict__ estart, int l)
{
    __shared__ float fs[2][4096];   // ping-pong: [p 8][ci 16][8 f4][4]
    int e = blockIdx.x;
    int coh = blockIdx.y;
    int z = blockIdx.z;
    int wsel = z & 1, cih = (z >> 1) & 1, mq = z >> 2;   // mq in [0,16)
    int p0 = estart[e], ne = estart[e + 1] - p0;
    if (ne == 0) return;
    int t = threadIdx.x;
    int co_l = t >> 3, m4 = t & 7;
    int co_g = coh * 32 + co_l;
    int mo = mq * 32 + m4 * 4;

    // staging geometry: id = t + s*256 (s=0..3); p = id>>7, ci = (id>>3)&15, f4 = id&7
    int st_tp  = t >> 7;
    int st_ci  = (t >> 3) & 15;
    int st_f4  = t & 7;
    int st_lds = t * 4;

    const float* wbase = (wsel == 0 ? w1 : w2) + (size_t)(e * 4 + l) * 2097152;
    const float* Wc = wbase + (size_t)(cih * 32) * 32768 + (size_t)co_g * 512 + mo;
    float* Fob = (cih ? FoB : FoA) + (size_t)co_g * 1024 + wsel * 512 + mo;
    const float* Fbase = F + (size_t)(cih * 32 + st_ci) * 1024 + wsel * 512
                           + mq * 32 + st_f4 * 4;

    for (int pc = 0; pc < ne; pc += 8) {
        int np = ne - pc; if (np > 8) np = 8;
        const float* sp0; const float* sp1; const float* sp2; const float* sp3;
        {
            int g0 = p0 + pc + st_tp;
            int g1 = g0 + 2, g2 = g0 + 4, g3 = g0 + 6;
            g0 = g0 > 63 ? 63 : g0; g1 = g1 > 63 ? 63 : g1;
            g2 = g2 > 63 ? 63 : g2; g3 = g3 > 63 ? 63 : g3;
            sp0 = Fbase + (size_t)g0 * 65536;
            sp1 = Fbase + (size_t)g1 * 65536;
            sp2 = Fbase + (size_t)g2 * 65536;
            sp3 = Fbase + (size_t)g3 * 65536;
        }
        float4 acc[8];
#pragma unroll
        for (int p = 0; p < 8; ++p) acc[p] = make_float4(0.f, 0.f, 0.f, 0.f);

        // prologue: stage chunk 0 -> buf 0
        {
            float4 r0 = LD4(sp0), r1 = LD4(sp1), r2 = LD4(sp2), r3 = LD4(sp3);
            *(float4*)(&fs[0][st_lds])        = r0;
            *(float4*)(&fs[0][st_lds + 1024]) = r1;
            *(float4*)(&fs[0][st_lds + 2048]) = r2;
            *(float4*)(&fs[0][st_lds + 3072]) = r3;
        }
        __syncthreads();
        // issue chunk 1 loads early (ci +16 -> +16384 floats)
        float4 n0 = LD4(sp0 + 16384), n1 = LD4(sp1 + 16384);
        float4 n2 = LD4(sp2 + 16384), n3 = LD4(sp3 + 16384);
        // compute chunk 0 from buf 0 (hides chunk-1 load latency)
        const float* Wp = Wc;
        for (int ci = 0; ci < 16; ++ci) {
            float4 wv = LD4(Wp);
            const float* fb = &fs[0][ci * 32 + m4 * 4];
#pragma unroll
            for (int p = 0; p < 8; ++p) {
                float4 fv = *(const float4*)(fb + p * 512);
                acc[p].x += fv.x * wv.x - fv.y * wv.y;
                acc[p].y += fv.x * wv.y + fv.y * wv.x;
                acc[p].z += fv.z * wv.z - fv.w * wv.w;
                acc[p].w += fv.z * wv.w + fv.w * wv.z;
            }
            Wp += 32768;
        }
        // write chunk 1 -> buf 1 (buf 1 never read yet in this pc-iter)
        *(float4*)(&fs[1][st_lds])        = n0;
        *(float4*)(&fs[1][st_lds + 1024]) = n1;
        *(float4*)(&fs[1][st_lds + 2048]) = n2;
        *(float4*)(&fs[1][st_lds + 3072]) = n3;
        __syncthreads();
        // compute chunk 1 from buf 1
        for (int ci = 0; ci < 16; ++ci) {
            float4 wv = LD4(Wp);
            const float* fb = &fs[1][ci * 32 + m4 * 4];
#pragma unroll
            for (int p = 0; p < 8; ++p) {
                float4 fv = *(const float4*)(fb + p * 512);
                acc[p].x += fv.x * wv.x - fv.y * wv.y;
                acc[p].y += fv.x * wv.y + fv.y * wv.x;
                acc[p].z += fv.z * wv.z - fv.w * wv.w;
                acc[p].w += fv.z * wv.w + fv.w * wv.z;
            }
            Wp += 32768;
        }
        __syncthreads();   // all reads of both buffers done before next pc overwrite
#pragma unroll
        for (int p = 0; p < 8; ++p) {
            if (p < np)
                *(float4*)(Fob + (size_t)(p0 + pc + p) * 65536) = acc[p];
        }
    }
}

// ---------------- 1x1 conv (skip / proj1) ----------------
__global__ __launch_bounds__(256) void conv1x1_kernel(
    const float* __restrict__ src, float* __restrict__ dst,
    const float* __restrict__ Wall, const float* __restrict__ Ball,
    const int* __restrict__ pair_e, int wmul, int wadd, int do_gelu)
{
    int p = blockIdx.x, tile = blockIdx.y, t = threadIdx.x;
    int e = pair_e[p];
    int widx = e * wmul + wadd;
    const float* W = Wall + (size_t)widx * 4096;
    const float* B = Ball + widx * 64;
    const float* s = src + (size_t)p * 262144 + tile * 256 + t;
    float acc[64];
#pragma unroll
    for (int c = 0; c < 64; ++c) acc[c] = 0.f;
    for (int ci = 0; ci < 64; ++ci) {
        float hv = s[(size_t)ci * 4096];
        const float* wr = W + ci * 64;
#pragma unroll
        for (int c = 0; c < 64; ++c) acc[c] += hv * wr[c];
    }
    float* d = dst + (size_t)p * 262144 + tile * 256 + t;
    for (int c = 0; c < 64; ++c) {
        float v = acc[c] + B[c];
        if (do_gelu) v = gelu_f(v);
        d[(size_t)c * 4096] = v;
    }
}

// ---------------- inverse DFT (sums FoA+FoB) + skip-add + gelu ----------------
__global__ __launch_bounds__(256) void inv_kernel(
    const float* __restrict__ FoA, const float* __restrict__ FoB,
    const float* __restrict__ WY2, float* __restrict__ dst_h, int do_gelu)
{
    __shared__ float wy2[2048];
    __shared__ float twl[128];
    __shared__ float fo_s[1024];
    __shared__ float tT[64][36];
    __shared__ float ot[64][66];
    int t = threadIdx.x;
    for (int i = t; i < 512; i += 256) *(float4*)(&wy2[i * 4]) = *(const float4*)(WY2 + i * 4);
    if (t < 64) {
        float a = TWOPI_F * (float)t / 64.f;
        twl[2 * t] = cosf(a);
        twl[2 * t + 1] = sinf(a);
    }
    __syncthreads();

    for (int item = 0; item < 4; ++item) {
        int wid = blockIdx.x * 4 + item;
        int p = wid >> 6, co = wid & 63;
        const float* fA = FoA + (size_t)p * 65536 + (size_t)co * 1024;
        const float* fB = FoB + (size_t)p * 65536 + (size_t)co * 1024;
        {
            float4 a = LD4(fA + t * 4);
            float4 b = LD4(fB + t * 4);
            *(float4*)(&fo_s[t * 4]) = make_float4(a.x + b.x, a.y + b.y, a.z + b.z, a.w + b.w);
        }
        __syncthreads();
        {
            int xx = t & 63, kq = t >> 6;
            float Tr0 = 0.f, Ti0 = 0.f, Tr1 = 0.f, Ti1 = 0.f;
            float Tr2 = 0.f, Ti2 = 0.f, Tr3 = 0.f, Ti3 = 0.f;
#pragma unroll 4
            for (int kxm = 0; kxm < 32; ++kxm) {
                int kx = kxm < 16 ? kxm : kxm + 32;
                int idx = (kx * xx) & 63;
                float c_ = twl[2 * idx], s_ = twl[2 * idx + 1];
                float4 f0 = *(const float4*)(&fo_s[kxm * 32 + kq * 8]);
                float4 f1 = *(const float4*)(&fo_s[kxm * 32 + kq * 8 + 4]);
                Tr0 += f0.x * c_ - f0.y * s_;  Ti0 += f0.x * s_ + f0.y * c_;
                Tr1 += f0.z * c_ - f0.w * s_;  Ti1 += f0.z * s_ + f0.w * c_;
                Tr2 += f1.x * c_ - f1.y * s_;  Ti2 += f1.x * s_ + f1.y * c_;
                Tr3 += f1.z * c_ - f1.w * s_;  Ti3 += f1.z * s_ + f1.w * c_;
            }
            *(float4*)(&tT[xx][kq * 8])     = make_float4(Tr0, Ti0, Tr1, Ti1);
            *(float4*)(&tT[xx][kq * 8 + 4]) = make_float4(Tr2, Ti2, Tr3, Ti3);
        }
        __syncthreads();
        {
            int xx = t & 63, yq = t >> 6;
            float Trr[16], Tii[16];
#pragma unroll
            for (int q = 0; q < 8; ++q) {
                float4 v = *(const float4*)(&tT[xx][q * 4]);
                Trr[q * 2] = v.x; Tii[q * 2] = v.y;
                Trr[q * 2 + 1] = v.z; Tii[q * 2 + 1] = v.w;
            }
            for (int j = 0; j < 16; ++j) {
                int y = yq * 16 + j;
                const float* wr = &wy2[y * 32];
                float acc = 0.f;
#pragma unroll
                for (int k = 0; k < 16; ++k)
                    acc += Trr[k] * wr[2 * k] - Tii[k] * wr[2 * k + 1];
                ot[xx][y] = acc;
            }
        }
        __syncthreads();
        {
            float* base = dst_h + (size_t)p * 262144 + (size_t)co * 4096;
            for (int r = 0; r < 16; ++r) {
                int gidx = r * 256 + t;
                int xx = gidx >> 6, y = gidx & 63;
                float v = base[gidx] + ot[xx][y];
                if (do_gelu) v = gelu_f(v);
                base[gidx] = v;
            }
        }
        __syncthreads();
    }
}

// ---------------- proj2 + weighted accumulate ----------------
__global__ __launch_bounds__(256) void proj2_kernel(
    const float* __restrict__ hsrc, const float* __restrict__ p2w, const float* __restrict__ p2b,
    const int* __restrict__ pair_b, const int* __restrict__ pair_e,
    const float* __restrict__ pw, float* __restrict__ out)
{
    int p = blockIdx.x, tile = blockIdx.y, t = threadIdx.x;
    int b = pair_b[p], e = pair_e[p];
    float wgt = pw[p];
    const float* h = hsrc + (size_t)p * 262144 + tile * 256 + t;
    const float* w2 = p2w + e * 64;
    float acc = p2b[e];
#pragma unroll
    for (int c = 0; c < 64; ++c) acc += h[(size_t)c * 4096] * w2[c];
    atomicAdd(out + (size_t)b * 4096 + tile * 256 + t, wgt * acc);
}

// ---------------- launch ----------------
extern "C" void kernel_launch(void* const* d_in, const int* in_sizes, int n_in,
                              void* d_out, int out_size, void* d_ws, size_t ws_size,
                              hipStream_t stream) {
    const float* x    = (const float*)d_in[0];
    const float* encw = (const float*)d_in[1];
    const float* encb = (const float*)d_in[2];
    const float* wqkv = (const float*)d_in[3];
    const float* bqkv = (const float*)d_in[4];
    const float* wo   = (const float*)d_in[5];
    const float* bo   = (const float*)d_in[6];
    const float* ln1g = (const float*)d_in[7];
    const float* ln1b = (const float*)d_in[8];
    const float* fw1  = (const float*)d_in[9];
    const float* fb1  = (const float*)d_in[10];
    const float* fw2  = (const float*)d_in[11];
    const float* fb2  = (const float*)d_in[12];
    const float* ln2g = (const float*)d_in[13];
    const float* ln2b = (const float*)d_in[14];
    const float* fcw  = (const float*)d_in[15];
    const float* fcb  = (const float*)d_in[16];
    const float* lw   = (const float*)d_in[17];
    const float* lb   = (const float*)d_in[18];
    const float* sw1  = (const float*)d_in[19];
    const float* sw2  = (const float*)d_in[20];
    const float* skw  = (const float*)d_in[21];
    const float* skb  = (const float*)d_in[22];
    const float* p1w  = (const float*)d_in[23];
    const float* p1b  = (const float*)d_in[24];
    const float* p2w  = (const float*)d_in[25];
    const float* p2b  = (const float*)d_in[26];
    float* out = (float*)d_out;

    float* wsf    = (float*)d_ws;
    float* rw     = wsf;               // 256
    float* pair_w = wsf + 256;         // 64
    int*   ipart  = (int*)(wsf + 320);
    int* pair_b = ipart;               // 64
    int* pair_e = ipart + 64;          // 64
    int* estart = ipart + 128;         // 9
    float* Wy  = wsf + 512;            // 2048
    float* TWX = wsf + 2560;           // 4096
    float* WY2 = wsf + 6656;           // 2048
    float* hA  = wsf + 16384;                       // 64 * 262144
    float* hB  = hA + (size_t)64 * 262144;          // 64 * 262144
    float* F   = hB + (size_t)64 * 262144;          // 64 * 65536
    float* FoA = F + (size_t)64 * 65536;            // 64 * 65536
    float* FoB = FoA + (size_t)64 * 65536;          // 64 * 65536
    size_t need = (16384 + 2ull * 64 * 262144 + 64ull * 65536 + 64ull * 131072) * 4;
    if (ws_size < need) return;

    hipMemsetAsync(d_out, 0, (size_t)out_size * sizeof(float), stream);
    init_tables_kernel<<<1, 256, 0, stream>>>(Wy, TWX, WY2);
    router_kernel<<<32, 512, 0, stream>>>(x, encw, encb, wqkv, bqkv, wo, bo, ln1g, ln1b,
                                          fw1, fb1, fw2, fb2, ln2g, ln2b, fcw, fcb, rw);
    build_pairs_kernel<<<1, 64, 0, stream>>>(rw, pair_b, pair_e, pair_w, estart);
    lift_kernel<<<dim3(64, 16), 256, 0, stream>>>(x, lw, lb, pair_b, pair_e, hA);
    for (int l = 0; l < 4; ++l) {
        float* cur = (l & 1) ? hB : hA;
        float* nxt = (l & 1) ? hA : hB;
        fwdft_kernel<<<4096, 256, 0, stream>>>(cur, Wy, TWX, F);
        spectral_kernel<<<dim3(8, 2, 64), 256, 0, stream>>>(F, FoA, FoB, sw1, sw2, estart, l);
        conv1x1_kernel<<<dim3(64, 16), 256, 0, stream>>>(cur, nxt, skw, skb, pair_e, 4, l, 0);
        inv_kernel<<<1024, 256, 0, stream>>>(FoA, FoB, WY2, nxt, (l < 3) ? 1 : 0);
    }
    conv1x1_kernel<<<dim3(64, 16), 256, 0, stream>>>(hA, hB, p1w, p1b, pair_e, 1, 0, 1);
    proj2_kernel<<<dim3(64, 16), 256, 0, stream>>>(hB, p2w, p2b, pair_b, pair_e, pair_w, out);
}

// Round 12
// 4345.835 us; speedup vs baseline: 2.6149x; 2.6149x over previous
//
#include <hip/hip_runtime.h>
#include <math.h>

#define TWOPI_F 6.283185307179586f
#define LD4(p) (*(const float4*)(p))

__device__ __forceinline__ float gelu_f(float v) {
    float u = 0.7978845608028654f * (v + 0.044715f * v * v * v);
    return 0.5f * v * (1.f + tanhf(u));
}

// ---------------- twiddle tables ----------------
__global__ void init_tables_kernel(float* __restrict__ Wy, float* __restrict__ TWX,
                                   float* __restrict__ WY2) {
    int t = threadIdx.x;
    for (int i = t; i < 1024; i += 256) {
        int y = i >> 4, k = i & 15;
        int m = (k * y) & 63;
        float a = -TWOPI_F * (float)m / 64.f;
        Wy[y * 32 + 2 * k]     = cosf(a);
        Wy[y * 32 + 2 * k + 1] = sinf(a);
    }
    for (int i = t; i < 2048; i += 256) {
        int x = i >> 5, kxm = i & 31;
        int kx = kxm < 16 ? kxm : kxm + 32;
        int m = (kx * x) & 63;
        float a = -TWOPI_F * (float)m / 64.f;
        TWX[x * 64 + 2 * kxm]     = cosf(a);
        TWX[x * 64 + 2 * kxm + 1] = sinf(a);
    }
    for (int i = t; i < 1024; i += 256) {
        int y = i >> 4, k = i & 15;
        int m = (k * y) & 63;
        float a = TWOPI_F * (float)m / 64.f;
        float sc = (k == 0 ? 1.f : 2.f) / 4096.f;
        WY2[y * 32 + 2 * k]     = sc * cosf(a);
        WY2[y * 32 + 2 * k + 1] = sc * sinf(a);
    }
}

// ---------------- router v3: weight-reuse layout (col-group x row-group) ----------------
__global__ __launch_bounds__(512) void router_kernel(
    const float* __restrict__ x, const float* __restrict__ enc_w, const float* __restrict__ enc_b,
    const float* __restrict__ wqkv, const float* __restrict__ bqkv,
    const float* __restrict__ wo, const float* __restrict__ bo,
    const float* __restrict__ ln1g, const float* __restrict__ ln1b,
    const float* __restrict__ w1, const float* __restrict__ b1,
    const float* __restrict__ w2, const float* __restrict__ b2,
    const float* __restrict__ ln2g, const float* __restrict__ ln2b,
    const float* __restrict__ fcw, const float* __restrict__ fcb,
    float* __restrict__ rw)
{
    __shared__ float s[64][65];
    __shared__ float qk[64][193];
    __shared__ float sc[64][65];
    __shared__ float o64[64][65];
    __shared__ float feat[64];
    __shared__ float logits[8];
    int b = blockIdx.x, t = threadIdx.x;

    for (int i = t; i < 4096; i += 512) {
        int w_ = i >> 6, d = i & 63;
        s[w_][d] = x[b * 4096 + w_] * enc_w[d] + enc_b[d];
    }
    __syncthreads();

    for (int l = 0; l < 2; ++l) {
        {
            const float* Wq = wqkv + l * 64 * 192;
            const float* Bq = bqkv + l * 192;
            int c4 = t % 48, rg = t / 48;
            if (rg < 8) {
                const float* wcol = Wq + 4 * c4;
                float4 bq = LD4(Bq + 4 * c4);
                float4 acc[8];
#pragma unroll
                for (int i = 0; i < 8; ++i) acc[i] = bq;
                int r0 = rg * 8;
#pragma unroll 8
                for (int k = 0; k < 64; ++k) {
                    float4 wv = LD4(wcol + k * 192);
#pragma unroll
                    for (int i = 0; i < 8; ++i) {
                        float sv = s[r0 + i][k];
                        acc[i].x += sv * wv.x; acc[i].y += sv * wv.y;
                        acc[i].z += sv * wv.z; acc[i].w += sv * wv.w;
                    }
                }
#pragma unroll
                for (int i = 0; i < 8; ++i) {
                    qk[r0 + i][4 * c4]     = acc[i].x;
                    qk[r0 + i][4 * c4 + 1] = acc[i].y;
                    qk[r0 + i][4 * c4 + 2] = acc[i].z;
                    qk[r0 + i][4 * c4 + 3] = acc[i].w;
                }
            }
        }
        __syncthreads();
        for (int h = 0; h < 4; ++h) {
            for (int i = t; i < 4096; i += 512) {
                int q = i >> 6, kj = i & 63;
                float acc = 0.f;
#pragma unroll
                for (int d = 0; d < 16; ++d)
                    acc += qk[q][h * 16 + d] * qk[kj][64 + h * 16 + d];
                sc[q][kj] = acc * 0.25f;
            }
            __syncthreads();
            if (t < 64) {
                float m = -1e30f;
                for (int j = 0; j < 64; ++j) m = fmaxf(m, sc[t][j]);
                float sum = 0.f;
                for (int j = 0; j < 64; ++j) { float e2 = expf(sc[t][j] - m); sc[t][j] = e2; sum += e2; }
                float inv = 1.f / sum;
                for (int j = 0; j < 64; ++j) sc[t][j] *= inv;
            }
            __syncthreads();
            for (int i = t; i < 1024; i += 512) {
                int q = i >> 4, d = i & 15;
                float acc = 0.f;
#pragma unroll 8
                for (int j = 0; j < 64; ++j) acc += sc[q][j] * qk[j][128 + h * 16 + d];
                o64[q][h * 16 + d] = acc;
            }
            __syncthreads();
        }
        {
            const float* Wo = wo + l * 4096;
            const float* Bo = bo + l * 64;
            int c4 = t & 15, rg = t >> 4;
            const float* wcol = Wo + 4 * c4;
            float4 acc0 = LD4(Bo + 4 * c4), acc1 = acc0;
            int r0 = rg * 2;
#pragma unroll 8
            for (int k = 0; k < 64; ++k) {
                float4 wv = LD4(wcol + k * 64);
                float h0 = o64[r0][k], h1 = o64[r0 + 1][k];
                acc0.x += h0 * wv.x; acc0.y += h0 * wv.y;
                acc0.z += h0 * wv.z; acc0.w += h0 * wv.w;
                acc1.x += h1 * wv.x; acc1.y += h1 * wv.y;
                acc1.z += h1 * wv.z; acc1.w += h1 * wv.w;
            }
            sc[r0][4 * c4]     = s[r0][4 * c4]     + acc0.x;
            sc[r0][4 * c4 + 1] = s[r0][4 * c4 + 1] + acc0.y;
            sc[r0][4 * c4 + 2] = s[r0][4 * c4 + 2] + acc0.z;
            sc[r0][4 * c4 + 3] = s[r0][4 * c4 + 3] + acc0.w;
            sc[r0 + 1][4 * c4]     = s[r0 + 1][4 * c4]     + acc1.x;
            sc[r0 + 1][4 * c4 + 1] = s[r0 + 1][4 * c4 + 1] + acc1.y;
            sc[r0 + 1][4 * c4 + 2] = s[r0 + 1][4 * c4 + 2] + acc1.z;
            sc[r0 + 1][4 * c4 + 3] = s[r0 + 1][4 * c4 + 3] + acc1.w;
        }
        __syncthreads();
        if (t < 64) {
            float m = 0.f;
            for (int j = 0; j < 64; ++j) m += sc[t][j];
            m *= (1.f / 64.f);
            float v = 0.f;
            for (int j = 0; j < 64; ++j) { float d = sc[t][j] - m; v += d * d; }
            v *= (1.f / 64.f);
            float inv = rsqrtf(v + 1e-5f);
            for (int j = 0; j < 64; ++j)
                s[t][j] = (sc[t][j] - m) * inv * ln1g[l * 64 + j] + ln1b[l * 64 + j];
        }
        __syncthreads();
        {
            const float* W1 = w1 + l * 64 * 256;
            const float* B1 = b1 + l * 256;
            int c4 = t & 63, rg = t >> 6;
            const float* wcol = W1 + 4 * c4;
            float4 b1v = LD4(B1 + 4 * c4);
            float4 acc[8];
#pragma unroll
            for (int i = 0; i < 8; ++i) acc[i] = b1v;
            int r0 = rg * 8;
#pragma unroll 4
            for (int k = 0; k < 64; ++k) {
                float4 wv = LD4(wcol + k * 256);
#pragma unroll
                for (int i = 0; i < 8; ++i) {
                    float sv = s[r0 + i][k];
                    acc[i].x += sv * wv.x; acc[i].y += sv * wv.y;
                    acc[i].z += sv * wv.z; acc[i].w += sv * wv.w;
                }
            }
#pragma unroll
            for (int i = 0; i < 8; ++i) {
                float a0 = fmaxf(acc[i].x, 0.f), a1 = fmaxf(acc[i].y, 0.f);
                float a2 = fmaxf(acc[i].z, 0.f), a3 = fmaxf(acc[i].w, 0.f);
                if (c4 < 48) {
                    qk[r0 + i][4 * c4] = a0; qk[r0 + i][4 * c4 + 1] = a1;
                    qk[r0 + i][4 * c4 + 2] = a2; qk[r0 + i][4 * c4 + 3] = a3;
                } else {
                    int c = 4 * c4 - 192;
                    o64[r0 + i][c] = a0; o64[r0 + i][c + 1] = a1;
                    o64[r0 + i][c + 2] = a2; o64[r0 + i][c + 3] = a3;
                }
            }
        }
        __syncthreads();
        {
            const float* W2 = w2 + l * 256 * 64;
            const float* B2 = b2 + l * 64;
            int c4 = t & 15, rg = t >> 4;
            const float* wcol = W2 + 4 * c4;
            float4 acc0 = LD4(B2 + 4 * c4), acc1 = acc0;
            int r0 = rg * 2;
#pragma unroll 8
            for (int k = 0; k < 192; ++k) {
                float4 wv = LD4(wcol + k * 64);
                float h0 = qk[r0][k], h1 = qk[r0 + 1][k];
                acc0.x += h0 * wv.x; acc0.y += h0 * wv.y;
                acc0.z += h0 * wv.z; acc0.w += h0 * wv.w;
                acc1.x += h1 * wv.x; acc1.y += h1 * wv.y;
                acc1.z += h1 * wv.z; acc1.w += h1 * wv.w;
            }
#pragma unroll 8
            for (int k = 192; k < 256; ++k) {
                float4 wv = LD4(wcol + k * 64);
                float h0 = o64[r0][k - 192], h1 = o64[r0 + 1][k - 192];
                acc0.x += h0 * wv.x; acc0.y += h0 * wv.y;
                acc0.z += h0 * wv.z; acc0.w += h0 * wv.w;
                acc1.x += h1 * wv.x; acc1.y += h1 * wv.y;
                acc1.z += h1 * wv.z; acc1.w += h1 * wv.w;
            }
            sc[r0][4 * c4]     = s[r0][4 * c4]     + acc0.x;
            sc[r0][4 * c4 + 1] = s[r0][4 * c4 + 1] + acc0.y;
            sc[r0][4 * c4 + 2] = s[r0][4 * c4 + 2] + acc0.z;
            sc[r0][4 * c4 + 3] = s[r0][4 * c4 + 3] + acc0.w;
            sc[r0 + 1][4 * c4]     = s[r0 + 1][4 * c4]     + acc1.x;
            sc[r0 + 1][4 * c4 + 1] = s[r0 + 1][4 * c4 + 1] + acc1.y;
            sc[r0 + 1][4 * c4 + 2] = s[r0 + 1][4 * c4 + 2] + acc1.z;
            sc[r0 + 1][4 * c4 + 3] = s[r0 + 1][4 * c4 + 3] + acc1.w;
        }
        __syncthreads();
        if (t < 64) {
            float m = 0.f;
            for (int j = 0; j < 64; ++j) m += sc[t][j];
            m *= (1.f / 64.f);
            float v = 0.f;
            for (int j = 0; j < 64; ++j) { float d = sc[t][j] - m; v += d * d; }
            v *= (1.f / 64.f);
            float inv = rsqrtf(v + 1e-5f);
            for (int j = 0; j < 64; ++j)
                s[t][j] = (sc[t][j] - m) * inv * ln2g[l * 64 + j] + ln2b[l * 64 + j];
        }
        __syncthreads();
    }
    if (t < 64) {
        float m = -1e30f;
        for (int r = 0; r < 64; ++r) m = fmaxf(m, s[r][t]);
        feat[t] = m;
    }
    __syncthreads();
    if (t < 8) {
        float acc = fcb[t];
        for (int k = 0; k < 64; ++k) acc += feat[k] * fcw[k * 8 + t];
        logits[t] = acc;
    }
    __syncthreads();
    if (t == 0) {
        int i0 = 0;
        for (int j = 1; j < 8; ++j) if (logits[j] > logits[i0]) i0 = j;
        int i1 = -1;
        for (int j = 0; j < 8; ++j) {
            if (j == i0) continue;
            if (i1 < 0 || logits[j] > logits[i1]) i1 = j;
        }
        float e1 = expf(logits[i1] - logits[i0]);
        float w0 = 1.f / (1.f + e1);
        float w1v = e1 / (1.f + e1);
        for (int j = 0; j < 8; ++j) rw[b * 8 + j] = 0.f;
        rw[b * 8 + i0] = w0;
        rw[b * 8 + i1] = w1v;
    }
}

// ---------------- build compact (b,e) pair list grouped by expert ----------------
__global__ void build_pairs_kernel(const float* __restrict__ rw, int* __restrict__ pair_b,
                                   int* __restrict__ pair_e, float* __restrict__ pair_w,
                                   int* __restrict__ estart) {
    __shared__ float r[256];
    __shared__ int cnt[8], off[9];
    int t = threadIdx.x;
    for (int i = t; i < 256; i += 64) r[i] = rw[i];
    if (t < 64) { pair_b[t] = 0; pair_e[t] = 0; pair_w[t] = 0.f; }
    __syncthreads();
    if (t < 8) {
        int c = 0;
        for (int b = 0; b < 32; ++b) if (r[b * 8 + t] != 0.f) ++c;
        cnt[t] = c;
    }
    __syncthreads();
    if (t == 0) {
        int a = 0;
        for (int e = 0; e < 8; ++e) { off[e] = a; a += cnt[e]; }
        off[8] = a;
        for (int e = 0; e <= 8; ++e) estart[e] = off[e];
    }
    __syncthreads();
    if (t < 8) {
        int n = off[t];
        for (int b = 0; b < 32; ++b) {
            float w = r[b * 8 + t];
            if (w != 0.f) { pair_b[n] = b; pair_e[n] = t; pair_w[n] = w; ++n; }
        }
    }
}

// ---------------- lift ----------------
__global__ __launch_bounds__(256) void lift_kernel(const float* __restrict__ x,
    const float* __restrict__ lw, const float* __restrict__ lb,
    const int* __restrict__ pair_b, const int* __restrict__ pair_e, float* __restrict__ hA) {
    int p = blockIdx.x, tile = blockIdx.y, t = threadIdx.x;
    int b = pair_b[p], e = pair_e[p];
    float* h = hA + (size_t)p * 262144;
    const float* xb = x + (size_t)b * 4096;
    for (int i = tile * 16384 + t; i < (tile + 1) * 16384; i += 256) {
        int co = i >> 12, xy = i & 4095;
        h[i] = xb[xy] * lw[e * 64 + co] + lb[e * 64 + co];
    }
}

// ---------------- fused forward DFT v2: twx table replaced by 64-root table ----------------
__global__ __launch_bounds__(256) void fwdft_kernel(const float* __restrict__ h,
    const float* __restrict__ Wy, float* __restrict__ F) {
    __shared__ float ht[64][68];
    __shared__ float gt[64][36];
    __shared__ float wy[2048];
    __shared__ float tw64[128];   // e^{-2pi i m/64}
    int bid = blockIdx.x;
    int t = threadIdx.x;
    const float* src = h + (size_t)bid * 4096;
    for (int i = t; i < 1024; i += 256) {
        float4 v = *(const float4*)(src + i * 4);
        int x = (i * 4) >> 6, y = (i * 4) & 63;
        *(float4*)(&ht[x][y]) = v;
    }
    for (int i = t; i < 512; i += 256) *(float4*)(&wy[i * 4]) = *(const float4*)(Wy + i * 4);
    if (t < 64) {
        float a = -TWOPI_F * (float)t / 64.f;
        tw64[2 * t]     = cosf(a);
        tw64[2 * t + 1] = sinf(a);
    }
    __syncthreads();
    {
        int xx = t >> 2, kq = t & 3;
        float gr0 = 0.f, gi0 = 0.f, gr1 = 0.f, gi1 = 0.f;
        float gr2 = 0.f, gi2 = 0.f, gr3 = 0.f, gi3 = 0.f;
#pragma unroll 4
        for (int y = 0; y < 64; ++y) {
            float hv = ht[xx][y];
            float4 w0 = *(const float4*)(&wy[y * 32 + kq * 8]);
            float4 w1 = *(const float4*)(&wy[y * 32 + kq * 8 + 4]);
            gr0 += hv * w0.x; gi0 += hv * w0.y;
            gr1 += hv * w0.z; gi1 += hv * w0.w;
            gr2 += hv * w1.x; gi2 += hv * w1.y;
            gr3 += hv * w1.z; gi3 += hv * w1.w;
        }
        *(float4*)(&gt[xx][kq * 8])     = make_float4(gr0, gi0, gr1, gi1);
        *(float4*)(&gt[xx][kq * 8 + 4]) = make_float4(gr2, gi2, gr3, gi3);
    }
    __syncthreads();
    {
        int kxm = t & 31, kyq = t >> 5;
        int kx = kxm < 16 ? kxm : kxm + 32;
        float ar0 = 0.f, ai0 = 0.f, ar1 = 0.f, ai1 = 0.f;
        int idx = 0;   // (kx*xx) & 63, strength-reduced
#pragma unroll 4
        for (int xx = 0; xx < 64; ++xx) {
            float c_ = tw64[2 * idx], s_ = tw64[2 * idx + 1];
            float4 g = *(const float4*)(&gt[xx][kyq * 4]);
            ar0 += g.x * c_ - g.y * s_;  ai0 += g.x * s_ + g.y * c_;
            ar1 += g.z * c_ - g.w * s_;  ai1 += g.z * s_ + g.w * c_;
            idx = (idx + kx) & 63;
        }
        float* fb = F + (size_t)bid * 1024 + kxm * 32 + kyq * 4;
        *(float4*)(fb) = make_float4(ar0, ai0, ar1, ai1);
    }
}

// ---------------- spectral multiply v10: v8 + ci-half split + 4-wave cap ----------------
// grid (8 e, 2 co-halves, 64 z = wsel + 2*cih + 4*mq), block 256 = 32 co_l x 8 m4.
// Block covers 32 co x 32-float mode slice x 32 ci (cih half) -> partial FoA/FoB.
// Plain {barrier, stage 16KB, barrier, 16-ci compute} x2. NO manual buffering
// (R6/R9/R11 spill lesson). launch_bounds(256,4) -> <=128 VGPR, 4 blocks/CU.
__global__ __launch_bounds__(256, 4) void spectral_kernel(
    const float* __restrict__ F, float* __restrict__ FoA, float* __restrict__ FoB,
    const float* __restrict__ w1, const float* __restrict__ w2,
    const int* __restrict__ estart, int l)
{
    __shared__ float fs[4096];   // [p 8][ci 16][8 f4][4] = 16KB
    int e = blockIdx.x;
    int coh = blockIdx.y;
    int z = blockIdx.z;
    int wsel = z & 1, cih = (z >> 1) & 1, mq = z >> 2;   // mq in [0,16)
    int p0 = estart[e], ne = estart[e + 1] - p0;
    if (ne == 0) return;
    int t = threadIdx.x;
    int co_l = t >> 3, m4 = t & 7;
    int co_g = coh * 32 + co_l;
    int mo = mq * 32 + m4 * 4;

    // staging geometry: id = t + s*256 (s=0..3); p = id>>7, ci = (id>>3)&15, f4 = id&7
    int st_tp  = t >> 7;
    int st_ci  = (t >> 3) & 15;
    int st_f4  = t & 7;
    int st_lds = t * 4;

    const float* wbase = (wsel == 0 ? w1 : w2) + (size_t)(e * 4 + l) * 2097152;
    const float* Wc = wbase + (size_t)(cih * 32) * 32768 + (size_t)co_g * 512 + mo;
    float* Fob = (cih ? FoB : FoA) + (size_t)co_g * 1024 + wsel * 512 + mo;
    const float* Fbase = F + (size_t)(cih * 32 + st_ci) * 1024 + wsel * 512
                           + mq * 32 + st_f4 * 4;

    for (int pc = 0; pc < ne; pc += 8) {
        int np = ne - pc; if (np > 8) np = 8;
        const float* sp0; const float* sp1; const float* sp2; const float* sp3;
        {
            int g0 = p0 + pc + st_tp;
            int g1 = g0 + 2, g2 = g0 + 4, g3 = g0 + 6;
            g0 = g0 > 63 ? 63 : g0; g1 = g1 > 63 ? 63 : g1;
            g2 = g2 > 63 ? 63 : g2; g3 = g3 > 63 ? 63 : g3;
            sp0 = Fbase + (size_t)g0 * 65536;
            sp1 = Fbase + (size_t)g1 * 65536;
            sp2 = Fbase + (size_t)g2 * 65536;
            sp3 = Fbase + (size_t)g3 * 65536;
        }
        float4 acc[8];
#pragma unroll
        for (int p = 0; p < 8; ++p) acc[p] = make_float4(0.f, 0.f, 0.f, 0.f);
        for (int cc = 0; cc < 2; ++cc) {
            __syncthreads();   // previous chunk fully consumed
            {
                int off = cc * 16384;
                *(float4*)(&fs[st_lds])        = LD4(sp0 + off);
                *(float4*)(&fs[st_lds + 1024]) = LD4(sp1 + off);
                *(float4*)(&fs[st_lds + 2048]) = LD4(sp2 + off);
                *(float4*)(&fs[st_lds + 3072]) = LD4(sp3 + off);
            }
            __syncthreads();
            const float* Wp = Wc + (size_t)(cc * 16) * 32768;
            for (int ci = 0; ci < 16; ++ci) {
                float4 wv = LD4(Wp);
                const float* fb = &fs[ci * 32 + m4 * 4];
#pragma unroll
                for (int p = 0; p < 8; ++p) {
                    float4 fv = *(const float4*)(fb + p * 512);
                    acc[p].x += fv.x * wv.x - fv.y * wv.y;
                    acc[p].y += fv.x * wv.y + fv.y * wv.x;
                    acc[p].z += fv.z * wv.z - fv.w * wv.w;
                    acc[p].w += fv.z * wv.w + fv.w * wv.z;
                }
                Wp += 32768;
            }
        }
        __syncthreads();
#pragma unroll
        for (int p = 0; p < 8; ++p) {
            if (p < np)
                *(float4*)(Fob + (size_t)(p0 + pc + p) * 65536) = acc[p];
        }
    }
}

// ---------------- 1x1 conv (skip / proj1) ----------------
__global__ __launch_bounds__(256) void conv1x1_kernel(
    const float* __restrict__ src, float* __restrict__ dst,
    const float* __restrict__ Wall, const float* __restrict__ Ball,
    const int* __restrict__ pair_e, int wmul, int wadd, int do_gelu)
{
    int p = blockIdx.x, tile = blockIdx.y, t = threadIdx.x;
    int e = pair_e[p];
    int widx = e * wmul + wadd;
    const float* W = Wall + (size_t)widx * 4096;
    const float* B = Ball + widx * 64;
    const float* s = src + (size_t)p * 262144 + tile * 256 + t;
    float acc[64];
#pragma unroll
    for (int c = 0; c < 64; ++c) acc[c] = 0.f;
    for (int ci = 0; ci < 64; ++ci) {
        float hv = s[(size_t)ci * 4096];
        const float* wr = W + ci * 64;
#pragma unroll
        for (int c = 0; c < 64; ++c) acc[c] += hv * wr[c];
    }
    float* d = dst + (size_t)p * 262144 + tile * 256 + t;
    for (int c = 0; c < 64; ++c) {
        float v = acc[c] + B[c];
        if (do_gelu) v = gelu_f(v);
        d[(size_t)c * 4096] = v;
    }
}

// ---------------- inverse DFT (sums FoA+FoB) + skip-add + gelu ----------------
__global__ __launch_bounds__(256) void inv_kernel(
    const float* __restrict__ FoA, const float* __restrict__ FoB,
    const float* __restrict__ WY2, float* __restrict__ dst_h, int do_gelu)
{
    __shared__ float wy2[2048];
    __shared__ float twl[128];
    __shared__ float fo_s[1024];
    __shared__ float tT[64][36];
    __shared__ float ot[64][66];
    int t = threadIdx.x;
    for (int i = t; i < 512; i += 256) *(float4*)(&wy2[i * 4]) = *(const float4*)(WY2 + i * 4);
    if (t < 64) {
        float a = TWOPI_F * (float)t / 64.f;
        twl[2 * t] = cosf(a);
        twl[2 * t + 1] = sinf(a);
    }
    __syncthreads();

    for (int item = 0; item < 4; ++item) {
        int wid = blockIdx.x * 4 + item;
        int p = wid >> 6, co = wid & 63;
        const float* fA = FoA + (size_t)p * 65536 + (size_t)co * 1024;
        const float* fB = FoB + (size_t)p * 65536 + (size_t)co * 1024;
        {
            float4 a = LD4(fA + t * 4);
            float4 b = LD4(fB + t * 4);
            *(float4*)(&fo_s[t * 4]) = make_float4(a.x + b.x, a.y + b.y, a.z + b.z, a.w + b.w);
        }
        __syncthreads();
        {
            int xx = t & 63, kq = t >> 6;
            float Tr0 = 0.f, Ti0 = 0.f, Tr1 = 0.f, Ti1 = 0.f;
            float Tr2 = 0.f, Ti2 = 0.f, Tr3 = 0.f, Ti3 = 0.f;
#pragma unroll 4
            for (int kxm = 0; kxm < 32; ++kxm) {
                int kx = kxm < 16 ? kxm : kxm + 32;
                int idx = (kx * xx) & 63;
                float c_ = twl[2 * idx], s_ = twl[2 * idx + 1];
                float4 f0 = *(const float4*)(&fo_s[kxm * 32 + kq * 8]);
                float4 f1 = *(const float4*)(&fo_s[kxm * 32 + kq * 8 + 4]);
                Tr0 += f0.x * c_ - f0.y * s_;  Ti0 += f0.x * s_ + f0.y * c_;
                Tr1 += f0.z * c_ - f0.w * s_;  Ti1 += f0.z * s_ + f0.w * c_;
                Tr2 += f1.x * c_ - f1.y * s_;  Ti2 += f1.x * s_ + f1.y * c_;
                Tr3 += f1.z * c_ - f1.w * s_;  Ti3 += f1.z * s_ + f1.w * c_;
            }
            *(float4*)(&tT[xx][kq * 8])     = make_float4(Tr0, Ti0, Tr1, Ti1);
            *(float4*)(&tT[xx][kq * 8 + 4]) = make_float4(Tr2, Ti2, Tr3, Ti3);
        }
        __syncthreads();
        {
            int xx = t & 63, yq = t >> 6;
            float Trr[16], Tii[16];
#pragma unroll
            for (int q = 0; q < 8; ++q) {
                float4 v = *(const float4*)(&tT[xx][q * 4]);
                Trr[q * 2] = v.x; Tii[q * 2] = v.y;
                Trr[q * 2 + 1] = v.z; Tii[q * 2 + 1] = v.w;
            }
            for (int j = 0; j < 16; ++j) {
                int y = yq * 16 + j;
                const float* wr = &wy2[y * 32];
                float acc = 0.f;
#pragma unroll
                for (int k = 0; k < 16; ++k)
                    acc += Trr[k] * wr[2 * k] - Tii[k] * wr[2 * k + 1];
                ot[xx][y] = acc;
            }
        }
        __syncthreads();
        {
            float* base = dst_h + (size_t)p * 262144 + (size_t)co * 4096;
            for (int r = 0; r < 16; ++r) {
                int gidx = r * 256 + t;
                int xx = gidx >> 6, y = gidx & 63;
                float v = base[gidx] + ot[xx][y];
                if (do_gelu) v = gelu_f(v);
                base[gidx] = v;
            }
        }
        __syncthreads();
    }
}

// ---------------- proj2 + weighted accumulate ----------------
__global__ __launch_bounds__(256) void proj2_kernel(
    const float* __restrict__ hsrc, const float* __restrict__ p2w, const float* __restrict__ p2b,
    const int* __restrict__ pair_b, const int* __restrict__ pair_e,
    const float* __restrict__ pw, float* __restrict__ out)
{
    int p = blockIdx.x, tile = blockIdx.y, t = threadIdx.x;
    int b = pair_b[p], e = pair_e[p];
    float wgt = pw[p];
    const float* h = hsrc + (size_t)p * 262144 + tile * 256 + t;
    const float* w2 = p2w + e * 64;
    float acc = p2b[e];
#pragma unroll
    for (int c = 0; c < 64; ++c) acc += h[(size_t)c * 4096] * w2[c];
    atomicAdd(out + (size_t)b * 4096 + tile * 256 + t, wgt * acc);
}

// ---------------- launch ----------------
extern "C" void kernel_launch(void* const* d_in, const int* in_sizes, int n_in,
                              void* d_out, int out_size, void* d_ws, size_t ws_size,
                              hipStream_t stream) {
    const float* x    = (const float*)d_in[0];
    const float* encw = (const float*)d_in[1];
    const float* encb = (const float*)d_in[2];
    const float* wqkv = (const float*)d_in[3];
    const float* bqkv = (const float*)d_in[4];
    const float* wo   = (const float*)d_in[5];
    const float* bo   = (const float*)d_in[6];
    const float* ln1g = (const float*)d_in[7];
    const float* ln1b = (const float*)d_in[8];
    const float* fw1  = (const float*)d_in[9];
    const float* fb1  = (const float*)d_in[10];
    const float* fw2  = (const float*)d_in[11];
    const float* fb2  = (const float*)d_in[12];
    const float* ln2g = (const float*)d_in[13];
    const float* ln2b = (const float*)d_in[14];
    const float* fcw  = (const float*)d_in[15];
    const float* fcb  = (const float*)d_in[16];
    const float* lw   = (const float*)d_in[17];
    const float* lb   = (const float*)d_in[18];
    const float* sw1  = (const float*)d_in[19];
    const float* sw2  = (const float*)d_in[20];
    const float* skw  = (const float*)d_in[21];
    const float* skb  = (const float*)d_in[22];
    const float* p1w  = (const float*)d_in[23];
    const float* p1b  = (const float*)d_in[24];
    const float* p2w  = (const float*)d_in[25];
    const float* p2b  = (const float*)d_in[26];
    float* out = (float*)d_out;

    float* wsf    = (float*)d_ws;
    float* rw     = wsf;               // 256
    float* pair_w = wsf + 256;         // 64
    int*   ipart  = (int*)(wsf + 320);
    int* pair_b = ipart;               // 64
    int* pair_e = ipart + 64;          // 64
    int* estart = ipart + 128;         // 9
    float* Wy  = wsf + 512;            // 2048
    float* TWX = wsf + 2560;           // 4096 (kept for layout compat; unused)
    float* WY2 = wsf + 6656;           // 2048
    float* hA  = wsf + 16384;                       // 64 * 262144
    float* hB  = hA + (size_t)64 * 262144;          // 64 * 262144
    float* F   = hB + (size_t)64 * 262144;          // 64 * 65536
    float* FoA = F + (size_t)64 * 65536;            // 64 * 65536
    float* FoB = FoA + (size_t)64 * 65536;          // 64 * 65536
    size_t need = (16384 + 2ull * 64 * 262144 + 64ull * 65536 + 64ull * 131072) * 4;
    if (ws_size < need) return;

    hipMemsetAsync(d_out, 0, (size_t)out_size * sizeof(float), stream);
    init_tables_kernel<<<1, 256, 0, stream>>>(Wy, TWX, WY2);
    router_kernel<<<32, 512, 0, stream>>>(x, encw, encb, wqkv, bqkv, wo, bo, ln1g, ln1b,
                                          fw1, fb1, fw2, fb2, ln2g, ln2b, fcw, fcb, rw);
    build_pairs_kernel<<<1, 64, 0, stream>>>(rw, pair_b, pair_e, pair_w, estart);
    lift_kernel<<<dim3(64, 16), 256, 0, stream>>>(x, lw, lb, pair_b, pair_e, hA);
    for (int l = 0; l < 4; ++l) {
        float* cur = (l & 1) ? hB : hA;
        float* nxt = (l & 1) ? hA : hB;
        fwdft_kernel<<<4096, 256, 0, stream>>>(cur, Wy, F);
        spectral_kernel<<<dim3(8, 2, 64), 256, 0, stream>>>(F, FoA, FoB, sw1, sw2, estart, l);
        conv1x1_kernel<<<dim3(64, 16), 256, 0, stream>>>(cur, nxt, skw, skb, pair_e, 4, l, 0);
        inv_kernel<<<1024, 256, 0, stream>>>(FoA, FoB, WY2, nxt, (l < 3) ? 1 : 0);
    }
    conv1x1_kernel<<<dim3(64, 16), 256, 0, stream>>>(hA, hB, p1w, p1b, pair_e, 1, 0, 1);
    proj2_kernel<<<dim3(64, 16), 256, 0, stream>>>(hB, p2w, p2b, pair_b, pair_e, pair_w, out);
}

// Round 13
// 2283.856 us; speedup vs baseline: 4.9758x; 1.9028x over previous
//
#include <hip/hip_runtime.h>
#include <math.h>

#define TWOPI_F 6.283185307179586f
#define LD4(p) (*(const float4*)(p))

__device__ __forceinline__ float gelu_f(float v) {
    float u = 0.7978845608028654f * (v + 0.044715f * v * v * v);
    return 0.5f * v * (1.f + tanhf(u));
}

// ---------------- twiddle tables ----------------
__global__ void init_tables_kernel(float* __restrict__ Wy, float* __restrict__ TWX,
                                   float* __restrict__ WY2) {
    int t = threadIdx.x;
    for (int i = t; i < 1024; i += 256) {
        int y = i >> 4, k = i & 15;
        int m = (k * y) & 63;
        float a = -TWOPI_F * (float)m / 64.f;
        Wy[y * 32 + 2 * k]     = cosf(a);
        Wy[y * 32 + 2 * k + 1] = sinf(a);
    }
    for (int i = t; i < 2048; i += 256) {
        int x = i >> 5, kxm = i & 31;
        int kx = kxm < 16 ? kxm : kxm + 32;
        int m = (kx * x) & 63;
        float a = -TWOPI_F * (float)m / 64.f;
        TWX[x * 64 + 2 * kxm]     = cosf(a);
        TWX[x * 64 + 2 * kxm + 1] = sinf(a);
    }
    for (int i = t; i < 1024; i += 256) {
        int y = i >> 4, k = i & 15;
        int m = (k * y) & 63;
        float a = TWOPI_F * (float)m / 64.f;
        float sc = (k == 0 ? 1.f : 2.f) / 4096.f;
        WY2[y * 32 + 2 * k]     = sc * cosf(a);
        WY2[y * 32 + 2 * k + 1] = sc * sinf(a);
    }
}

// ---------------- router v3: weight-reuse layout (col-group x row-group) ----------------
__global__ __launch_bounds__(512) void router_kernel(
    const float* __restrict__ x, const float* __restrict__ enc_w, const float* __restrict__ enc_b,
    const float* __restrict__ wqkv, const float* __restrict__ bqkv,
    const float* __restrict__ wo, const float* __restrict__ bo,
    const float* __restrict__ ln1g, const float* __restrict__ ln1b,
    const float* __restrict__ w1, const float* __restrict__ b1,
    const float* __restrict__ w2, const float* __restrict__ b2,
    const float* __restrict__ ln2g, const float* __restrict__ ln2b,
    const float* __restrict__ fcw, const float* __restrict__ fcb,
    float* __restrict__ rw)
{
    __shared__ float s[64][65];
    __shared__ float qk[64][193];
    __shared__ float sc[64][65];
    __shared__ float o64[64][65];
    __shared__ float feat[64];
    __shared__ float logits[8];
    int b = blockIdx.x, t = threadIdx.x;

    for (int i = t; i < 4096; i += 512) {
        int w_ = i >> 6, d = i & 63;
        s[w_][d] = x[b * 4096 + w_] * enc_w[d] + enc_b[d];
    }
    __syncthreads();

    for (int l = 0; l < 2; ++l) {
        {
            const float* Wq = wqkv + l * 64 * 192;
            const float* Bq = bqkv + l * 192;
            int c4 = t % 48, rg = t / 48;
            if (rg < 8) {
                const float* wcol = Wq + 4 * c4;
                float4 bq = LD4(Bq + 4 * c4);
                float4 acc[8];
#pragma unroll
                for (int i = 0; i < 8; ++i) acc[i] = bq;
                int r0 = rg * 8;
#pragma unroll 8
                for (int k = 0; k < 64; ++k) {
                    float4 wv = LD4(wcol + k * 192);
#pragma unroll
                    for (int i = 0; i < 8; ++i) {
                        float sv = s[r0 + i][k];
                        acc[i].x += sv * wv.x; acc[i].y += sv * wv.y;
                        acc[i].z += sv * wv.z; acc[i].w += sv * wv.w;
                    }
                }
#pragma unroll
                for (int i = 0; i < 8; ++i) {
                    qk[r0 + i][4 * c4]     = acc[i].x;
                    qk[r0 + i][4 * c4 + 1] = acc[i].y;
                    qk[r0 + i][4 * c4 + 2] = acc[i].z;
                    qk[r0 + i][4 * c4 + 3] = acc[i].w;
                }
            }
        }
        __syncthreads();
        for (int h = 0; h < 4; ++h) {
            for (int i = t; i < 4096; i += 512) {
                int q = i >> 6, kj = i & 63;
                float acc = 0.f;
#pragma unroll
                for (int d = 0; d < 16; ++d)
                    acc += qk[q][h * 16 + d] * qk[kj][64 + h * 16 + d];
                sc[q][kj] = acc * 0.25f;
            }
            __syncthreads();
            if (t < 64) {
                float m = -1e30f;
                for (int j = 0; j < 64; ++j) m = fmaxf(m, sc[t][j]);
                float sum = 0.f;
                for (int j = 0; j < 64; ++j) { float e2 = expf(sc[t][j] - m); sc[t][j] = e2; sum += e2; }
                float inv = 1.f / sum;
                for (int j = 0; j < 64; ++j) sc[t][j] *= inv;
            }
            __syncthreads();
            for (int i = t; i < 1024; i += 512) {
                int q = i >> 4, d = i & 15;
                float acc = 0.f;
#pragma unroll 8
                for (int j = 0; j < 64; ++j) acc += sc[q][j] * qk[j][128 + h * 16 + d];
                o64[q][h * 16 + d] = acc;
            }
            __syncthreads();
        }
        {
            const float* Wo = wo + l * 4096;
            const float* Bo = bo + l * 64;
            int c4 = t & 15, rg = t >> 4;
            const float* wcol = Wo + 4 * c4;
            float4 acc0 = LD4(Bo + 4 * c4), acc1 = acc0;
            int r0 = rg * 2;
#pragma unroll 8
            for (int k = 0; k < 64; ++k) {
                float4 wv = LD4(wcol + k * 64);
                float h0 = o64[r0][k], h1 = o64[r0 + 1][k];
                acc0.x += h0 * wv.x; acc0.y += h0 * wv.y;
                acc0.z += h0 * wv.z; acc0.w += h0 * wv.w;
                acc1.x += h1 * wv.x; acc1.y += h1 * wv.y;
                acc1.z += h1 * wv.z; acc1.w += h1 * wv.w;
            }
            sc[r0][4 * c4]     = s[r0][4 * c4]     + acc0.x;
            sc[r0][4 * c4 + 1] = s[r0][4 * c4 + 1] + acc0.y;
            sc[r0][4 * c4 + 2] = s[r0][4 * c4 + 2] + acc0.z;
            sc[r0][4 * c4 + 3] = s[r0][4 * c4 + 3] + acc0.w;
            sc[r0 + 1][4 * c4]     = s[r0 + 1][4 * c4]     + acc1.x;
            sc[r0 + 1][4 * c4 + 1] = s[r0 + 1][4 * c4 + 1] + acc1.y;
            sc[r0 + 1][4 * c4 + 2] = s[r0 + 1][4 * c4 + 2] + acc1.z;
            sc[r0 + 1][4 * c4 + 3] = s[r0 + 1][4 * c4 + 3] + acc1.w;
        }
        __syncthreads();
        if (t < 64) {
            float m = 0.f;
            for (int j = 0; j < 64; ++j) m += sc[t][j];
            m *= (1.f / 64.f);
            float v = 0.f;
            for (int j = 0; j < 64; ++j) { float d = sc[t][j] - m; v += d * d; }
            v *= (1.f / 64.f);
            float inv = rsqrtf(v + 1e-5f);
            for (int j = 0; j < 64; ++j)
                s[t][j] = (sc[t][j] - m) * inv * ln1g[l * 64 + j] + ln1b[l * 64 + j];
        }
        __syncthreads();
        {
            const float* W1 = w1 + l * 64 * 256;
            const float* B1 = b1 + l * 256;
            int c4 = t & 63, rg = t >> 6;
            const float* wcol = W1 + 4 * c4;
            float4 b1v = LD4(B1 + 4 * c4);
            float4 acc[8];
#pragma unroll
            for (int i = 0; i < 8; ++i) acc[i] = b1v;
            int r0 = rg * 8;
#pragma unroll 4
            for (int k = 0; k < 64; ++k) {
                float4 wv = LD4(wcol + k * 256);
#pragma unroll
                for (int i = 0; i < 8; ++i) {
                    float sv = s[r0 + i][k];
                    acc[i].x += sv * wv.x; acc[i].y += sv * wv.y;
                    acc[i].z += sv * wv.z; acc[i].w += sv * wv.w;
                }
            }
#pragma unroll
            for (int i = 0; i < 8; ++i) {
                float a0 = fmaxf(acc[i].x, 0.f), a1 = fmaxf(acc[i].y, 0.f);
                float a2 = fmaxf(acc[i].z, 0.f), a3 = fmaxf(acc[i].w, 0.f);
                if (c4 < 48) {
                    qk[r0 + i][4 * c4] = a0; qk[r0 + i][4 * c4 + 1] = a1;
                    qk[r0 + i][4 * c4 + 2] = a2; qk[r0 + i][4 * c4 + 3] = a3;
                } else {
                    int c = 4 * c4 - 192;
                    o64[r0 + i][c] = a0; o64[r0 + i][c + 1] = a1;
                    o64[r0 + i][c + 2] = a2; o64[r0 + i][c + 3] = a3;
                }
            }
        }
        __syncthreads();
        {
            const float* W2 = w2 + l * 256 * 64;
            const float* B2 = b2 + l * 64;
            int c4 = t & 15, rg = t >> 4;
            const float* wcol = W2 + 4 * c4;
            float4 acc0 = LD4(B2 + 4 * c4), acc1 = acc0;
            int r0 = rg * 2;
#pragma unroll 8
            for (int k = 0; k < 192; ++k) {
                float4 wv = LD4(wcol + k * 64);
                float h0 = qk[r0][k], h1 = qk[r0 + 1][k];
                acc0.x += h0 * wv.x; acc0.y += h0 * wv.y;
                acc0.z += h0 * wv.z; acc0.w += h0 * wv.w;
                acc1.x += h1 * wv.x; acc1.y += h1 * wv.y;
                acc1.z += h1 * wv.z; acc1.w += h1 * wv.w;
            }
#pragma unroll 8
            for (int k = 192; k < 256; ++k) {
                float4 wv = LD4(wcol + k * 64);
                float h0 = o64[r0][k - 192], h1 = o64[r0 + 1][k - 192];
                acc0.x += h0 * wv.x; acc0.y += h0 * wv.y;
                acc0.z += h0 * wv.z; acc0.w += h0 * wv.w;
                acc1.x += h1 * wv.x; acc1.y += h1 * wv.y;
                acc1.z += h1 * wv.z; acc1.w += h1 * wv.w;
            }
            sc[r0][4 * c4]     = s[r0][4 * c4]     + acc0.x;
            sc[r0][4 * c4 + 1] = s[r0][4 * c4 + 1] + acc0.y;
            sc[r0][4 * c4 + 2] = s[r0][4 * c4 + 2] + acc0.z;
            sc[r0][4 * c4 + 3] = s[r0][4 * c4 + 3] + acc0.w;
            sc[r0 + 1][4 * c4]     = s[r0 + 1][4 * c4]     + acc1.x;
            sc[r0 + 1][4 * c4 + 1] = s[r0 + 1][4 * c4 + 1] + acc1.y;
            sc[r0 + 1][4 * c4 + 2] = s[r0 + 1][4 * c4 + 2] + acc1.z;
            sc[r0 + 1][4 * c4 + 3] = s[r0 + 1][4 * c4 + 3] + acc1.w;
        }
        __syncthreads();
        if (t < 64) {
            float m = 0.f;
            for (int j = 0; j < 64; ++j) m += sc[t][j];
            m *= (1.f / 64.f);
            float v = 0.f;
            for (int j = 0; j < 64; ++j) { float d = sc[t][j] - m; v += d * d; }
            v *= (1.f / 64.f);
            float inv = rsqrtf(v + 1e-5f);
            for (int j = 0; j < 64; ++j)
                s[t][j] = (sc[t][j] - m) * inv * ln2g[l * 64 + j] + ln2b[l * 64 + j];
        }
        __syncthreads();
    }
    if (t < 64) {
        float m = -1e30f;
        for (int r = 0; r < 64; ++r) m = fmaxf(m, s[r][t]);
        feat[t] = m;
    }
    __syncthreads();
    if (t < 8) {
        float acc = fcb[t];
        for (int k = 0; k < 64; ++k) acc += feat[k] * fcw[k * 8 + t];
        logits[t] = acc;
    }
    __syncthreads();
    if (t == 0) {
        int i0 = 0;
        for (int j = 1; j < 8; ++j) if (logits[j] > logits[i0]) i0 = j;
        int i1 = -1;
        for (int j = 0; j < 8; ++j) {
            if (j == i0) continue;
            if (i1 < 0 || logits[j] > logits[i1]) i1 = j;
        }
        float e1 = expf(logits[i1] - logits[i0]);
        float w0 = 1.f / (1.f + e1);
        float w1v = e1 / (1.f + e1);
        for (int j = 0; j < 8; ++j) rw[b * 8 + j] = 0.f;
        rw[b * 8 + i0] = w0;
        rw[b * 8 + i1] = w1v;
    }
}

// ---------------- build compact (b,e) pair list grouped by expert ----------------
__global__ void build_pairs_kernel(const float* __restrict__ rw, int* __restrict__ pair_b,
                                   int* __restrict__ pair_e, float* __restrict__ pair_w,
                                   int* __restrict__ estart) {
    __shared__ float r[256];
    __shared__ int cnt[8], off[9];
    int t = threadIdx.x;
    for (int i = t; i < 256; i += 64) r[i] = rw[i];
    if (t < 64) { pair_b[t] = 0; pair_e[t] = 0; pair_w[t] = 0.f; }
    __syncthreads();
    if (t < 8) {
        int c = 0;
        for (int b = 0; b < 32; ++b) if (r[b * 8 + t] != 0.f) ++c;
        cnt[t] = c;
    }
    __syncthreads();
    if (t == 0) {
        int a = 0;
        for (int e = 0; e < 8; ++e) { off[e] = a; a += cnt[e]; }
        off[8] = a;
        for (int e = 0; e <= 8; ++e) estart[e] = off[e];
    }
    __syncthreads();
    if (t < 8) {
        int n = off[t];
        for (int b = 0; b < 32; ++b) {
            float w = r[b * 8 + t];
            if (w != 0.f) { pair_b[n] = b; pair_e[n] = t; pair_w[n] = w; ++n; }
        }
    }
}

// ---------------- lift ----------------
__global__ __launch_bounds__(256) void lift_kernel(const float* __restrict__ x,
    const float* __restrict__ lw, const float* __restrict__ lb,
    const int* __restrict__ pair_b, const int* __restrict__ pair_e, float* __restrict__ hA) {
    int p = blockIdx.x, tile = blockIdx.y, t = threadIdx.x;
    int b = pair_b[p], e = pair_e[p];
    float* h = hA + (size_t)p * 262144;
    const float* xb = x + (size_t)b * 4096;
    for (int i = tile * 16384 + t; i < (tile + 1) * 16384; i += 256) {
        int co = i >> 12, xy = i & 4095;
        h[i] = xb[xy] * lw[e * 64 + co] + lb[e * 64 + co];
    }
}

// ---------------- fused forward DFT v2: twx table replaced by 64-root table ----------------
__global__ __launch_bounds__(256) void fwdft_kernel(const float* __restrict__ h,
    const float* __restrict__ Wy, float* __restrict__ F) {
    __shared__ float ht[64][68];
    __shared__ float gt[64][36];
    __shared__ float wy[2048];
    __shared__ float tw64[128];   // e^{-2pi i m/64}
    int bid = blockIdx.x;
    int t = threadIdx.x;
    const float* src = h + (size_t)bid * 4096;
    for (int i = t; i < 1024; i += 256) {
        float4 v = *(const float4*)(src + i * 4);
        int x = (i * 4) >> 6, y = (i * 4) & 63;
        *(float4*)(&ht[x][y]) = v;
    }
    for (int i = t; i < 512; i += 256) *(float4*)(&wy[i * 4]) = *(const float4*)(Wy + i * 4);
    if (t < 64) {
        float a = -TWOPI_F * (float)t / 64.f;
        tw64[2 * t]     = cosf(a);
        tw64[2 * t + 1] = sinf(a);
    }
    __syncthreads();
    {
        int xx = t >> 2, kq = t & 3;
        float gr0 = 0.f, gi0 = 0.f, gr1 = 0.f, gi1 = 0.f;
        float gr2 = 0.f, gi2 = 0.f, gr3 = 0.f, gi3 = 0.f;
#pragma unroll 4
        for (int y = 0; y < 64; ++y) {
            float hv = ht[xx][y];
            float4 w0 = *(const float4*)(&wy[y * 32 + kq * 8]);
            float4 w1 = *(const float4*)(&wy[y * 32 + kq * 8 + 4]);
            gr0 += hv * w0.x; gi0 += hv * w0.y;
            gr1 += hv * w0.z; gi1 += hv * w0.w;
            gr2 += hv * w1.x; gi2 += hv * w1.y;
            gr3 += hv * w1.z; gi3 += hv * w1.w;
        }
        *(float4*)(&gt[xx][kq * 8])     = make_float4(gr0, gi0, gr1, gi1);
        *(float4*)(&gt[xx][kq * 8 + 4]) = make_float4(gr2, gi2, gr3, gi3);
    }
    __syncthreads();
    {
        int kxm = t & 31, kyq = t >> 5;
        int kx = kxm < 16 ? kxm : kxm + 32;
        float ar0 = 0.f, ai0 = 0.f, ar1 = 0.f, ai1 = 0.f;
        int idx = 0;   // (kx*xx) & 63, strength-reduced
#pragma unroll 4
        for (int xx = 0; xx < 64; ++xx) {
            float c_ = tw64[2 * idx], s_ = tw64[2 * idx + 1];
            float4 g = *(const float4*)(&gt[xx][kyq * 4]);
            ar0 += g.x * c_ - g.y * s_;  ai0 += g.x * s_ + g.y * c_;
            ar1 += g.z * c_ - g.w * s_;  ai1 += g.z * s_ + g.w * c_;
            idx = (idx + kx) & 63;
        }
        float* fb = F + (size_t)bid * 1024 + kxm * 32 + kyq * 4;
        *(float4*)(fb) = make_float4(ar0, ai0, ar1, ai1);
    }
}

// ---------------- spectral multiply v5 (PROVEN 204us, R7): fine split, no LDS ----------------
// grid (8 e, 16 co-groups, 8 = mq x cih x wsel), block = 4 waves (one co each).
// Thread owns float4 at mode-offset mq*256 + lane*4 of the 512-float (ci,co,wsel)
// chunk; wave reads 1KB contiguous for both W and F. acc[8] = 32 VGPR, VGPR=56.
// ci split in halves -> partials into FoA/FoB (summed in inv).
__global__ __launch_bounds__(256) void spectral_kernel(
    const float* __restrict__ F, float* __restrict__ FoA, float* __restrict__ FoB,
    const float* __restrict__ w1, const float* __restrict__ w2,
    const int* __restrict__ estart, int l)
{
    int e = blockIdx.x;
    int z = blockIdx.z;                       // bit0 = wsel, bit1 = cih, bit2 = mq
    int wsel = z & 1, cih = (z >> 1) & 1, mq = z >> 2;
    int p0 = estart[e], ne = estart[e + 1] - p0;
    if (ne == 0) return;
    int t = threadIdx.x;
    int co = blockIdx.y * 4 + (t >> 6);
    int lane = t & 63;
    int moff = mq * 256 + lane * 4;           // float offset within 512-float chunk

    const float* wbase = (wsel == 0 ? w1 : w2) + (size_t)(e * 4 + l) * 2097152;
    const float* Wc  = wbase + (size_t)(cih * 32) * 32768 + (size_t)co * 512 + moff;
    const float* Fc0 = F + (size_t)p0 * 65536 + (size_t)(cih * 32) * 1024 + wsel * 512 + moff;
    float* Fob = (cih ? FoB : FoA) + (size_t)p0 * 65536 + (size_t)co * 1024 + wsel * 512 + moff;

    for (int pc = 0; pc < ne; pc += 8) {
        int np = ne - pc; if (np > 8) np = 8;
        float4 acc[8];
#pragma unroll
        for (int p = 0; p < 8; ++p) acc[p] = make_float4(0.f, 0.f, 0.f, 0.f);
        const float* Wp = Wc;
        const float* Fp = Fc0 + (size_t)pc * 65536;
        for (int ci = 0; ci < 32; ++ci) {
            float4 wv = LD4(Wp);
#pragma unroll
            for (int p = 0; p < 8; ++p) {
                // p >= np reads in-workspace garbage (never stored) - static indexing
                float4 fv = LD4(Fp + (size_t)p * 65536);
                acc[p].x += fv.x * wv.x - fv.y * wv.y;
                acc[p].y += fv.x * wv.y + fv.y * wv.x;
                acc[p].z += fv.z * wv.z - fv.w * wv.w;
                acc[p].w += fv.z * wv.w + fv.w * wv.z;
            }
            Wp += 32768;
            Fp += 1024;
        }
#pragma unroll
        for (int p = 0; p < 8; ++p) {
            if (p < np)
                *(float4*)(Fob + (size_t)(pc + p) * 65536) = acc[p];
        }
    }
}

// ---------------- 1x1 conv (skip / proj1) ----------------
__global__ __launch_bounds__(256) void conv1x1_kernel(
    const float* __restrict__ src, float* __restrict__ dst,
    const float* __restrict__ Wall, const float* __restrict__ Ball,
    const int* __restrict__ pair_e, int wmul, int wadd, int do_gelu)
{
    int p = blockIdx.x, tile = blockIdx.y, t = threadIdx.x;
    int e = pair_e[p];
    int widx = e * wmul + wadd;
    const float* W = Wall + (size_t)widx * 4096;
    const float* B = Ball + widx * 64;
    const float* s = src + (size_t)p * 262144 + tile * 256 + t;
    float acc[64];
#pragma unroll
    for (int c = 0; c < 64; ++c) acc[c] = 0.f;
    for (int ci = 0; ci < 64; ++ci) {
        float hv = s[(size_t)ci * 4096];
        const float* wr = W + ci * 64;
#pragma unroll
        for (int c = 0; c < 64; ++c) acc[c] += hv * wr[c];
    }
    float* d = dst + (size_t)p * 262144 + tile * 256 + t;
    for (int c = 0; c < 64; ++c) {
        float v = acc[c] + B[c];
        if (do_gelu) v = gelu_f(v);
        d[(size_t)c * 4096] = v;
    }
}

// ---------------- inverse DFT (sums FoA+FoB) + skip-add + gelu ----------------
__global__ __launch_bounds__(256) void inv_kernel(
    const float* __restrict__ FoA, const float* __restrict__ FoB,
    const float* __restrict__ WY2, float* __restrict__ dst_h, int do_gelu)
{
    __shared__ float wy2[2048];
    __shared__ float twl[128];
    __shared__ float fo_s[1024];
    __shared__ float tT[64][36];
    __shared__ float ot[64][66];
    int t = threadIdx.x;
    for (int i = t; i < 512; i += 256) *(float4*)(&wy2[i * 4]) = *(const float4*)(WY2 + i * 4);
    if (t < 64) {
        float a = TWOPI_F * (float)t / 64.f;
        twl[2 * t] = cosf(a);
        twl[2 * t + 1] = sinf(a);
    }
    __syncthreads();

    for (int item = 0; item < 4; ++item) {
        int wid = blockIdx.x * 4 + item;
        int p = wid >> 6, co = wid & 63;
        const float* fA = FoA + (size_t)p * 65536 + (size_t)co * 1024;
        const float* fB = FoB + (size_t)p * 65536 + (size_t)co * 1024;
        {
            float4 a = LD4(fA + t * 4);
            float4 b = LD4(fB + t * 4);
            *(float4*)(&fo_s[t * 4]) = make_float4(a.x + b.x, a.y + b.y, a.z + b.z, a.w + b.w);
        }
        __syncthreads();
        {
            int xx = t & 63, kq = t >> 6;
            float Tr0 = 0.f, Ti0 = 0.f, Tr1 = 0.f, Ti1 = 0.f;
            float Tr2 = 0.f, Ti2 = 0.f, Tr3 = 0.f, Ti3 = 0.f;
#pragma unroll 4
            for (int kxm = 0; kxm < 32; ++kxm) {
                int kx = kxm < 16 ? kxm : kxm + 32;
                int idx = (kx * xx) & 63;
                float c_ = twl[2 * idx], s_ = twl[2 * idx + 1];
                float4 f0 = *(const float4*)(&fo_s[kxm * 32 + kq * 8]);
                float4 f1 = *(const float4*)(&fo_s[kxm * 32 + kq * 8 + 4]);
                Tr0 += f0.x * c_ - f0.y * s_;  Ti0 += f0.x * s_ + f0.y * c_;
                Tr1 += f0.z * c_ - f0.w * s_;  Ti1 += f0.z * s_ + f0.w * c_;
                Tr2 += f1.x * c_ - f1.y * s_;  Ti2 += f1.x * s_ + f1.y * c_;
                Tr3 += f1.z * c_ - f1.w * s_;  Ti3 += f1.z * s_ + f1.w * c_;
            }
            *(float4*)(&tT[xx][kq * 8])     = make_float4(Tr0, Ti0, Tr1, Ti1);
            *(float4*)(&tT[xx][kq * 8 + 4]) = make_float4(Tr2, Ti2, Tr3, Ti3);
        }
        __syncthreads();
        {
            int xx = t & 63, yq = t >> 6;
            float Trr[16], Tii[16];
#pragma unroll
            for (int q = 0; q < 8; ++q) {
                float4 v = *(const float4*)(&tT[xx][q * 4]);
                Trr[q * 2] = v.x; Tii[q * 2] = v.y;
                Trr[q * 2 + 1] = v.z; Tii[q * 2 + 1] = v.w;
            }
            for (int j = 0; j < 16; ++j) {
                int y = yq * 16 + j;
                const float* wr = &wy2[y * 32];
                float acc = 0.f;
#pragma unroll
                for (int k = 0; k < 16; ++k)
                    acc += Trr[k] * wr[2 * k] - Tii[k] * wr[2 * k + 1];
                ot[xx][y] = acc;
            }
        }
        __syncthreads();
        {
            float* base = dst_h + (size_t)p * 262144 + (size_t)co * 4096;
            for (int r = 0; r < 16; ++r) {
                int gidx = r * 256 + t;
                int xx = gidx >> 6, y = gidx & 63;
                float v = base[gidx] + ot[xx][y];
                if (do_gelu) v = gelu_f(v);
                base[gidx] = v;
            }
        }
        __syncthreads();
    }
}

// ---------------- proj2 + weighted accumulate ----------------
__global__ __launch_bounds__(256) void proj2_kernel(
    const float* __restrict__ hsrc, const float* __restrict__ p2w, const float* __restrict__ p2b,
    const int* __restrict__ pair_b, const int* __restrict__ pair_e,
    const float* __restrict__ pw, float* __restrict__ out)
{
    int p = blockIdx.x, tile = blockIdx.y, t = threadIdx.x;
    int b = pair_b[p], e = pair_e[p];
    float wgt = pw[p];
    const float* h = hsrc + (size_t)p * 262144 + tile * 256 + t;
    const float* w2 = p2w + e * 64;
    float acc = p2b[e];
#pragma unroll
    for (int c = 0; c < 64; ++c) acc += h[(size_t)c * 4096] * w2[c];
    atomicAdd(out + (size_t)b * 4096 + tile * 256 + t, wgt * acc);
}

// ---------------- launch ----------------
extern "C" void kernel_launch(void* const* d_in, const int* in_sizes, int n_in,
                              void* d_out, int out_size, void* d_ws, size_t ws_size,
                              hipStream_t stream) {
    const float* x    = (const float*)d_in[0];
    const float* encw = (const float*)d_in[1];
    const float* encb = (const float*)d_in[2];
    const float* wqkv = (const float*)d_in[3];
    const float* bqkv = (const float*)d_in[4];
    const float* wo   = (const float*)d_in[5];
    const float* bo   = (const float*)d_in[6];
    const float* ln1g = (const float*)d_in[7];
    const float* ln1b = (const float*)d_in[8];
    const float* fw1  = (const float*)d_in[9];
    const float* fb1  = (const float*)d_in[10];
    const float* fw2  = (const float*)d_in[11];
    const float* fb2  = (const float*)d_in[12];
    const float* ln2g = (const float*)d_in[13];
    const float* ln2b = (const float*)d_in[14];
    const float* fcw  = (const float*)d_in[15];
    const float* fcb  = (const float*)d_in[16];
    const float* lw   = (const float*)d_in[17];
    const float* lb   = (const float*)d_in[18];
    const float* sw1  = (const float*)d_in[19];
    const float* sw2  = (const float*)d_in[20];
    const float* skw  = (const float*)d_in[21];
    const float* skb  = (const float*)d_in[22];
    const float* p1w  = (const float*)d_in[23];
    const float* p1b  = (const float*)d_in[24];
    const float* p2w  = (const float*)d_in[25];
    const float* p2b  = (const float*)d_in[26];
    float* out = (float*)d_out;

    float* wsf    = (float*)d_ws;
    float* rw     = wsf;               // 256
    float* pair_w = wsf + 256;         // 64
    int*   ipart  = (int*)(wsf + 320);
    int* pair_b = ipart;               // 64
    int* pair_e = ipart + 64;          // 64
    int* estart = ipart + 128;         // 9
    float* Wy  = wsf + 512;            // 2048
    float* TWX = wsf + 2560;           // 4096 (kept for layout compat; unused)
    float* WY2 = wsf + 6656;           // 2048
    float* hA  = wsf + 16384;                       // 64 * 262144
    float* hB  = hA + (size_t)64 * 262144;          // 64 * 262144
    float* F   = hB + (size_t)64 * 262144;          // 64 * 65536
    float* FoA = F + (size_t)64 * 65536;            // 64 * 65536
    float* FoB = FoA + (size_t)64 * 65536;          // 64 * 65536
    size_t need = (16384 + 2ull * 64 * 262144 + 64ull * 65536 + 64ull * 131072) * 4;
    if (ws_size < need) return;

    hipMemsetAsync(d_out, 0, (size_t)out_size * sizeof(float), stream);
    init_tables_kernel<<<1, 256, 0, stream>>>(Wy, TWX, WY2);
    router_kernel<<<32, 512, 0, stream>>>(x, encw, encb, wqkv, bqkv, wo, bo, ln1g, ln1b,
                                          fw1, fb1, fw2, fb2, ln2g, ln2b, fcw, fcb, rw);
    build_pairs_kernel<<<1, 64, 0, stream>>>(rw, pair_b, pair_e, pair_w, estart);
    lift_kernel<<<dim3(64, 16), 256, 0, stream>>>(x, lw, lb, pair_b, pair_e, hA);
    for (int l = 0; l < 4; ++l) {
        float* cur = (l & 1) ? hB : hA;
        float* nxt = (l & 1) ? hA : hB;
        fwdft_kernel<<<4096, 256, 0, stream>>>(cur, Wy, F);
        spectral_kernel<<<dim3(8, 16, 8), 256, 0, stream>>>(F, FoA, FoB, sw1, sw2, estart, l);
        conv1x1_kernel<<<dim3(64, 16), 256, 0, stream>>>(cur, nxt, skw, skb, pair_e, 4, l, 0);
        inv_kernel<<<1024, 256, 0, stream>>>(FoA, FoB, WY2, nxt, (l < 3) ? 1 : 0);
    }
    conv1x1_kernel<<<dim3(64, 16), 256, 0, stream>>>(hA, hB, p1w, p1b, pair_e, 1, 0, 1);
    proj2_kernel<<<dim3(64, 16), 256, 0, stream>>>(hB, p2w, p2b, pair_b, pair_e, pair_w, out);
}

// Round 14
// 1998.501 us; speedup vs baseline: 5.6863x; 1.1428x over previous
//
#include <hip/hip_runtime.h>
#include <math.h>

#define TWOPI_F 6.283185307179586f
#define LD4(p) (*(const float4*)(p))

__device__ __forceinline__ float gelu_f(float v) {
    float u = 0.7978845608028654f * (v + 0.044715f * v * v * v);
    return 0.5f * v * (1.f + tanhf(u));
}

// ---------------- twiddle tables ----------------
__global__ void init_tables_kernel(float* __restrict__ Wy, float* __restrict__ TWX,
                                   float* __restrict__ WY2) {
    int t = threadIdx.x;
    for (int i = t; i < 1024; i += 256) {
        int y = i >> 4, k = i & 15;
        int m = (k * y) & 63;
        float a = -TWOPI_F * (float)m / 64.f;
        Wy[y * 32 + 2 * k]     = cosf(a);
        Wy[y * 32 + 2 * k + 1] = sinf(a);
    }
    for (int i = t; i < 2048; i += 256) {
        int x = i >> 5, kxm = i & 31;
        int kx = kxm < 16 ? kxm : kxm + 32;
        int m = (kx * x) & 63;
        float a = -TWOPI_F * (float)m / 64.f;
        TWX[x * 64 + 2 * kxm]     = cosf(a);
        TWX[x * 64 + 2 * kxm + 1] = sinf(a);
    }
    for (int i = t; i < 1024; i += 256) {
        int y = i >> 4, k = i & 15;
        int m = (k * y) & 63;
        float a = TWOPI_F * (float)m / 64.f;
        float sc = (k == 0 ? 1.f : 2.f) / 4096.f;
        WY2[y * 32 + 2 * k]     = sc * cosf(a);
        WY2[y * 32 + 2 * k + 1] = sc * sinf(a);
    }
}

// ---------------- router v3: weight-reuse layout (col-group x row-group) ----------------
__global__ __launch_bounds__(512) void router_kernel(
    const float* __restrict__ x, const float* __restrict__ enc_w, const float* __restrict__ enc_b,
    const float* __restrict__ wqkv, const float* __restrict__ bqkv,
    const float* __restrict__ wo, const float* __restrict__ bo,
    const float* __restrict__ ln1g, const float* __restrict__ ln1b,
    const float* __restrict__ w1, const float* __restrict__ b1,
    const float* __restrict__ w2, const float* __restrict__ b2,
    const float* __restrict__ ln2g, const float* __restrict__ ln2b,
    const float* __restrict__ fcw, const float* __restrict__ fcb,
    float* __restrict__ rw)
{
    __shared__ float s[64][65];
    __shared__ float qk[64][193];
    __shared__ float sc[64][65];
    __shared__ float o64[64][65];
    __shared__ float feat[64];
    __shared__ float logits[8];
    int b = blockIdx.x, t = threadIdx.x;

    for (int i = t; i < 4096; i += 512) {
        int w_ = i >> 6, d = i & 63;
        s[w_][d] = x[b * 4096 + w_] * enc_w[d] + enc_b[d];
    }
    __syncthreads();

    for (int l = 0; l < 2; ++l) {
        {
            const float* Wq = wqkv + l * 64 * 192;
            const float* Bq = bqkv + l * 192;
            int c4 = t % 48, rg = t / 48;
            if (rg < 8) {
                const float* wcol = Wq + 4 * c4;
                float4 bq = LD4(Bq + 4 * c4);
                float4 acc[8];
#pragma unroll
                for (int i = 0; i < 8; ++i) acc[i] = bq;
                int r0 = rg * 8;
#pragma unroll 8
                for (int k = 0; k < 64; ++k) {
                    float4 wv = LD4(wcol + k * 192);
#pragma unroll
                    for (int i = 0; i < 8; ++i) {
                        float sv = s[r0 + i][k];
                        acc[i].x += sv * wv.x; acc[i].y += sv * wv.y;
                        acc[i].z += sv * wv.z; acc[i].w += sv * wv.w;
                    }
                }
#pragma unroll
                for (int i = 0; i < 8; ++i) {
                    qk[r0 + i][4 * c4]     = acc[i].x;
                    qk[r0 + i][4 * c4 + 1] = acc[i].y;
                    qk[r0 + i][4 * c4 + 2] = acc[i].z;
                    qk[r0 + i][4 * c4 + 3] = acc[i].w;
                }
            }
        }
        __syncthreads();
        for (int h = 0; h < 4; ++h) {
            for (int i = t; i < 4096; i += 512) {
                int q = i >> 6, kj = i & 63;
                float acc = 0.f;
#pragma unroll
                for (int d = 0; d < 16; ++d)
                    acc += qk[q][h * 16 + d] * qk[kj][64 + h * 16 + d];
                sc[q][kj] = acc * 0.25f;
            }
            __syncthreads();
            if (t < 64) {
                float m = -1e30f;
                for (int j = 0; j < 64; ++j) m = fmaxf(m, sc[t][j]);
                float sum = 0.f;
                for (int j = 0; j < 64; ++j) { float e2 = expf(sc[t][j] - m); sc[t][j] = e2; sum += e2; }
                float inv = 1.f / sum;
                for (int j = 0; j < 64; ++j) sc[t][j] *= inv;
            }
            __syncthreads();
            for (int i = t; i < 1024; i += 512) {
                int q = i >> 4, d = i & 15;
                float acc = 0.f;
#pragma unroll 8
                for (int j = 0; j < 64; ++j) acc += sc[q][j] * qk[j][128 + h * 16 + d];
                o64[q][h * 16 + d] = acc;
            }
            __syncthreads();
        }
        {
            const float* Wo = wo + l * 4096;
            const float* Bo = bo + l * 64;
            int c4 = t & 15, rg = t >> 4;
            const float* wcol = Wo + 4 * c4;
            float4 acc0 = LD4(Bo + 4 * c4), acc1 = acc0;
            int r0 = rg * 2;
#pragma unroll 8
            for (int k = 0; k < 64; ++k) {
                float4 wv = LD4(wcol + k * 64);
                float h0 = o64[r0][k], h1 = o64[r0 + 1][k];
                acc0.x += h0 * wv.x; acc0.y += h0 * wv.y;
                acc0.z += h0 * wv.z; acc0.w += h0 * wv.w;
                acc1.x += h1 * wv.x; acc1.y += h1 * wv.y;
                acc1.z += h1 * wv.z; acc1.w += h1 * wv.w;
            }
            sc[r0][4 * c4]     = s[r0][4 * c4]     + acc0.x;
            sc[r0][4 * c4 + 1] = s[r0][4 * c4 + 1] + acc0.y;
            sc[r0][4 * c4 + 2] = s[r0][4 * c4 + 2] + acc0.z;
            sc[r0][4 * c4 + 3] = s[r0][4 * c4 + 3] + acc0.w;
            sc[r0 + 1][4 * c4]     = s[r0 + 1][4 * c4]     + acc1.x;
            sc[r0 + 1][4 * c4 + 1] = s[r0 + 1][4 * c4 + 1] + acc1.y;
            sc[r0 + 1][4 * c4 + 2] = s[r0 + 1][4 * c4 + 2] + acc1.z;
            sc[r0 + 1][4 * c4 + 3] = s[r0 + 1][4 * c4 + 3] + acc1.w;
        }
        __syncthreads();
        if (t < 64) {
            float m = 0.f;
            for (int j = 0; j < 64; ++j) m += sc[t][j];
            m *= (1.f / 64.f);
            float v = 0.f;
            for (int j = 0; j < 64; ++j) { float d = sc[t][j] - m; v += d * d; }
            v *= (1.f / 64.f);
            float inv = rsqrtf(v + 1e-5f);
            for (int j = 0; j < 64; ++j)
                s[t][j] = (sc[t][j] - m) * inv * ln1g[l * 64 + j] + ln1b[l * 64 + j];
        }
        __syncthreads();
        {
            const float* W1 = w1 + l * 64 * 256;
            const float* B1 = b1 + l * 256;
            int c4 = t & 63, rg = t >> 6;
            const float* wcol = W1 + 4 * c4;
            float4 b1v = LD4(B1 + 4 * c4);
            float4 acc[8];
#pragma unroll
            for (int i = 0; i < 8; ++i) acc[i] = b1v;
            int r0 = rg * 8;
#pragma unroll 4
            for (int k = 0; k < 64; ++k) {
                float4 wv = LD4(wcol + k * 256);
#pragma unroll
                for (int i = 0; i < 8; ++i) {
                    float sv = s[r0 + i][k];
                    acc[i].x += sv * wv.x; acc[i].y += sv * wv.y;
                    acc[i].z += sv * wv.z; acc[i].w += sv * wv.w;
                }
            }
#pragma unroll
            for (int i = 0; i < 8; ++i) {
                float a0 = fmaxf(acc[i].x, 0.f), a1 = fmaxf(acc[i].y, 0.f);
                float a2 = fmaxf(acc[i].z, 0.f), a3 = fmaxf(acc[i].w, 0.f);
                if (c4 < 48) {
                    qk[r0 + i][4 * c4] = a0; qk[r0 + i][4 * c4 + 1] = a1;
                    qk[r0 + i][4 * c4 + 2] = a2; qk[r0 + i][4 * c4 + 3] = a3;
                } else {
                    int c = 4 * c4 - 192;
                    o64[r0 + i][c] = a0; o64[r0 + i][c + 1] = a1;
                    o64[r0 + i][c + 2] = a2; o64[r0 + i][c + 3] = a3;
                }
            }
        }
        __syncthreads();
        {
            const float* W2 = w2 + l * 256 * 64;
            const float* B2 = b2 + l * 64;
            int c4 = t & 15, rg = t >> 4;
            const float* wcol = W2 + 4 * c4;
            float4 acc0 = LD4(B2 + 4 * c4), acc1 = acc0;
            int r0 = rg * 2;
#pragma unroll 8
            for (int k = 0; k < 192; ++k) {
                float4 wv = LD4(wcol + k * 64);
                float h0 = qk[r0][k], h1 = qk[r0 + 1][k];
                acc0.x += h0 * wv.x; acc0.y += h0 * wv.y;
                acc0.z += h0 * wv.z; acc0.w += h0 * wv.w;
                acc1.x += h1 * wv.x; acc1.y += h1 * wv.y;
                acc1.z += h1 * wv.z; acc1.w += h1 * wv.w;
            }
#pragma unroll 8
            for (int k = 192; k < 256; ++k) {
                float4 wv = LD4(wcol + k * 64);
                float h0 = o64[r0][k - 192], h1 = o64[r0 + 1][k - 192];
                acc0.x += h0 * wv.x; acc0.y += h0 * wv.y;
                acc0.z += h0 * wv.z; acc0.w += h0 * wv.w;
                acc1.x += h1 * wv.x; acc1.y += h1 * wv.y;
                acc1.z += h1 * wv.z; acc1.w += h1 * wv.w;
            }
            sc[r0][4 * c4]     = s[r0][4 * c4]     + acc0.x;
            sc[r0][4 * c4 + 1] = s[r0][4 * c4 + 1] + acc0.y;
            sc[r0][4 * c4 + 2] = s[r0][4 * c4 + 2] + acc0.z;
            sc[r0][4 * c4 + 3] = s[r0][4 * c4 + 3] + acc0.w;
            sc[r0 + 1][4 * c4]     = s[r0 + 1][4 * c4]     + acc1.x;
            sc[r0 + 1][4 * c4 + 1] = s[r0 + 1][4 * c4 + 1] + acc1.y;
            sc[r0 + 1][4 * c4 + 2] = s[r0 + 1][4 * c4 + 2] + acc1.z;
            sc[r0 + 1][4 * c4 + 3] = s[r0 + 1][4 * c4 + 3] + acc1.w;
        }
        __syncthreads();
        if (t < 64) {
            float m = 0.f;
            for (int j = 0; j < 64; ++j) m += sc[t][j];
            m *= (1.f / 64.f);
            float v = 0.f;
            for (int j = 0; j < 64; ++j) { float d = sc[t][j] - m; v += d * d; }
            v *= (1.f / 64.f);
            float inv = rsqrtf(v + 1e-5f);
            for (int j = 0; j < 64; ++j)
                s[t][j] = (sc[t][j] - m) * inv * ln2g[l * 64 + j] + ln2b[l * 64 + j];
        }
        __syncthreads();
    }
    if (t < 64) {
        float m = -1e30f;
        for (int r = 0; r < 64; ++r) m = fmaxf(m, s[r][t]);
        feat[t] = m;
    }
    __syncthreads();
    if (t < 8) {
        float acc = fcb[t];
        for (int k = 0; k < 64; ++k) acc += feat[k] * fcw[k * 8 + t];
        logits[t] = acc;
    }
    __syncthreads();
    if (t == 0) {
        int i0 = 0;
        for (int j = 1; j < 8; ++j) if (logits[j] > logits[i0]) i0 = j;
        int i1 = -1;
        for (int j = 0; j < 8; ++j) {
            if (j == i0) continue;
            if (i1 < 0 || logits[j] > logits[i1]) i1 = j;
        }
        float e1 = expf(logits[i1] - logits[i0]);
        float w0 = 1.f / (1.f + e1);
        float w1v = e1 / (1.f + e1);
        for (int j = 0; j < 8; ++j) rw[b * 8 + j] = 0.f;
        rw[b * 8 + i0] = w0;
        rw[b * 8 + i1] = w1v;
    }
}

// ---------------- build pairs + balanced chunk table ----------------
__global__ void build_pairs_kernel(const float* __restrict__ rw, int* __restrict__ pair_b,
                                   int* __restrict__ pair_e, float* __restrict__ pair_w,
                                   int* __restrict__ estart, int* __restrict__ chunk_e,
                                   int* __restrict__ chunk_p0, int* __restrict__ chunk_np) {
    __shared__ float r[256];
    __shared__ int cnt[8], off[9];
    int t = threadIdx.x;
    for (int i = t; i < 256; i += 64) r[i] = rw[i];
    if (t < 64) { pair_b[t] = 0; pair_e[t] = 0; pair_w[t] = 0.f; }
    __syncthreads();
    if (t < 8) {
        int c = 0;
        for (int b = 0; b < 32; ++b) if (r[b * 8 + t] != 0.f) ++c;
        cnt[t] = c;
    }
    __syncthreads();
    if (t == 0) {
        int a = 0;
        for (int e = 0; e < 8; ++e) { off[e] = a; a += cnt[e]; }
        off[8] = a;
        for (int e = 0; e <= 8; ++e) estart[e] = off[e];
        // chunk table: one entry per <=8-pair slice of each expert (<=15 total)
        int nc = 0;
        for (int e = 0; e < 8; ++e) {
            for (int s = off[e]; s < off[e + 1]; s += 8) {
                int np = off[e + 1] - s; if (np > 8) np = 8;
                chunk_e[nc] = e; chunk_p0[nc] = s; chunk_np[nc] = np; ++nc;
            }
        }
        for (int c = nc; c < 16; ++c) { chunk_e[c] = 0; chunk_p0[c] = 0; chunk_np[c] = 0; }
    }
    __syncthreads();
    if (t < 8) {
        int n = off[t];
        for (int b = 0; b < 32; ++b) {
            float w = r[b * 8 + t];
            if (w != 0.f) { pair_b[n] = b; pair_e[n] = t; pair_w[n] = w; ++n; }
        }
    }
}

// ---------------- lift ----------------
__global__ __launch_bounds__(256) void lift_kernel(const float* __restrict__ x,
    const float* __restrict__ lw, const float* __restrict__ lb,
    const int* __restrict__ pair_b, const int* __restrict__ pair_e, float* __restrict__ hA) {
    int p = blockIdx.x, tile = blockIdx.y, t = threadIdx.x;
    int b = pair_b[p], e = pair_e[p];
    float* h = hA + (size_t)p * 262144;
    const float* xb = x + (size_t)b * 4096;
    for (int i = tile * 16384 + t; i < (tile + 1) * 16384; i += 256) {
        int co = i >> 12, xy = i & 4095;
        h[i] = xb[xy] * lw[e * 64 + co] + lb[e * 64 + co];
    }
}

// ---------------- fused forward DFT v2 ----------------
__global__ __launch_bounds__(256) void fwdft_kernel(const float* __restrict__ h,
    const float* __restrict__ Wy, float* __restrict__ F) {
    __shared__ float ht[64][68];
    __shared__ float gt[64][36];
    __shared__ float wy[2048];
    __shared__ float tw64[128];
    int bid = blockIdx.x;
    int t = threadIdx.x;
    const float* src = h + (size_t)bid * 4096;
    for (int i = t; i < 1024; i += 256) {
        float4 v = *(const float4*)(src + i * 4);
        int x = (i * 4) >> 6, y = (i * 4) & 63;
        *(float4*)(&ht[x][y]) = v;
    }
    for (int i = t; i < 512; i += 256) *(float4*)(&wy[i * 4]) = *(const float4*)(Wy + i * 4);
    if (t < 64) {
        float a = -TWOPI_F * (float)t / 64.f;
        tw64[2 * t]     = cosf(a);
        tw64[2 * t + 1] = sinf(a);
    }
    __syncthreads();
    {
        int xx = t >> 2, kq = t & 3;
        float gr0 = 0.f, gi0 = 0.f, gr1 = 0.f, gi1 = 0.f;
        float gr2 = 0.f, gi2 = 0.f, gr3 = 0.f, gi3 = 0.f;
#pragma unroll 4
        for (int y = 0; y < 64; ++y) {
            float hv = ht[xx][y];
            float4 w0 = *(const float4*)(&wy[y * 32 + kq * 8]);
            float4 w1 = *(const float4*)(&wy[y * 32 + kq * 8 + 4]);
            gr0 += hv * w0.x; gi0 += hv * w0.y;
            gr1 += hv * w0.z; gi1 += hv * w0.w;
            gr2 += hv * w1.x; gi2 += hv * w1.y;
            gr3 += hv * w1.z; gi3 += hv * w1.w;
        }
        *(float4*)(&gt[xx][kq * 8])     = make_float4(gr0, gi0, gr1, gi1);
        *(float4*)(&gt[xx][kq * 8 + 4]) = make_float4(gr2, gi2, gr3, gi3);
    }
    __syncthreads();
    {
        int kxm = t & 31, kyq = t >> 5;
        int kx = kxm < 16 ? kxm : kxm + 32;
        float ar0 = 0.f, ai0 = 0.f, ar1 = 0.f, ai1 = 0.f;
        int idx = 0;
#pragma unroll 4
        for (int xx = 0; xx < 64; ++xx) {
            float c_ = tw64[2 * idx], s_ = tw64[2 * idx + 1];
            float4 g = *(const float4*)(&gt[xx][kyq * 4]);
            ar0 += g.x * c_ - g.y * s_;  ai0 += g.x * s_ + g.y * c_;
            ar1 += g.z * c_ - g.w * s_;  ai1 += g.z * s_ + g.w * c_;
            idx = (idx + kx) & 63;
        }
        float* fb = F + (size_t)bid * 1024 + kxm * 32 + kyq * 4;
        *(float4*)(fb) = make_float4(ar0, ai0, ar1, ai1);
    }
}

// ---------------- spectral v11: chunk-balanced v5 ----------------
// grid (16 chunks, 16 co-groups, 8 = mq x cih x wsel); each block = ONE uniform
// 8-pair chunk (from chunk table) -> no expert load imbalance, no tail.
// Body identical to proven v5 (acc[8], no manual buffering, no min-waves bound).
__global__ __launch_bounds__(256) void spectral_kernel(
    const float* __restrict__ F, float* __restrict__ FoA, float* __restrict__ FoB,
    const float* __restrict__ w1, const float* __restrict__ w2,
    const int* __restrict__ chunk_e, const int* __restrict__ chunk_p0,
    const int* __restrict__ chunk_np, int l)
{
    int c = blockIdx.x;
    int np = chunk_np[c];
    if (np == 0) return;
    int e = chunk_e[c], p0 = chunk_p0[c];
    int z = blockIdx.z;
    int wsel = z & 1, cih = (z >> 1) & 1, mq = z >> 2;
    int t = threadIdx.x;
    int co = blockIdx.y * 4 + (t >> 6);
    int lane = t & 63;
    int moff = mq * 256 + lane * 4;

    const float* wbase = (wsel == 0 ? w1 : w2) + (size_t)(e * 4 + l) * 2097152;
    const float* Wc  = wbase + (size_t)(cih * 32) * 32768 + (size_t)co * 512 + moff;
    const float* Fc0 = F + (size_t)p0 * 65536 + (size_t)(cih * 32) * 1024 + wsel * 512 + moff;
    float* Fob = (cih ? FoB : FoA) + (size_t)p0 * 65536 + (size_t)co * 1024 + wsel * 512 + moff;

    float4 acc[8];
#pragma unroll
    for (int p = 0; p < 8; ++p) acc[p] = make_float4(0.f, 0.f, 0.f, 0.f);
    const float* Wp = Wc;
    const float* Fp = Fc0;
    for (int ci = 0; ci < 32; ++ci) {
        float4 wv = LD4(Wp);
#pragma unroll
        for (int p = 0; p < 8; ++p) {
            // p >= np reads adjacent workspace garbage (never stored) - static idx
            float4 fv = LD4(Fp + (size_t)p * 65536);
            acc[p].x += fv.x * wv.x - fv.y * wv.y;
            acc[p].y += fv.x * wv.y + fv.y * wv.x;
            acc[p].z += fv.z * wv.z - fv.w * wv.w;
            acc[p].w += fv.z * wv.w + fv.w * wv.z;
        }
        Wp += 32768;
        Fp += 1024;
    }
#pragma unroll
    for (int p = 0; p < 8; ++p) {
        if (p < np)
            *(float4*)(Fob + (size_t)(p + 0) * 65536) = acc[p];
    }
}

// ---------------- 1x1 conv (skip / proj1) ----------------
__global__ __launch_bounds__(256) void conv1x1_kernel(
    const float* __restrict__ src, float* __restrict__ dst,
    const float* __restrict__ Wall, const float* __restrict__ Ball,
    const int* __restrict__ pair_e, int wmul, int wadd, int do_gelu)
{
    int p = blockIdx.x, tile = blockIdx.y, t = threadIdx.x;
    int e = pair_e[p];
    int widx = e * wmul + wadd;
    const float* W = Wall + (size_t)widx * 4096;
    const float* B = Ball + widx * 64;
    const float* s = src + (size_t)p * 262144 + tile * 256 + t;
    float acc[64];
#pragma unroll
    for (int c = 0; c < 64; ++c) acc[c] = 0.f;
    for (int ci = 0; ci < 64; ++ci) {
        float hv = s[(size_t)ci * 4096];
        const float* wr = W + ci * 64;
#pragma unroll
        for (int c = 0; c < 64; ++c) acc[c] += hv * wr[c];
    }
    float* d = dst + (size_t)p * 262144 + tile * 256 + t;
    for (int c = 0; c < 64; ++c) {
        float v = acc[c] + B[c];
        if (do_gelu) v = gelu_f(v);
        d[(size_t)c * 4096] = v;
    }
}

// ---------------- inverse DFT (sums FoA+FoB) + skip-add + gelu ----------------
__global__ __launch_bounds__(256) void inv_kernel(
    const float* __restrict__ FoA, const float* __restrict__ FoB,
    const float* __restrict__ WY2, float* __restrict__ dst_h, int do_gelu)
{
    __shared__ float wy2[2048];
    __shared__ float twl[128];
    __shared__ float fo_s[1024];
    __shared__ float tT[64][36];
    __shared__ float ot[64][66];
    int t = threadIdx.x;
    for (int i = t; i < 512; i += 256) *(float4*)(&wy2[i * 4]) = *(const float4*)(WY2 + i * 4);
    if (t < 64) {
        float a = TWOPI_F * (float)t / 64.f;
        twl[2 * t] = cosf(a);
        twl[2 * t + 1] = sinf(a);
    }
    __syncthreads();

    for (int item = 0; item < 4; ++item) {
        int wid = blockIdx.x * 4 + item;
        int p = wid >> 6, co = wid & 63;
        const float* fA = FoA + (size_t)p * 65536 + (size_t)co * 1024;
        const float* fB = FoB + (size_t)p * 65536 + (size_t)co * 1024;
        {
            float4 a = LD4(fA + t * 4);
            float4 b = LD4(fB + t * 4);
            *(float4*)(&fo_s[t * 4]) = make_float4(a.x + b.x, a.y + b.y, a.z + b.z, a.w + b.w);
        }
        __syncthreads();
        {
            int xx = t & 63, kq = t >> 6;
            float Tr0 = 0.f, Ti0 = 0.f, Tr1 = 0.f, Ti1 = 0.f;
            float Tr2 = 0.f, Ti2 = 0.f, Tr3 = 0.f, Ti3 = 0.f;
#pragma unroll 4
            for (int kxm = 0; kxm < 32; ++kxm) {
                int kx = kxm < 16 ? kxm : kxm + 32;
                int idx = (kx * xx) & 63;
                float c_ = twl[2 * idx], s_ = twl[2 * idx + 1];
                float4 f0 = *(const float4*)(&fo_s[kxm * 32 + kq * 8]);
                float4 f1 = *(const float4*)(&fo_s[kxm * 32 + kq * 8 + 4]);
                Tr0 += f0.x * c_ - f0.y * s_;  Ti0 += f0.x * s_ + f0.y * c_;
                Tr1 += f0.z * c_ - f0.w * s_;  Ti1 += f0.z * s_ + f0.w * c_;
                Tr2 += f1.x * c_ - f1.y * s_;  Ti2 += f1.x * s_ + f1.y * c_;
                Tr3 += f1.z * c_ - f1.w * s_;  Ti3 += f1.z * s_ + f1.w * c_;
            }
            *(float4*)(&tT[xx][kq * 8])     = make_float4(Tr0, Ti0, Tr1, Ti1);
            *(float4*)(&tT[xx][kq * 8 + 4]) = make_float4(Tr2, Ti2, Tr3, Ti3);
        }
        __syncthreads();
        {
            int xx = t & 63, yq = t >> 6;
            float Trr[16], Tii[16];
#pragma unroll
            for (int q = 0; q < 8; ++q) {
                float4 v = *(const float4*)(&tT[xx][q * 4]);
                Trr[q * 2] = v.x; Tii[q * 2] = v.y;
                Trr[q * 2 + 1] = v.z; Tii[q * 2 + 1] = v.w;
            }
            for (int j = 0; j < 16; ++j) {
                int y = yq * 16 + j;
                const float* wr = &wy2[y * 32];
                float acc = 0.f;
#pragma unroll
                for (int k = 0; k < 16; ++k)
                    acc += Trr[k] * wr[2 * k] - Tii[k] * wr[2 * k + 1];
                ot[xx][y] = acc;
            }
        }
        __syncthreads();
        {
            float* base = dst_h + (size_t)p * 262144 + (size_t)co * 4096;
            for (int r = 0; r < 16; ++r) {
                int gidx = r * 256 + t;
                int xx = gidx >> 6, y = gidx & 63;
                float v = base[gidx] + ot[xx][y];
                if (do_gelu) v = gelu_f(v);
                base[gidx] = v;
            }
        }
        __syncthreads();
    }
}

// ---------------- proj2 + weighted accumulate ----------------
__global__ __launch_bounds__(256) void proj2_kernel(
    const float* __restrict__ hsrc, const float* __restrict__ p2w, const float* __restrict__ p2b,
    const int* __restrict__ pair_b, const int* __restrict__ pair_e,
    const float* __restrict__ pw, float* __restrict__ out)
{
    int p = blockIdx.x, tile = blockIdx.y, t = threadIdx.x;
    int b = pair_b[p], e = pair_e[p];
    float wgt = pw[p];
    const float* h = hsrc + (size_t)p * 262144 + tile * 256 + t;
    const float* w2 = p2w + e * 64;
    float acc = p2b[e];
#pragma unroll
    for (int c = 0; c < 64; ++c) acc += h[(size_t)c * 4096] * w2[c];
    atomicAdd(out + (size_t)b * 4096 + tile * 256 + t, wgt * acc);
}

// ---------------- launch ----------------
extern "C" void kernel_launch(void* const* d_in, const int* in_sizes, int n_in,
                              void* d_out, int out_size, void* d_ws, size_t ws_size,
                              hipStream_t stream) {
    const float* x    = (const float*)d_in[0];
    const float* encw = (const float*)d_in[1];
    const float* encb = (const float*)d_in[2];
    const float* wqkv = (const float*)d_in[3];
    const float* bqkv = (const float*)d_in[4];
    const float* wo   = (const float*)d_in[5];
    const float* bo   = (const float*)d_in[6];
    const float* ln1g = (const float*)d_in[7];
    const float* ln1b = (const float*)d_in[8];
    const float* fw1  = (const float*)d_in[9];
    const float* fb1  = (const float*)d_in[10];
    const float* fw2  = (const float*)d_in[11];
    const float* fb2  = (const float*)d_in[12];
    const float* ln2g = (const float*)d_in[13];
    const float* ln2b = (const float*)d_in[14];
    const float* fcw  = (const float*)d_in[15];
    const float* fcb  = (const float*)d_in[16];
    const float* lw   = (const float*)d_in[17];
    const float* lb   = (const float*)d_in[18];
    const float* sw1  = (const float*)d_in[19];
    const float* sw2  = (const float*)d_in[20];
    const float* skw  = (const float*)d_in[21];
    const float* skb  = (const float*)d_in[22];
    const float* p1w  = (const float*)d_in[23];
    const float* p1b  = (const float*)d_in[24];
    const float* p2w  = (const float*)d_in[25];
    const float* p2b  = (const float*)d_in[26];
    float* out = (float*)d_out;

    float* wsf    = (float*)d_ws;
    float* rw     = wsf;               // 256
    float* pair_w = wsf + 256;         // 64
    int*   ipart  = (int*)(wsf + 320); // 192 ints available
    int* pair_b   = ipart;             // 64
    int* pair_e   = ipart + 64;        // 64
    int* estart   = ipart + 128;       // 9
    int* chunk_e  = ipart + 137;       // 16
    int* chunk_p0 = ipart + 153;       // 16
    int* chunk_np = ipart + 169;       // 16 (ends 185 < 192)
    float* Wy  = wsf + 512;            // 2048
    float* TWX = wsf + 2560;           // 4096 (unused, layout compat)
    float* WY2 = wsf + 6656;           // 2048
    float* hA  = wsf + 16384;                       // 64 * 262144
    float* hB  = hA + (size_t)64 * 262144;          // 64 * 262144
    float* F   = hB + (size_t)64 * 262144;          // 64 * 65536
    float* FoA = F + (size_t)64 * 65536;            // 64 * 65536
    float* FoB = FoA + (size_t)64 * 65536;          // 64 * 65536
    size_t need = (16384 + 2ull * 64 * 262144 + 64ull * 65536 + 64ull * 131072) * 4;
    if (ws_size < need) return;

    hipMemsetAsync(d_out, 0, (size_t)out_size * sizeof(float), stream);
    init_tables_kernel<<<1, 256, 0, stream>>>(Wy, TWX, WY2);
    router_kernel<<<32, 512, 0, stream>>>(x, encw, encb, wqkv, bqkv, wo, bo, ln1g, ln1b,
                                          fw1, fb1, fw2, fb2, ln2g, ln2b, fcw, fcb, rw);
    build_pairs_kernel<<<1, 64, 0, stream>>>(rw, pair_b, pair_e, pair_w, estart,
                                             chunk_e, chunk_p0, chunk_np);
    lift_kernel<<<dim3(64, 16), 256, 0, stream>>>(x, lw, lb, pair_b, pair_e, hA);
    for (int l = 0; l < 4; ++l) {
        float* cur = (l & 1) ? hB : hA;
        float* nxt = (l & 1) ? hA : hB;
        fwdft_kernel<<<4096, 256, 0, stream>>>(cur, Wy, F);
        spectral_kernel<<<dim3(16, 16, 8), 256, 0, stream>>>(F, FoA, FoB, sw1, sw2,
                                                             chunk_e, chunk_p0, chunk_np, l);
        conv1x1_kernel<<<dim3(64, 16), 256, 0, stream>>>(cur, nxt, skw, skb, pair_e, 4, l, 0);
        inv_kernel<<<1024, 256, 0, stream>>>(FoA, FoB, WY2, nxt, (l < 3) ? 1 : 0);
    }
    conv1x1_kernel<<<dim3(64, 16), 256, 0, stream>>>(hA, hB, p1w, p1b, pair_e, 1, 0, 1);
    proj2_kernel<<<dim3(64, 16), 256, 0, stream>>>(hB, p2w, p2b, pair_b, pair_e, pair_w, out);
}

// Round 15
// 1422.345 us; speedup vs baseline: 7.9896x; 1.4051x over previous
//
#include <hip/hip_runtime.h>
#include <math.h>

#define TWOPI_F 6.283185307179586f
#define LD4(p) (*(const float4*)(p))

__device__ __forceinline__ float gelu_f(float v) {
    float u = 0.7978845608028654f * (v + 0.044715f * v * v * v);
    return 0.5f * v * (1.f + tanhf(u));
}

// ---------------- twiddle tables ----------------
__global__ void init_tables_kernel(float* __restrict__ Wy, float* __restrict__ TWX,
                                   float* __restrict__ WY2) {
    int t = threadIdx.x;
    for (int i = t; i < 1024; i += 256) {
        int y = i >> 4, k = i & 15;
        int m = (k * y) & 63;
        float a = -TWOPI_F * (float)m / 64.f;
        Wy[y * 32 + 2 * k]     = cosf(a);
        Wy[y * 32 + 2 * k + 1] = sinf(a);
    }
    for (int i = t; i < 2048; i += 256) {
        int x = i >> 5, kxm = i & 31;
        int kx = kxm < 16 ? kxm : kxm + 32;
        int m = (kx * x) & 63;
        float a = -TWOPI_F * (float)m / 64.f;
        TWX[x * 64 + 2 * kxm]     = cosf(a);
        TWX[x * 64 + 2 * kxm + 1] = sinf(a);
    }
    for (int i = t; i < 1024; i += 256) {
        int y = i >> 4, k = i & 15;
        int m = (k * y) & 63;
        float a = TWOPI_F * (float)m / 64.f;
        float sc = (k == 0 ? 1.f : 2.f) / 4096.f;
        WY2[y * 32 + 2 * k]     = sc * cosf(a);
        WY2[y * 32 + 2 * k + 1] = sc * sinf(a);
    }
}

// ---------------- router v3 ----------------
__global__ __launch_bounds__(512) void router_kernel(
    const float* __restrict__ x, const float* __restrict__ enc_w, const float* __restrict__ enc_b,
    const float* __restrict__ wqkv, const float* __restrict__ bqkv,
    const float* __restrict__ wo, const float* __restrict__ bo,
    const float* __restrict__ ln1g, const float* __restrict__ ln1b,
    const float* __restrict__ w1, const float* __restrict__ b1,
    const float* __restrict__ w2, const float* __restrict__ b2,
    const float* __restrict__ ln2g, const float* __restrict__ ln2b,
    const float* __restrict__ fcw, const float* __restrict__ fcb,
    float* __restrict__ rw)
{
    __shared__ float s[64][65];
    __shared__ float qk[64][193];
    __shared__ float sc[64][65];
    __shared__ float o64[64][65];
    __shared__ float feat[64];
    __shared__ float logits[8];
    int b = blockIdx.x, t = threadIdx.x;

    for (int i = t; i < 4096; i += 512) {
        int w_ = i >> 6, d = i & 63;
        s[w_][d] = x[b * 4096 + w_] * enc_w[d] + enc_b[d];
    }
    __syncthreads();

    for (int l = 0; l < 2; ++l) {
        {
            const float* Wq = wqkv + l * 64 * 192;
            const float* Bq = bqkv + l * 192;
            int c4 = t % 48, rg = t / 48;
            if (rg < 8) {
                const float* wcol = Wq + 4 * c4;
                float4 bq = LD4(Bq + 4 * c4);
                float4 acc[8];
#pragma unroll
                for (int i = 0; i < 8; ++i) acc[i] = bq;
                int r0 = rg * 8;
#pragma unroll 8
                for (int k = 0; k < 64; ++k) {
                    float4 wv = LD4(wcol + k * 192);
#pragma unroll
                    for (int i = 0; i < 8; ++i) {
                        float sv = s[r0 + i][k];
                        acc[i].x += sv * wv.x; acc[i].y += sv * wv.y;
                        acc[i].z += sv * wv.z; acc[i].w += sv * wv.w;
                    }
                }
#pragma unroll
                for (int i = 0; i < 8; ++i) {
                    qk[r0 + i][4 * c4]     = acc[i].x;
                    qk[r0 + i][4 * c4 + 1] = acc[i].y;
                    qk[r0 + i][4 * c4 + 2] = acc[i].z;
                    qk[r0 + i][4 * c4 + 3] = acc[i].w;
                }
            }
        }
        __syncthreads();
        for (int h = 0; h < 4; ++h) {
            for (int i = t; i < 4096; i += 512) {
                int q = i >> 6, kj = i & 63;
                float acc = 0.f;
#pragma unroll
                for (int d = 0; d < 16; ++d)
                    acc += qk[q][h * 16 + d] * qk[kj][64 + h * 16 + d];
                sc[q][kj] = acc * 0.25f;
            }
            __syncthreads();
            if (t < 64) {
                float m = -1e30f;
                for (int j = 0; j < 64; ++j) m = fmaxf(m, sc[t][j]);
                float sum = 0.f;
                for (int j = 0; j < 64; ++j) { float e2 = expf(sc[t][j] - m); sc[t][j] = e2; sum += e2; }
                float inv = 1.f / sum;
                for (int j = 0; j < 64; ++j) sc[t][j] *= inv;
            }
            __syncthreads();
            for (int i = t; i < 1024; i += 512) {
                int q = i >> 4, d = i & 15;
                float acc = 0.f;
#pragma unroll 8
                for (int j = 0; j < 64; ++j) acc += sc[q][j] * qk[j][128 + h * 16 + d];
                o64[q][h * 16 + d] = acc;
            }
            __syncthreads();
        }
        {
            const float* Wo = wo + l * 4096;
            const float* Bo = bo + l * 64;
            int c4 = t & 15, rg = t >> 4;
            const float* wcol = Wo + 4 * c4;
            float4 acc0 = LD4(Bo + 4 * c4), acc1 = acc0;
            int r0 = rg * 2;
#pragma unroll 8
            for (int k = 0; k < 64; ++k) {
                float4 wv = LD4(wcol + k * 64);
                float h0 = o64[r0][k], h1 = o64[r0 + 1][k];
                acc0.x += h0 * wv.x; acc0.y += h0 * wv.y;
                acc0.z += h0 * wv.z; acc0.w += h0 * wv.w;
                acc1.x += h1 * wv.x; acc1.y += h1 * wv.y;
                acc1.z += h1 * wv.z; acc1.w += h1 * wv.w;
            }
            sc[r0][4 * c4]     = s[r0][4 * c4]     + acc0.x;
            sc[r0][4 * c4 + 1] = s[r0][4 * c4 + 1] + acc0.y;
            sc[r0][4 * c4 + 2] = s[r0][4 * c4 + 2] + acc0.z;
            sc[r0][4 * c4 + 3] = s[r0][4 * c4 + 3] + acc0.w;
            sc[r0 + 1][4 * c4]     = s[r0 + 1][4 * c4]     + acc1.x;
            sc[r0 + 1][4 * c4 + 1] = s[r0 + 1][4 * c4 + 1] + acc1.y;
            sc[r0 + 1][4 * c4 + 2] = s[r0 + 1][4 * c4 + 2] + acc1.z;
            sc[r0 + 1][4 * c4 + 3] = s[r0 + 1][4 * c4 + 3] + acc1.w;
        }
        __syncthreads();
        if (t < 64) {
            float m = 0.f;
            for (int j = 0; j < 64; ++j) m += sc[t][j];
            m *= (1.f / 64.f);
            float v = 0.f;
            for (int j = 0; j < 64; ++j) { float d = sc[t][j] - m; v += d * d; }
            v *= (1.f / 64.f);
            float inv = rsqrtf(v + 1e-5f);
            for (int j = 0; j < 64; ++j)
                s[t][j] = (sc[t][j] - m) * inv * ln1g[l * 64 + j] + ln1b[l * 64 + j];
        }
        __syncthreads();
        {
            const float* W1 = w1 + l * 64 * 256;
            const float* B1 = b1 + l * 256;
            int c4 = t & 63, rg = t >> 6;
            const float* wcol = W1 + 4 * c4;
            float4 b1v = LD4(B1 + 4 * c4);
            float4 acc[8];
#pragma unroll
            for (int i = 0; i < 8; ++i) acc[i] = b1v;
            int r0 = rg * 8;
#pragma unroll 4
            for (int k = 0; k < 64; ++k) {
                float4 wv = LD4(wcol + k * 256);
#pragma unroll
                for (int i = 0; i < 8; ++i) {
                    float sv = s[r0 + i][k];
                    acc[i].x += sv * wv.x; acc[i].y += sv * wv.y;
                    acc[i].z += sv * wv.z; acc[i].w += sv * wv.w;
                }
            }
#pragma unroll
            for (int i = 0; i < 8; ++i) {
                float a0 = fmaxf(acc[i].x, 0.f), a1 = fmaxf(acc[i].y, 0.f);
                float a2 = fmaxf(acc[i].z, 0.f), a3 = fmaxf(acc[i].w, 0.f);
                if (c4 < 48) {
                    qk[r0 + i][4 * c4] = a0; qk[r0 + i][4 * c4 + 1] = a1;
                    qk[r0 + i][4 * c4 + 2] = a2; qk[r0 + i][4 * c4 + 3] = a3;
                } else {
                    int c = 4 * c4 - 192;
                    o64[r0 + i][c] = a0; o64[r0 + i][c + 1] = a1;
                    o64[r0 + i][c + 2] = a2; o64[r0 + i][c + 3] = a3;
                }
            }
        }
        __syncthreads();
        {
            const float* W2 = w2 + l * 256 * 64;
            const float* B2 = b2 + l * 64;
            int c4 = t & 15, rg = t >> 4;
            const float* wcol = W2 + 4 * c4;
            float4 acc0 = LD4(B2 + 4 * c4), acc1 = acc0;
            int r0 = rg * 2;
#pragma unroll 8
            for (int k = 0; k < 192; ++k) {
                float4 wv = LD4(wcol + k * 64);
                float h0 = qk[r0][k], h1 = qk[r0 + 1][k];
                acc0.x += h0 * wv.x; acc0.y += h0 * wv.y;
                acc0.z += h0 * wv.z; acc0.w += h0 * wv.w;
                acc1.x += h1 * wv.x; acc1.y += h1 * wv.y;
                acc1.z += h1 * wv.z; acc1.w += h1 * wv.w;
            }
#pragma unroll 8
            for (int k = 192; k < 256; ++k) {
                float4 wv = LD4(wcol + k * 64);
                float h0 = o64[r0][k - 192], h1 = o64[r0 + 1][k - 192];
                acc0.x += h0 * wv.x; acc0.y += h0 * wv.y;
                acc0.z += h0 * wv.z; acc0.w += h0 * wv.w;
                acc1.x += h1 * wv.x; acc1.y += h1 * wv.y;
                acc1.z += h1 * wv.z; acc1.w += h1 * wv.w;
            }
            sc[r0][4 * c4]     = s[r0][4 * c4]     + acc0.x;
            sc[r0][4 * c4 + 1] = s[r0][4 * c4 + 1] + acc0.y;
            sc[r0][4 * c4 + 2] = s[r0][4 * c4 + 2] + acc0.z;
            sc[r0][4 * c4 + 3] = s[r0][4 * c4 + 3] + acc0.w;
            sc[r0 + 1][4 * c4]     = s[r0 + 1][4 * c4]     + acc1.x;
            sc[r0 + 1][4 * c4 + 1] = s[r0 + 1][4 * c4 + 1] + acc1.y;
            sc[r0 + 1][4 * c4 + 2] = s[r0 + 1][4 * c4 + 2] + acc1.z;
            sc[r0 + 1][4 * c4 + 3] = s[r0 + 1][4 * c4 + 3] + acc1.w;
        }
        __syncthreads();
        if (t < 64) {
            float m = 0.f;
            for (int j = 0; j < 64; ++j) m += sc[t][j];
            m *= (1.f / 64.f);
            float v = 0.f;
            for (int j = 0; j < 64; ++j) { float d = sc[t][j] - m; v += d * d; }
            v *= (1.f / 64.f);
            float inv = rsqrtf(v + 1e-5f);
            for (int j = 0; j < 64; ++j)
                s[t][j] = (sc[t][j] - m) * inv * ln2g[l * 64 + j] + ln2b[l * 64 + j];
        }
        __syncthreads();
    }
    if (t < 64) {
        float m = -1e30f;
        for (int r = 0; r < 64; ++r) m = fmaxf(m, s[r][t]);
        feat[t] = m;
    }
    __syncthreads();
    if (t < 8) {
        float acc = fcb[t];
        for (int k = 0; k < 64; ++k) acc += feat[k] * fcw[k * 8 + t];
        logits[t] = acc;
    }
    __syncthreads();
    if (t == 0) {
        int i0 = 0;
        for (int j = 1; j < 8; ++j) if (logits[j] > logits[i0]) i0 = j;
        int i1 = -1;
        for (int j = 0; j < 8; ++j) {
            if (j == i0) continue;
            if (i1 < 0 || logits[j] > logits[i1]) i1 = j;
        }
        float e1 = expf(logits[i1] - logits[i0]);
        float w0 = 1.f / (1.f + e1);
        float w1v = e1 / (1.f + e1);
        for (int j = 0; j < 8; ++j) rw[b * 8 + j] = 0.f;
        rw[b * 8 + i0] = w0;
        rw[b * 8 + i1] = w1v;
    }
}

// ---------------- build pairs + balanced chunk table ----------------
__global__ void build_pairs_kernel(const float* __restrict__ rw, int* __restrict__ pair_b,
                                   int* __restrict__ pair_e, float* __restrict__ pair_w,
                                   int* __restrict__ estart, int* __restrict__ chunk_e,
                                   int* __restrict__ chunk_p0, int* __restrict__ chunk_np) {
    __shared__ float r[256];
    __shared__ int cnt[8], off[9];
    int t = threadIdx.x;
    for (int i = t; i < 256; i += 64) r[i] = rw[i];
    if (t < 64) { pair_b[t] = 0; pair_e[t] = 0; pair_w[t] = 0.f; }
    __syncthreads();
    if (t < 8) {
        int c = 0;
        for (int b = 0; b < 32; ++b) if (r[b * 8 + t] != 0.f) ++c;
        cnt[t] = c;
    }
    __syncthreads();
    if (t == 0) {
        int a = 0;
        for (int e = 0; e < 8; ++e) { off[e] = a; a += cnt[e]; }
        off[8] = a;
        for (int e = 0; e <= 8; ++e) estart[e] = off[e];
        int nc = 0;
        for (int e = 0; e < 8; ++e) {
            for (int s = off[e]; s < off[e + 1]; s += 8) {
                int np = off[e + 1] - s; if (np > 8) np = 8;
                chunk_e[nc] = e; chunk_p0[nc] = s; chunk_np[nc] = np; ++nc;
            }
        }
        for (int c = nc; c < 16; ++c) { chunk_e[c] = 0; chunk_p0[c] = 0; chunk_np[c] = 0; }
    }
    __syncthreads();
    if (t < 8) {
        int n = off[t];
        for (int b = 0; b < 32; ++b) {
            float w = r[b * 8 + t];
            if (w != 0.f) { pair_b[n] = b; pair_e[n] = t; pair_w[n] = w; ++n; }
        }
    }
}

// ---------------- lift ----------------
__global__ __launch_bounds__(256) void lift_kernel(const float* __restrict__ x,
    const float* __restrict__ lw, const float* __restrict__ lb,
    const int* __restrict__ pair_b, const int* __restrict__ pair_e, float* __restrict__ hA) {
    int p = blockIdx.x, tile = blockIdx.y, t = threadIdx.x;
    int b = pair_b[p], e = pair_e[p];
    float* h = hA + (size_t)p * 262144;
    const float* xb = x + (size_t)b * 4096;
    for (int i = tile * 16384 + t; i < (tile + 1) * 16384; i += 256) {
        int co = i >> 12, xy = i & 4095;
        h[i] = xb[xy] * lw[e * 64 + co] + lb[e * 64 + co];
    }
}

// ---------------- fused forward DFT v2 ----------------
__global__ __launch_bounds__(256) void fwdft_kernel(const float* __restrict__ h,
    const float* __restrict__ Wy, float* __restrict__ F) {
    __shared__ float ht[64][68];
    __shared__ float gt[64][36];
    __shared__ float wy[2048];
    __shared__ float tw64[128];
    int bid = blockIdx.x;
    int t = threadIdx.x;
    const float* src = h + (size_t)bid * 4096;
    for (int i = t; i < 1024; i += 256) {
        float4 v = *(const float4*)(src + i * 4);
        int x = (i * 4) >> 6, y = (i * 4) & 63;
        *(float4*)(&ht[x][y]) = v;
    }
    for (int i = t; i < 512; i += 256) *(float4*)(&wy[i * 4]) = *(const float4*)(Wy + i * 4);
    if (t < 64) {
        float a = -TWOPI_F * (float)t / 64.f;
        tw64[2 * t]     = cosf(a);
        tw64[2 * t + 1] = sinf(a);
    }
    __syncthreads();
    {
        int xx = t >> 2, kq = t & 3;
        float gr0 = 0.f, gi0 = 0.f, gr1 = 0.f, gi1 = 0.f;
        float gr2 = 0.f, gi2 = 0.f, gr3 = 0.f, gi3 = 0.f;
#pragma unroll 4
        for (int y = 0; y < 64; ++y) {
            float hv = ht[xx][y];
            float4 w0 = *(const float4*)(&wy[y * 32 + kq * 8]);
            float4 w1 = *(const float4*)(&wy[y * 32 + kq * 8 + 4]);
            gr0 += hv * w0.x; gi0 += hv * w0.y;
            gr1 += hv * w0.z; gi1 += hv * w0.w;
            gr2 += hv * w1.x; gi2 += hv * w1.y;
            gr3 += hv * w1.z; gi3 += hv * w1.w;
        }
        *(float4*)(&gt[xx][kq * 8])     = make_float4(gr0, gi0, gr1, gi1);
        *(float4*)(&gt[xx][kq * 8 + 4]) = make_float4(gr2, gi2, gr3, gi3);
    }
    __syncthreads();
    {
        int kxm = t & 31, kyq = t >> 5;
        int kx = kxm < 16 ? kxm : kxm + 32;
        float ar0 = 0.f, ai0 = 0.f, ar1 = 0.f, ai1 = 0.f;
        int idx = 0;
#pragma unroll 4
        for (int xx = 0; xx < 64; ++xx) {
            float c_ = tw64[2 * idx], s_ = tw64[2 * idx + 1];
            float4 g = *(const float4*)(&gt[xx][kyq * 4]);
            ar0 += g.x * c_ - g.y * s_;  ai0 += g.x * s_ + g.y * c_;
            ar1 += g.z * c_ - g.w * s_;  ai1 += g.z * s_ + g.w * c_;
            idx = (idx + kx) & 63;
        }
        float* fb = F + (size_t)bid * 1024 + kxm * 32 + kyq * 4;
        *(float4*)(fb) = make_float4(ar0, ai0, ar1, ai1);
    }
}

// ---------------- spectral v11: chunk-balanced (R14 proven) ----------------
__global__ __launch_bounds__(256) void spectral_kernel(
    const float* __restrict__ F, float* __restrict__ FoA, float* __restrict__ FoB,
    const float* __restrict__ w1, const float* __restrict__ w2,
    const int* __restrict__ chunk_e, const int* __restrict__ chunk_p0,
    const int* __restrict__ chunk_np, int l)
{
    int c = blockIdx.x;
    int np = chunk_np[c];
    if (np == 0) return;
    int e = chunk_e[c], p0 = chunk_p0[c];
    int z = blockIdx.z;
    int wsel = z & 1, cih = (z >> 1) & 1, mq = z >> 2;
    int t = threadIdx.x;
    int co = blockIdx.y * 4 + (t >> 6);
    int lane = t & 63;
    int moff = mq * 256 + lane * 4;

    const float* wbase = (wsel == 0 ? w1 : w2) + (size_t)(e * 4 + l) * 2097152;
    const float* Wc  = wbase + (size_t)(cih * 32) * 32768 + (size_t)co * 512 + moff;
    const float* Fc0 = F + (size_t)p0 * 65536 + (size_t)(cih * 32) * 1024 + wsel * 512 + moff;
    float* Fob = (cih ? FoB : FoA) + (size_t)p0 * 65536 + (size_t)co * 1024 + wsel * 512 + moff;

    float4 acc[8];
#pragma unroll
    for (int p = 0; p < 8; ++p) acc[p] = make_float4(0.f, 0.f, 0.f, 0.f);
    const float* Wp = Wc;
    const float* Fp = Fc0;
    for (int ci = 0; ci < 32; ++ci) {
        float4 wv = LD4(Wp);
#pragma unroll
        for (int p = 0; p < 8; ++p) {
            float4 fv = LD4(Fp + (size_t)p * 65536);
            acc[p].x += fv.x * wv.x - fv.y * wv.y;
            acc[p].y += fv.x * wv.y + fv.y * wv.x;
            acc[p].z += fv.z * wv.z - fv.w * wv.w;
            acc[p].w += fv.z * wv.w + fv.w * wv.z;
        }
        Wp += 32768;
        Fp += 1024;
    }
#pragma unroll
    for (int p = 0; p < 8; ++p) {
        if (p < np)
            *(float4*)(Fob + (size_t)p * 65536) = acc[p];
    }
}

// ---------------- conv1x1 v2: float4 xy, 4 co-groups, weights in LDS ----------------
// block 256 = 64 xy4-lanes x 4 co-groups(16 co); grid (64 p, 16 xy-tiles).
// Per ci: one 1KB-coalesced float4 src load/wave + 4 broadcast ds_read_b128.
// Stores: 16 float4/thread, 1KB/wave-instruction. acc 64 VGPR, no min-waves bound.
__global__ __launch_bounds__(256) void conv1x1_kernel(
    const float* __restrict__ src, float* __restrict__ dst,
    const float* __restrict__ Wall, const float* __restrict__ Ball,
    const int* __restrict__ pair_e, int wmul, int wadd, int do_gelu)
{
    __shared__ float ws[64][68];   // W[ci][co], row stride 272B (16B-aligned)
    __shared__ float bs[64];
    int p = blockIdx.x, tile = blockIdx.y, t = threadIdx.x;
    int e = pair_e[p];
    int widx = e * wmul + wadd;
    const float* W = Wall + (size_t)widx * 4096;
    for (int i = t; i < 1024; i += 256) {
        float4 v = LD4(W + i * 4);
        int ci = (i * 4) >> 6, co = (i * 4) & 63;
        *(float4*)(&ws[ci][co]) = v;
    }
    if (t < 64) bs[t] = Ball[widx * 64 + t];
    __syncthreads();

    int xy4 = t & 63, cog = t >> 6;
    const float* sb = src + (size_t)p * 262144 + tile * 256 + xy4 * 4;
    float4 acc[16];
#pragma unroll
    for (int j = 0; j < 16; ++j) {
        float bv = bs[cog * 16 + j];
        acc[j] = make_float4(bv, bv, bv, bv);
    }
    for (int ci = 0; ci < 64; ++ci) {
        float4 sv = LD4(sb + (size_t)ci * 4096);
        float4 w0 = *(const float4*)(&ws[ci][cog * 16]);
        float4 w1 = *(const float4*)(&ws[ci][cog * 16 + 4]);
        float4 w2 = *(const float4*)(&ws[ci][cog * 16 + 8]);
        float4 w3 = *(const float4*)(&ws[ci][cog * 16 + 12]);
        float wr[16] = {w0.x, w0.y, w0.z, w0.w, w1.x, w1.y, w1.z, w1.w,
                        w2.x, w2.y, w2.z, w2.w, w3.x, w3.y, w3.z, w3.w};
#pragma unroll
        for (int j = 0; j < 16; ++j) {
            float w = wr[j];
            acc[j].x += sv.x * w; acc[j].y += sv.y * w;
            acc[j].z += sv.z * w; acc[j].w += sv.w * w;
        }
    }
    float* d = dst + (size_t)p * 262144 + (size_t)(cog * 16) * 4096 + tile * 256 + xy4 * 4;
#pragma unroll
    for (int j = 0; j < 16; ++j) {
        float4 v = acc[j];
        if (do_gelu) {
            v.x = gelu_f(v.x); v.y = gelu_f(v.y);
            v.z = gelu_f(v.z); v.w = gelu_f(v.w);
        }
        *(float4*)(d + (size_t)j * 4096) = v;
    }
}

// ---------------- inverse DFT (sums FoA+FoB) + skip-add + gelu ----------------
__global__ __launch_bounds__(256) void inv_kernel(
    const float* __restrict__ FoA, const float* __restrict__ FoB,
    const float* __restrict__ WY2, float* __restrict__ dst_h, int do_gelu)
{
    __shared__ float wy2[2048];
    __shared__ float twl[128];
    __shared__ float fo_s[1024];
    __shared__ float tT[64][36];
    __shared__ float ot[64][66];
    int t = threadIdx.x;
    for (int i = t; i < 512; i += 256) *(float4*)(&wy2[i * 4]) = *(const float4*)(WY2 + i * 4);
    if (t < 64) {
        float a = TWOPI_F * (float)t / 64.f;
        twl[2 * t] = cosf(a);
        twl[2 * t + 1] = sinf(a);
    }
    __syncthreads();

    for (int item = 0; item < 4; ++item) {
        int wid = blockIdx.x * 4 + item;
        int p = wid >> 6, co = wid & 63;
        const float* fA = FoA + (size_t)p * 65536 + (size_t)co * 1024;
        const float* fB = FoB + (size_t)p * 65536 + (size_t)co * 1024;
        {
            float4 a = LD4(fA + t * 4);
            float4 b = LD4(fB + t * 4);
            *(float4*)(&fo_s[t * 4]) = make_float4(a.x + b.x, a.y + b.y, a.z + b.z, a.w + b.w);
        }
        __syncthreads();
        {
            int xx = t & 63, kq = t >> 6;
            float Tr0 = 0.f, Ti0 = 0.f, Tr1 = 0.f, Ti1 = 0.f;
            float Tr2 = 0.f, Ti2 = 0.f, Tr3 = 0.f, Ti3 = 0.f;
#pragma unroll 4
            for (int kxm = 0; kxm < 32; ++kxm) {
                int kx = kxm < 16 ? kxm : kxm + 32;
                int idx = (kx * xx) & 63;
                float c_ = twl[2 * idx], s_ = twl[2 * idx + 1];
                float4 f0 = *(const float4*)(&fo_s[kxm * 32 + kq * 8]);
                float4 f1 = *(const float4*)(&fo_s[kxm * 32 + kq * 8 + 4]);
                Tr0 += f0.x * c_ - f0.y * s_;  Ti0 += f0.x * s_ + f0.y * c_;
                Tr1 += f0.z * c_ - f0.w * s_;  Ti1 += f0.z * s_ + f0.w * c_;
                Tr2 += f1.x * c_ - f1.y * s_;  Ti2 += f1.x * s_ + f1.y * c_;
                Tr3 += f1.z * c_ - f1.w * s_;  Ti3 += f1.z * s_ + f1.w * c_;
            }
            *(float4*)(&tT[xx][kq * 8])     = make_float4(Tr0, Ti0, Tr1, Ti1);
            *(float4*)(&tT[xx][kq * 8 + 4]) = make_float4(Tr2, Ti2, Tr3, Ti3);
        }
        __syncthreads();
        {
            int xx = t & 63, yq = t >> 6;
            float Trr[16], Tii[16];
#pragma unroll
            for (int q = 0; q < 8; ++q) {
                float4 v = *(const float4*)(&tT[xx][q * 4]);
                Trr[q * 2] = v.x; Tii[q * 2] = v.y;
                Trr[q * 2 + 1] = v.z; Tii[q * 2 + 1] = v.w;
            }
            for (int j = 0; j < 16; ++j) {
                int y = yq * 16 + j;
                const float* wr = &wy2[y * 32];
                float acc = 0.f;
#pragma unroll
                for (int k = 0; k < 16; ++k)
                    acc += Trr[k] * wr[2 * k] - Tii[k] * wr[2 * k + 1];
                ot[xx][y] = acc;
            }
        }
        __syncthreads();
        {
            float* base = dst_h + (size_t)p * 262144 + (size_t)co * 4096;
            for (int r = 0; r < 16; ++r) {
                int gidx = r * 256 + t;
                int xx = gidx >> 6, y = gidx & 63;
                float v = base[gidx] + ot[xx][y];
                if (do_gelu) v = gelu_f(v);
                base[gidx] = v;
            }
        }
        __syncthreads();
    }
}

// ---------------- proj2 + weighted accumulate ----------------
__global__ __launch_bounds__(256) void proj2_kernel(
    const float* __restrict__ hsrc, const float* __restrict__ p2w, const float* __restrict__ p2b,
    const int* __restrict__ pair_b, const int* __restrict__ pair_e,
    const float* __restrict__ pw, float* __restrict__ out)
{
    int p = blockIdx.x, tile = blockIdx.y, t = threadIdx.x;
    int b = pair_b[p], e = pair_e[p];
    float wgt = pw[p];
    const float* h = hsrc + (size_t)p * 262144 + tile * 256 + t;
    const float* w2 = p2w + e * 64;
    float acc = p2b[e];
#pragma unroll
    for (int c = 0; c < 64; ++c) acc += h[(size_t)c * 4096] * w2[c];
    atomicAdd(out + (size_t)b * 4096 + tile * 256 + t, wgt * acc);
}

// ---------------- launch ----------------
extern "C" void kernel_launch(void* const* d_in, const int* in_sizes, int n_in,
                              void* d_out, int out_size, void* d_ws, size_t ws_size,
                              hipStream_t stream) {
    const float* x    = (const float*)d_in[0];
    const float* encw = (const float*)d_in[1];
    const float* encb = (const float*)d_in[2];
    const float* wqkv = (const float*)d_in[3];
    const float* bqkv = (const float*)d_in[4];
    const float* wo   = (const float*)d_in[5];
    const float* bo   = (const float*)d_in[6];
    const float* ln1g = (const float*)d_in[7];
    const float* ln1b = (const float*)d_in[8];
    const float* fw1  = (const float*)d_in[9];
    const float* fb1  = (const float*)d_in[10];
    const float* fw2  = (const float*)d_in[11];
    const float* fb2  = (const float*)d_in[12];
    const float* ln2g = (const float*)d_in[13];
    const float* ln2b = (const float*)d_in[14];
    const float* fcw  = (const float*)d_in[15];
    const float* fcb  = (const float*)d_in[16];
    const float* lw   = (const float*)d_in[17];
    const float* lb   = (const float*)d_in[18];
    const float* sw1  = (const float*)d_in[19];
    const float* sw2  = (const float*)d_in[20];
    const float* skw  = (const float*)d_in[21];
    const float* skb  = (const float*)d_in[22];
    const float* p1w  = (const float*)d_in[23];
    const float* p1b  = (const float*)d_in[24];
    const float* p2w  = (const float*)d_in[25];
    const float* p2b  = (const float*)d_in[26];
    float* out = (float*)d_out;

    float* wsf    = (float*)d_ws;
    float* rw     = wsf;               // 256
    float* pair_w = wsf + 256;         // 64
    int*   ipart  = (int*)(wsf + 320); // 192 ints available
    int* pair_b   = ipart;             // 64
    int* pair_e   = ipart + 64;        // 64
    int* estart   = ipart + 128;       // 9
    int* chunk_e  = ipart + 137;       // 16
    int* chunk_p0 = ipart + 153;       // 16
    int* chunk_np = ipart + 169;       // 16
    float* Wy  = wsf + 512;            // 2048
    float* TWX = wsf + 2560;           // 4096 (unused, layout compat)
    float* WY2 = wsf + 6656;           // 2048
    float* hA  = wsf + 16384;                       // 64 * 262144
    float* hB  = hA + (size_t)64 * 262144;          // 64 * 262144
    float* F   = hB + (size_t)64 * 262144;          // 64 * 65536
    float* FoA = F + (size_t)64 * 65536;            // 64 * 65536
    float* FoB = FoA + (size_t)64 * 65536;          // 64 * 65536
    size_t need = (16384 + 2ull * 64 * 262144 + 64ull * 65536 + 64ull * 131072) * 4;
    if (ws_size < need) return;

    hipMemsetAsync(d_out, 0, (size_t)out_size * sizeof(float), stream);
    init_tables_kernel<<<1, 256, 0, stream>>>(Wy, TWX, WY2);
    router_kernel<<<32, 512, 0, stream>>>(x, encw, encb, wqkv, bqkv, wo, bo, ln1g, ln1b,
                                          fw1, fb1, fw2, fb2, ln2g, ln2b, fcw, fcb, rw);
    build_pairs_kernel<<<1, 64, 0, stream>>>(rw, pair_b, pair_e, pair_w, estart,
                                             chunk_e, chunk_p0, chunk_np);
    lift_kernel<<<dim3(64, 16), 256, 0, stream>>>(x, lw, lb, pair_b, pair_e, hA);
    for (int l = 0; l < 4; ++l) {
        float* cur = (l & 1) ? hB : hA;
        float* nxt = (l & 1) ? hA : hB;
        fwdft_kernel<<<4096, 256, 0, stream>>>(cur, Wy, F);
        spectral_kernel<<<dim3(16, 16, 8), 256, 0, stream>>>(F, FoA, FoB, sw1, sw2,
                                                             chunk_e, chunk_p0, chunk_np, l);
        conv1x1_kernel<<<dim3(64, 16), 256, 0, stream>>>(cur, nxt, skw, skb, pair_e, 4, l, 0);
        inv_kernel<<<1024, 256, 0, stream>>>(FoA, FoB, WY2, nxt, (l < 3) ? 1 : 0);
    }
    conv1x1_kernel<<<dim3(64, 16), 256, 0, stream>>>(hA, hB, p1w, p1b, pair_e, 1, 0, 1);
    proj2_kernel<<<dim3(64, 16), 256, 0, stream>>>(hB, p2w, p2b, pair_b, pair_e, pair_w, out);
}

// Round 16
// 1321.948 us; speedup vs baseline: 8.5964x; 1.0759x over previous
//
#include <hip/hip_runtime.h>
#include <math.h>

#define TWOPI_F 6.283185307179586f
#define LD4(p) (*(const float4*)(p))

__device__ __forceinline__ float gelu_f(float v) {
    float u = 0.7978845608028654f * (v + 0.044715f * v * v * v);
    return 0.5f * v * (1.f + tanhf(u));
}

// ---------------- twiddle tables ----------------
// TWX[0:128]  = e^{-2pi i m/64} (cos,sin pairs)  -- forward
// TWX[128:256]= e^{+2pi i m/64}                   -- inverse
__global__ void init_tables_kernel(float* __restrict__ Wy, float* __restrict__ TWX,
                                   float* __restrict__ WY2) {
    int t = threadIdx.x;
    for (int i = t; i < 1024; i += 256) {
        int y = i >> 4, k = i & 15;
        int m = (k * y) & 63;
        float a = -TWOPI_F * (float)m / 64.f;
        Wy[y * 32 + 2 * k]     = cosf(a);
        Wy[y * 32 + 2 * k + 1] = sinf(a);
    }
    if (t < 64) {
        float a = -TWOPI_F * (float)t / 64.f;
        TWX[2 * t]           = cosf(a);
        TWX[2 * t + 1]       = sinf(a);
        TWX[128 + 2 * t]     = cosf(a);
        TWX[128 + 2 * t + 1] = -sinf(a);
    }
    for (int i = t; i < 1024; i += 256) {
        int y = i >> 4, k = i & 15;
        int m = (k * y) & 63;
        float a = TWOPI_F * (float)m / 64.f;
        float sc = (k == 0 ? 1.f : 2.f) / 4096.f;
        WY2[y * 32 + 2 * k]     = sc * cosf(a);
        WY2[y * 32 + 2 * k + 1] = sc * sinf(a);
    }
}

// ---------------- router v3 ----------------
__global__ __launch_bounds__(512) void router_kernel(
    const float* __restrict__ x, const float* __restrict__ enc_w, const float* __restrict__ enc_b,
    const float* __restrict__ wqkv, const float* __restrict__ bqkv,
    const float* __restrict__ wo, const float* __restrict__ bo,
    const float* __restrict__ ln1g, const float* __restrict__ ln1b,
    const float* __restrict__ w1, const float* __restrict__ b1,
    const float* __restrict__ w2, const float* __restrict__ b2,
    const float* __restrict__ ln2g, const float* __restrict__ ln2b,
    const float* __restrict__ fcw, const float* __restrict__ fcb,
    float* __restrict__ rw)
{
    __shared__ float s[64][65];
    __shared__ float qk[64][193];
    __shared__ float sc[64][65];
    __shared__ float o64[64][65];
    __shared__ float feat[64];
    __shared__ float logits[8];
    int b = blockIdx.x, t = threadIdx.x;

    for (int i = t; i < 4096; i += 512) {
        int w_ = i >> 6, d = i & 63;
        s[w_][d] = x[b * 4096 + w_] * enc_w[d] + enc_b[d];
    }
    __syncthreads();

    for (int l = 0; l < 2; ++l) {
        {
            const float* Wq = wqkv + l * 64 * 192;
            const float* Bq = bqkv + l * 192;
            int c4 = t % 48, rg = t / 48;
            if (rg < 8) {
                const float* wcol = Wq + 4 * c4;
                float4 bq = LD4(Bq + 4 * c4);
                float4 acc[8];
#pragma unroll
                for (int i = 0; i < 8; ++i) acc[i] = bq;
                int r0 = rg * 8;
#pragma unroll 8
                for (int k = 0; k < 64; ++k) {
                    float4 wv = LD4(wcol + k * 192);
#pragma unroll
                    for (int i = 0; i < 8; ++i) {
                        float sv = s[r0 + i][k];
                        acc[i].x += sv * wv.x; acc[i].y += sv * wv.y;
                        acc[i].z += sv * wv.z; acc[i].w += sv * wv.w;
                    }
                }
#pragma unroll
                for (int i = 0; i < 8; ++i) {
                    qk[r0 + i][4 * c4]     = acc[i].x;
                    qk[r0 + i][4 * c4 + 1] = acc[i].y;
                    qk[r0 + i][4 * c4 + 2] = acc[i].z;
                    qk[r0 + i][4 * c4 + 3] = acc[i].w;
                }
            }
        }
        __syncthreads();
        for (int h = 0; h < 4; ++h) {
            for (int i = t; i < 4096; i += 512) {
                int q = i >> 6, kj = i & 63;
                float acc = 0.f;
#pragma unroll
                for (int d = 0; d < 16; ++d)
                    acc += qk[q][h * 16 + d] * qk[kj][64 + h * 16 + d];
                sc[q][kj] = acc * 0.25f;
            }
            __syncthreads();
            if (t < 64) {
                float m = -1e30f;
                for (int j = 0; j < 64; ++j) m = fmaxf(m, sc[t][j]);
                float sum = 0.f;
                for (int j = 0; j < 64; ++j) { float e2 = expf(sc[t][j] - m); sc[t][j] = e2; sum += e2; }
                float inv = 1.f / sum;
                for (int j = 0; j < 64; ++j) sc[t][j] *= inv;
            }
            __syncthreads();
            for (int i = t; i < 1024; i += 512) {
                int q = i >> 4, d = i & 15;
                float acc = 0.f;
#pragma unroll 8
                for (int j = 0; j < 64; ++j) acc += sc[q][j] * qk[j][128 + h * 16 + d];
                o64[q][h * 16 + d] = acc;
            }
            __syncthreads();
        }
        {
            const float* Wo = wo + l * 4096;
            const float* Bo = bo + l * 64;
            int c4 = t & 15, rg = t >> 4;
            const float* wcol = Wo + 4 * c4;
            float4 acc0 = LD4(Bo + 4 * c4), acc1 = acc0;
            int r0 = rg * 2;
#pragma unroll 8
            for (int k = 0; k < 64; ++k) {
                float4 wv = LD4(wcol + k * 64);
                float h0 = o64[r0][k], h1 = o64[r0 + 1][k];
                acc0.x += h0 * wv.x; acc0.y += h0 * wv.y;
                acc0.z += h0 * wv.z; acc0.w += h0 * wv.w;
                acc1.x += h1 * wv.x; acc1.y += h1 * wv.y;
                acc1.z += h1 * wv.z; acc1.w += h1 * wv.w;
            }
            sc[r0][4 * c4]     = s[r0][4 * c4]     + acc0.x;
            sc[r0][4 * c4 + 1] = s[r0][4 * c4 + 1] + acc0.y;
            sc[r0][4 * c4 + 2] = s[r0][4 * c4 + 2] + acc0.z;
            sc[r0][4 * c4 + 3] = s[r0][4 * c4 + 3] + acc0.w;
            sc[r0 + 1][4 * c4]     = s[r0 + 1][4 * c4]     + acc1.x;
            sc[r0 + 1][4 * c4 + 1] = s[r0 + 1][4 * c4 + 1] + acc1.y;
            sc[r0 + 1][4 * c4 + 2] = s[r0 + 1][4 * c4 + 2] + acc1.z;
            sc[r0 + 1][4 * c4 + 3] = s[r0 + 1][4 * c4 + 3] + acc1.w;
        }
        __syncthreads();
        if (t < 64) {
            float m = 0.f;
            for (int j = 0; j < 64; ++j) m += sc[t][j];
            m *= (1.f / 64.f);
            float v = 0.f;
            for (int j = 0; j < 64; ++j) { float d = sc[t][j] - m; v += d * d; }
            v *= (1.f / 64.f);
            float inv = rsqrtf(v + 1e-5f);
            for (int j = 0; j < 64; ++j)
                s[t][j] = (sc[t][j] - m) * inv * ln1g[l * 64 + j] + ln1b[l * 64 + j];
        }
        __syncthreads();
        {
            const float* W1 = w1 + l * 64 * 256;
            const float* B1 = b1 + l * 256;
            int c4 = t & 63, rg = t >> 6;
            const float* wcol = W1 + 4 * c4;
            float4 b1v = LD4(B1 + 4 * c4);
            float4 acc[8];
#pragma unroll
            for (int i = 0; i < 8; ++i) acc[i] = b1v;
            int r0 = rg * 8;
#pragma unroll 4
            for (int k = 0; k < 64; ++k) {
                float4 wv = LD4(wcol + k * 256);
#pragma unroll
                for (int i = 0; i < 8; ++i) {
                    float sv = s[r0 + i][k];
                    acc[i].x += sv * wv.x; acc[i].y += sv * wv.y;
                    acc[i].z += sv * wv.z; acc[i].w += sv * wv.w;
                }
            }
#pragma unroll
            for (int i = 0; i < 8; ++i) {
                float a0 = fmaxf(acc[i].x, 0.f), a1 = fmaxf(acc[i].y, 0.f);
                float a2 = fmaxf(acc[i].z, 0.f), a3 = fmaxf(acc[i].w, 0.f);
                if (c4 < 48) {
                    qk[r0 + i][4 * c4] = a0; qk[r0 + i][4 * c4 + 1] = a1;
                    qk[r0 + i][4 * c4 + 2] = a2; qk[r0 + i][4 * c4 + 3] = a3;
                } else {
                    int c = 4 * c4 - 192;
                    o64[r0 + i][c] = a0; o64[r0 + i][c + 1] = a1;
                    o64[r0 + i][c + 2] = a2; o64[r0 + i][c + 3] = a3;
                }
            }
        }
        __syncthreads();
        {
            const float* W2 = w2 + l * 256 * 64;
            const float* B2 = b2 + l * 64;
            int c4 = t & 15, rg = t >> 4;
            const float* wcol = W2 + 4 * c4;
            float4 acc0 = LD4(B2 + 4 * c4), acc1 = acc0;
            int r0 = rg * 2;
#pragma unroll 8
            for (int k = 0; k < 192; ++k) {
                float4 wv = LD4(wcol + k * 64);
                float h0 = qk[r0][k], h1 = qk[r0 + 1][k];
                acc0.x += h0 * wv.x; acc0.y += h0 * wv.y;
                acc0.z += h0 * wv.z; acc0.w += h0 * wv.w;
                acc1.x += h1 * wv.x; acc1.y += h1 * wv.y;
                acc1.z += h1 * wv.z; acc1.w += h1 * wv.w;
            }
#pragma unroll 8
            for (int k = 192; k < 256; ++k) {
                float4 wv = LD4(wcol + k * 64);
                float h0 = o64[r0][k - 192], h1 = o64[r0 + 1][k - 192];
                acc0.x += h0 * wv.x; acc0.y += h0 * wv.y;
                acc0.z += h0 * wv.z; acc0.w += h0 * wv.w;
                acc1.x += h1 * wv.x; acc1.y += h1 * wv.y;
                acc1.z += h1 * wv.z; acc1.w += h1 * wv.w;
            }
            sc[r0][4 * c4]     = s[r0][4 * c4]     + acc0.x;
            sc[r0][4 * c4 + 1] = s[r0][4 * c4 + 1] + acc0.y;
            sc[r0][4 * c4 + 2] = s[r0][4 * c4 + 2] + acc0.z;
            sc[r0][4 * c4 + 3] = s[r0][4 * c4 + 3] + acc0.w;
            sc[r0 + 1][4 * c4]     = s[r0 + 1][4 * c4]     + acc1.x;
            sc[r0 + 1][4 * c4 + 1] = s[r0 + 1][4 * c4 + 1] + acc1.y;
            sc[r0 + 1][4 * c4 + 2] = s[r0 + 1][4 * c4 + 2] + acc1.z;
            sc[r0 + 1][4 * c4 + 3] = s[r0 + 1][4 * c4 + 3] + acc1.w;
        }
        __syncthreads();
        if (t < 64) {
            float m = 0.f;
            for (int j = 0; j < 64; ++j) m += sc[t][j];
            m *= (1.f / 64.f);
            float v = 0.f;
            for (int j = 0; j < 64; ++j) { float d = sc[t][j] - m; v += d * d; }
            v *= (1.f / 64.f);
            float inv = rsqrtf(v + 1e-5f);
            for (int j = 0; j < 64; ++j)
                s[t][j] = (sc[t][j] - m) * inv * ln2g[l * 64 + j] + ln2b[l * 64 + j];
        }
        __syncthreads();
    }
    if (t < 64) {
        float m = -1e30f;
        for (int r = 0; r < 64; ++r) m = fmaxf(m, s[r][t]);
        feat[t] = m;
    }
    __syncthreads();
    if (t < 8) {
        float acc = fcb[t];
        for (int k = 0; k < 64; ++k) acc += feat[k] * fcw[k * 8 + t];
        logits[t] = acc;
    }
    __syncthreads();
    if (t == 0) {
        int i0 = 0;
        for (int j = 1; j < 8; ++j) if (logits[j] > logits[i0]) i0 = j;
        int i1 = -1;
        for (int j = 0; j < 8; ++j) {
            if (j == i0) continue;
            if (i1 < 0 || logits[j] > logits[i1]) i1 = j;
        }
        float e1 = expf(logits[i1] - logits[i0]);
        float w0 = 1.f / (1.f + e1);
        float w1v = e1 / (1.f + e1);
        for (int j = 0; j < 8; ++j) rw[b * 8 + j] = 0.f;
        rw[b * 8 + i0] = w0;
        rw[b * 8 + i1] = w1v;
    }
}

// ---------------- build pairs + balanced chunk table ----------------
__global__ void build_pairs_kernel(const float* __restrict__ rw, int* __restrict__ pair_b,
                                   int* __restrict__ pair_e, float* __restrict__ pair_w,
                                   int* __restrict__ estart, int* __restrict__ chunk_e,
                                   int* __restrict__ chunk_p0, int* __restrict__ chunk_np) {
    __shared__ float r[256];
    __shared__ int cnt[8], off[9];
    int t = threadIdx.x;
    for (int i = t; i < 256; i += 64) r[i] = rw[i];
    if (t < 64) { pair_b[t] = 0; pair_e[t] = 0; pair_w[t] = 0.f; }
    __syncthreads();
    if (t < 8) {
        int c = 0;
        for (int b = 0; b < 32; ++b) if (r[b * 8 + t] != 0.f) ++c;
        cnt[t] = c;
    }
    __syncthreads();
    if (t == 0) {
        int a = 0;
        for (int e = 0; e < 8; ++e) { off[e] = a; a += cnt[e]; }
        off[8] = a;
        for (int e = 0; e <= 8; ++e) estart[e] = off[e];
        int nc = 0;
        for (int e = 0; e < 8; ++e) {
            for (int s = off[e]; s < off[e + 1]; s += 8) {
                int np = off[e + 1] - s; if (np > 8) np = 8;
                chunk_e[nc] = e; chunk_p0[nc] = s; chunk_np[nc] = np; ++nc;
            }
        }
        for (int c = nc; c < 16; ++c) { chunk_e[c] = 0; chunk_p0[c] = 0; chunk_np[c] = 0; }
    }
    __syncthreads();
    if (t < 8) {
        int n = off[t];
        for (int b = 0; b < 32; ++b) {
            float w = r[b * 8 + t];
            if (w != 0.f) { pair_b[n] = b; pair_e[n] = t; pair_w[n] = w; ++n; }
        }
    }
}

// ---------------- lift ----------------
__global__ __launch_bounds__(256) void lift_kernel(const float* __restrict__ x,
    const float* __restrict__ lw, const float* __restrict__ lb,
    const int* __restrict__ pair_b, const int* __restrict__ pair_e, float* __restrict__ hA) {
    int p = blockIdx.x, tile = blockIdx.y, t = threadIdx.x;
    int b = pair_b[p], e = pair_e[p];
    float* h = hA + (size_t)p * 262144;
    const float* xb = x + (size_t)b * 4096;
    for (int i = tile * 16384 + t; i < (tile + 1) * 16384; i += 256) {
        int co = i >> 12, xy = i & 4095;
        h[i] = xb[xy] * lw[e * 64 + co] + lb[e * 64 + co];
    }
}

// ---------------- fused forward DFT v3: table-driven twiddles ----------------
__global__ __launch_bounds__(256) void fwdft_kernel(const float* __restrict__ h,
    const float* __restrict__ Wy, const float* __restrict__ TWX, float* __restrict__ F) {
    __shared__ float ht[64][68];
    __shared__ float gt[64][36];
    __shared__ float wy[2048];
    __shared__ float tw64[128];
    int bid = blockIdx.x;
    int t = threadIdx.x;
    const float* src = h + (size_t)bid * 4096;
    for (int i = t; i < 1024; i += 256) {
        float4 v = *(const float4*)(src + i * 4);
        int x = (i * 4) >> 6, y = (i * 4) & 63;
        *(float4*)(&ht[x][y]) = v;
    }
    for (int i = t; i < 512; i += 256) *(float4*)(&wy[i * 4]) = *(const float4*)(Wy + i * 4);
    if (t < 32) *(float4*)(&tw64[t * 4]) = LD4(TWX + t * 4);
    __syncthreads();
    {
        int xx = t >> 2, kq = t & 3;
        float gr0 = 0.f, gi0 = 0.f, gr1 = 0.f, gi1 = 0.f;
        float gr2 = 0.f, gi2 = 0.f, gr3 = 0.f, gi3 = 0.f;
#pragma unroll 4
        for (int y = 0; y < 64; ++y) {
            float hv = ht[xx][y];
            float4 w0 = *(const float4*)(&wy[y * 32 + kq * 8]);
            float4 w1 = *(const float4*)(&wy[y * 32 + kq * 8 + 4]);
            gr0 += hv * w0.x; gi0 += hv * w0.y;
            gr1 += hv * w0.z; gi1 += hv * w0.w;
            gr2 += hv * w1.x; gi2 += hv * w1.y;
            gr3 += hv * w1.z; gi3 += hv * w1.w;
        }
        *(float4*)(&gt[xx][kq * 8])     = make_float4(gr0, gi0, gr1, gi1);
        *(float4*)(&gt[xx][kq * 8 + 4]) = make_float4(gr2, gi2, gr3, gi3);
    }
    __syncthreads();
    {
        int kxm = t & 31, kyq = t >> 5;
        int kx = kxm < 16 ? kxm : kxm + 32;
        float ar0 = 0.f, ai0 = 0.f, ar1 = 0.f, ai1 = 0.f;
        int idx = 0;
#pragma unroll 4
        for (int xx = 0; xx < 64; ++xx) {
            float c_ = tw64[2 * idx], s_ = tw64[2 * idx + 1];
            float4 g = *(const float4*)(&gt[xx][kyq * 4]);
            ar0 += g.x * c_ - g.y * s_;  ai0 += g.x * s_ + g.y * c_;
            ar1 += g.z * c_ - g.w * s_;  ai1 += g.z * s_ + g.w * c_;
            idx = (idx + kx) & 63;
        }
        float* fb = F + (size_t)bid * 1024 + kxm * 32 + kyq * 4;
        *(float4*)(fb) = make_float4(ar0, ai0, ar1, ai1);
    }
}

// ---------------- spectral v11: chunk-balanced (R14 proven) ----------------
__global__ __launch_bounds__(256) void spectral_kernel(
    const float* __restrict__ F, float* __restrict__ FoA, float* __restrict__ FoB,
    const float* __restrict__ w1, const float* __restrict__ w2,
    const int* __restrict__ chunk_e, const int* __restrict__ chunk_p0,
    const int* __restrict__ chunk_np, int l)
{
    int c = blockIdx.x;
    int np = chunk_np[c];
    if (np == 0) return;
    int e = chunk_e[c], p0 = chunk_p0[c];
    int z = blockIdx.z;
    int wsel = z & 1, cih = (z >> 1) & 1, mq = z >> 2;
    int t = threadIdx.x;
    int co = blockIdx.y * 4 + (t >> 6);
    int lane = t & 63;
    int moff = mq * 256 + lane * 4;

    const float* wbase = (wsel == 0 ? w1 : w2) + (size_t)(e * 4 + l) * 2097152;
    const float* Wc  = wbase + (size_t)(cih * 32) * 32768 + (size_t)co * 512 + moff;
    const float* Fc0 = F + (size_t)p0 * 65536 + (size_t)(cih * 32) * 1024 + wsel * 512 + moff;
    float* Fob = (cih ? FoB : FoA) + (size_t)p0 * 65536 + (size_t)co * 1024 + wsel * 512 + moff;

    float4 acc[8];
#pragma unroll
    for (int p = 0; p < 8; ++p) acc[p] = make_float4(0.f, 0.f, 0.f, 0.f);
    const float* Wp = Wc;
    const float* Fp = Fc0;
    for (int ci = 0; ci < 32; ++ci) {
        float4 wv = LD4(Wp);
#pragma unroll
        for (int p = 0; p < 8; ++p) {
            float4 fv = LD4(Fp + (size_t)p * 65536);
            acc[p].x += fv.x * wv.x - fv.y * wv.y;
            acc[p].y += fv.x * wv.y + fv.y * wv.x;
            acc[p].z += fv.z * wv.z - fv.w * wv.w;
            acc[p].w += fv.z * wv.w + fv.w * wv.z;
        }
        Wp += 32768;
        Fp += 1024;
    }
#pragma unroll
    for (int p = 0; p < 8; ++p) {
        if (p < np)
            *(float4*)(Fob + (size_t)p * 65536) = acc[p];
    }
}

// ---------------- conv1x1 v2 (R15 proven) ----------------
__global__ __launch_bounds__(256) void conv1x1_kernel(
    const float* __restrict__ src, float* __restrict__ dst,
    const float* __restrict__ Wall, const float* __restrict__ Ball,
    const int* __restrict__ pair_e, int wmul, int wadd, int do_gelu)
{
    __shared__ float ws[64][68];
    __shared__ float bs[64];
    int p = blockIdx.x, tile = blockIdx.y, t = threadIdx.x;
    int e = pair_e[p];
    int widx = e * wmul + wadd;
    const float* W = Wall + (size_t)widx * 4096;
    for (int i = t; i < 1024; i += 256) {
        float4 v = LD4(W + i * 4);
        int ci = (i * 4) >> 6, co = (i * 4) & 63;
        *(float4*)(&ws[ci][co]) = v;
    }
    if (t < 64) bs[t] = Ball[widx * 64 + t];
    __syncthreads();

    int xy4 = t & 63, cog = t >> 6;
    const float* sb = src + (size_t)p * 262144 + tile * 256 + xy4 * 4;
    float4 acc[16];
#pragma unroll
    for (int j = 0; j < 16; ++j) {
        float bv = bs[cog * 16 + j];
        acc[j] = make_float4(bv, bv, bv, bv);
    }
    for (int ci = 0; ci < 64; ++ci) {
        float4 sv = LD4(sb + (size_t)ci * 4096);
        float4 w0 = *(const float4*)(&ws[ci][cog * 16]);
        float4 w1 = *(const float4*)(&ws[ci][cog * 16 + 4]);
        float4 w2 = *(const float4*)(&ws[ci][cog * 16 + 8]);
        float4 w3 = *(const float4*)(&ws[ci][cog * 16 + 12]);
        float wr[16] = {w0.x, w0.y, w0.z, w0.w, w1.x, w1.y, w1.z, w1.w,
                        w2.x, w2.y, w2.z, w2.w, w3.x, w3.y, w3.z, w3.w};
#pragma unroll
        for (int j = 0; j < 16; ++j) {
            float w = wr[j];
            acc[j].x += sv.x * w; acc[j].y += sv.y * w;
            acc[j].z += sv.z * w; acc[j].w += sv.w * w;
        }
    }
    float* d = dst + (size_t)p * 262144 + (size_t)(cog * 16) * 4096 + tile * 256 + xy4 * 4;
#pragma unroll
    for (int j = 0; j < 16; ++j) {
        float4 v = acc[j];
        if (do_gelu) {
            v.x = gelu_f(v.x); v.y = gelu_f(v.y);
            v.z = gelu_f(v.z); v.w = gelu_f(v.w);
        }
        *(float4*)(d + (size_t)j * 4096) = v;
    }
}

// ---------------- fused proj1+gelu+proj2 + weighted accumulate ----------------
// block 256 = 64 xy4 x 4 cog; per cog 16 co of proj1 in regs, gelu, dot p2w,
// LDS-reduce over cog, atomicAdd weighted into out. Saves hB roundtrip.
__global__ __launch_bounds__(256) void projfused_kernel(
    const float* __restrict__ src, const float* __restrict__ p1w,
    const float* __restrict__ p1b, const float* __restrict__ p2w,
    const float* __restrict__ p2b, const int* __restrict__ pair_b,
    const int* __restrict__ pair_e, const float* __restrict__ pw,
    float* __restrict__ out)
{
    __shared__ float ws[64][68];
    __shared__ float bs[64];
    __shared__ float w2s[64];
    __shared__ float4 red[4][64];
    int p = blockIdx.x, tile = blockIdx.y, t = threadIdx.x;
    int e = pair_e[p];
    const float* W = p1w + (size_t)e * 4096;
    for (int i = t; i < 1024; i += 256) {
        float4 v = LD4(W + i * 4);
        int ci = (i * 4) >> 6, co = (i * 4) & 63;
        *(float4*)(&ws[ci][co]) = v;
    }
    if (t < 64) { bs[t] = p1b[e * 64 + t]; w2s[t] = p2w[e * 64 + t]; }
    __syncthreads();

    int xy4 = t & 63, cog = t >> 6;
    const float* sb = src + (size_t)p * 262144 + tile * 256 + xy4 * 4;
    float4 acc[16];
#pragma unroll
    for (int j = 0; j < 16; ++j) {
        float bv = bs[cog * 16 + j];
        acc[j] = make_float4(bv, bv, bv, bv);
    }
    for (int ci = 0; ci < 64; ++ci) {
        float4 sv = LD4(sb + (size_t)ci * 4096);
        float4 w0 = *(const float4*)(&ws[ci][cog * 16]);
        float4 w1 = *(const float4*)(&ws[ci][cog * 16 + 4]);
        float4 w2 = *(const float4*)(&ws[ci][cog * 16 + 8]);
        float4 w3 = *(const float4*)(&ws[ci][cog * 16 + 12]);
        float wr[16] = {w0.x, w0.y, w0.z, w0.w, w1.x, w1.y, w1.z, w1.w,
                        w2.x, w2.y, w2.z, w2.w, w3.x, w3.y, w3.z, w3.w};
#pragma unroll
        for (int j = 0; j < 16; ++j) {
            float w = wr[j];
            acc[j].x += sv.x * w; acc[j].y += sv.y * w;
            acc[j].z += sv.z * w; acc[j].w += sv.w * w;
        }
    }
    float4 part = make_float4(0.f, 0.f, 0.f, 0.f);
#pragma unroll
    for (int j = 0; j < 16; ++j) {
        float w = w2s[cog * 16 + j];
        part.x += gelu_f(acc[j].x) * w;
        part.y += gelu_f(acc[j].y) * w;
        part.z += gelu_f(acc[j].z) * w;
        part.w += gelu_f(acc[j].w) * w;
    }
    red[cog][xy4] = part;
    __syncthreads();
    if (t < 64) {
        float4 s0 = red[0][t], s1 = red[1][t], s2 = red[2][t], s3 = red[3][t];
        float wgt = pw[p];
        float b2 = p2b[e];
        int b = pair_b[p];
        float* ob = out + (size_t)b * 4096 + tile * 256 + t * 4;
        atomicAdd(ob,     wgt * (s0.x + s1.x + s2.x + s3.x + b2));
        atomicAdd(ob + 1, wgt * (s0.y + s1.y + s2.y + s3.y + b2));
        atomicAdd(ob + 2, wgt * (s0.z + s1.z + s2.z + s3.z + b2));
        atomicAdd(ob + 3, wgt * (s0.w + s1.w + s2.w + s3.w + b2));
    }
}

// ---------------- inverse DFT v3: one (p,co) per block, table twiddles ----------------
__global__ __launch_bounds__(256) void inv_kernel(
    const float* __restrict__ FoA, const float* __restrict__ FoB,
    const float* __restrict__ WY2, const float* __restrict__ TWX,
    float* __restrict__ dst_h, int do_gelu)
{
    __shared__ float wy2[2048];
    __shared__ float twl[128];
    __shared__ float fo_s[1024];
    __shared__ float tT[64][36];
    __shared__ float ot[64][66];
    int t = threadIdx.x;
    for (int i = t; i < 512; i += 256) *(float4*)(&wy2[i * 4]) = *(const float4*)(WY2 + i * 4);
    if (t < 32) *(float4*)(&twl[t * 4]) = LD4(TWX + 128 + t * 4);
    int wid = blockIdx.x;
    int p = wid >> 6, co = wid & 63;
    const float* fA = FoA + (size_t)p * 65536 + (size_t)co * 1024;
    const float* fB = FoB + (size_t)p * 65536 + (size_t)co * 1024;
    {
        float4 a = LD4(fA + t * 4);
        float4 b = LD4(fB + t * 4);
        *(float4*)(&fo_s[t * 4]) = make_float4(a.x + b.x, a.y + b.y, a.z + b.z, a.w + b.w);
    }
    __syncthreads();
    {
        int xx = t & 63, kq = t >> 6;
        float Tr0 = 0.f, Ti0 = 0.f, Tr1 = 0.f, Ti1 = 0.f;
        float Tr2 = 0.f, Ti2 = 0.f, Tr3 = 0.f, Ti3 = 0.f;
#pragma unroll 4
        for (int kxm = 0; kxm < 32; ++kxm) {
            int kx = kxm < 16 ? kxm : kxm + 32;
            int idx = (kx * xx) & 63;
            float c_ = twl[2 * idx], s_ = twl[2 * idx + 1];
            float4 f0 = *(const float4*)(&fo_s[kxm * 32 + kq * 8]);
            float4 f1 = *(const float4*)(&fo_s[kxm * 32 + kq * 8 + 4]);
            Tr0 += f0.x * c_ - f0.y * s_;  Ti0 += f0.x * s_ + f0.y * c_;
            Tr1 += f0.z * c_ - f0.w * s_;  Ti1 += f0.z * s_ + f0.w * c_;
            Tr2 += f1.x * c_ - f1.y * s_;  Ti2 += f1.x * s_ + f1.y * c_;
            Tr3 += f1.z * c_ - f1.w * s_;  Ti3 += f1.z * s_ + f1.w * c_;
        }
        *(float4*)(&tT[xx][kq * 8])     = make_float4(Tr0, Ti0, Tr1, Ti1);
        *(float4*)(&tT[xx][kq * 8 + 4]) = make_float4(Tr2, Ti2, Tr3, Ti3);
    }
    __syncthreads();
    {
        int xx = t & 63, yq = t >> 6;
        float Trr[16], Tii[16];
#pragma unroll
        for (int q = 0; q < 8; ++q) {
            float4 v = *(const float4*)(&tT[xx][q * 4]);
            Trr[q * 2] = v.x; Tii[q * 2] = v.y;
            Trr[q * 2 + 1] = v.z; Tii[q * 2 + 1] = v.w;
        }
        for (int j = 0; j < 16; ++j) {
            int y = yq * 16 + j;
            const float* wr = &wy2[y * 32];
            float acc = 0.f;
#pragma unroll
            for (int k = 0; k < 16; ++k)
                acc += Trr[k] * wr[2 * k] - Tii[k] * wr[2 * k + 1];
            ot[xx][y] = acc;
        }
    }
    __syncthreads();
    {
        float* base = dst_h + (size_t)p * 262144 + (size_t)co * 4096;
        for (int r = 0; r < 16; ++r) {
            int gidx = r * 256 + t;
            int xx = gidx >> 6, y = gidx & 63;
            float v = base[gidx] + ot[xx][y];
            if (do_gelu) v = gelu_f(v);
            base[gidx] = v;
        }
    }
}

// ---------------- launch ----------------
extern "C" void kernel_launch(void* const* d_in, const int* in_sizes, int n_in,
                              void* d_out, int out_size, void* d_ws, size_t ws_size,
                              hipStream_t stream) {
    const float* x    = (const float*)d_in[0];
    const float* encw = (const float*)d_in[1];
    const float* encb = (const float*)d_in[2];
    const float* wqkv = (const float*)d_in[3];
    const float* bqkv = (const float*)d_in[4];
    const float* wo   = (const float*)d_in[5];
    const float* bo   = (const float*)d_in[6];
    const float* ln1g = (const float*)d_in[7];
    const float* ln1b = (const float*)d_in[8];
    const float* fw1  = (const float*)d_in[9];
    const float* fb1  = (const float*)d_in[10];
    const float* fw2  = (const float*)d_in[11];
    const float* fb2  = (const float*)d_in[12];
    const float* ln2g = (const float*)d_in[13];
    const float* ln2b = (const float*)d_in[14];
    const float* fcw  = (const float*)d_in[15];
    const float* fcb  = (const float*)d_in[16];
    const float* lw   = (const float*)d_in[17];
    const float* lb   = (const float*)d_in[18];
    const float* sw1  = (const float*)d_in[19];
    const float* sw2  = (const float*)d_in[20];
    const float* skw  = (const float*)d_in[21];
    const float* skb  = (const float*)d_in[22];
    const float* p1w  = (const float*)d_in[23];
    const float* p1b  = (const float*)d_in[24];
    const float* p2w  = (const float*)d_in[25];
    const float* p2b  = (const float*)d_in[26];
    float* out = (float*)d_out;

    float* wsf    = (float*)d_ws;
    float* rw     = wsf;               // 256
    float* pair_w = wsf + 256;         // 64
    int*   ipart  = (int*)(wsf + 320); // 192 ints available
    int* pair_b   = ipart;             // 64
    int* pair_e   = ipart + 64;        // 64
    int* estart   = ipart + 128;       // 9
    int* chunk_e  = ipart + 137;       // 16
    int* chunk_p0 = ipart + 153;       // 16
    int* chunk_np = ipart + 169;       // 16
    float* Wy  = wsf + 512;            // 2048
    float* TWX = wsf + 2560;           // 256 used (4096 reserved)
    float* WY2 = wsf + 6656;           // 2048
    float* hA  = wsf + 16384;                       // 64 * 262144
    float* hB  = hA + (size_t)64 * 262144;          // 64 * 262144 (unused now)
    float* F   = hB + (size_t)64 * 262144;          // 64 * 65536
    float* FoA = F + (size_t)64 * 65536;            // 64 * 65536
    float* FoB = FoA + (size_t)64 * 65536;          // 64 * 65536
    size_t need = (16384 + 2ull * 64 * 262144 + 64ull * 65536 + 64ull * 131072) * 4;
    if (ws_size < need) return;

    hipMemsetAsync(d_out, 0, (size_t)out_size * sizeof(float), stream);
    init_tables_kernel<<<1, 256, 0, stream>>>(Wy, TWX, WY2);
    router_kernel<<<32, 512, 0, stream>>>(x, encw, encb, wqkv, bqkv, wo, bo, ln1g, ln1b,
                                          fw1, fb1, fw2, fb2, ln2g, ln2b, fcw, fcb, rw);
    build_pairs_kernel<<<1, 64, 0, stream>>>(rw, pair_b, pair_e, pair_w, estart,
                                             chunk_e, chunk_p0, chunk_np);
    lift_kernel<<<dim3(64, 16), 256, 0, stream>>>(x, lw, lb, pair_b, pair_e, hA);
    for (int l = 0; l < 4; ++l) {
        float* cur = (l & 1) ? hB : hA;
        float* nxt = (l & 1) ? hA : hB;
        fwdft_kernel<<<4096, 256, 0, stream>>>(cur, Wy, TWX, F);
        spectral_kernel<<<dim3(16, 16, 8), 256, 0, stream>>>(F, FoA, FoB, sw1, sw2,
                                                             chunk_e, chunk_p0, chunk_np, l);
        conv1x1_kernel<<<dim3(64, 16), 256, 0, stream>>>(cur, nxt, skw, skb, pair_e, 4, l, 0);
        inv_kernel<<<4096, 256, 0, stream>>>(FoA, FoB, WY2, TWX, nxt, (l < 3) ? 1 : 0);
    }
    projfused_kernel<<<dim3(64, 16), 256, 0, stream>>>(hA, p1w, p1b, p2w, p2b,
                                                       pair_b, pair_e, pair_w, out);
}

// Round 17
// 1300.191 us; speedup vs baseline: 8.7403x; 1.0167x over previous
//
#include <hip/hip_runtime.h>
#include <math.h>

#define TWOPI_F 6.283185307179586f
#define LD4(p) (*(const float4*)(p))

__device__ __forceinline__ float gelu_f(float v) {
    float u = 0.7978845608028654f * (v + 0.044715f * v * v * v);
    return 0.5f * v * (1.f + tanhf(u));
}

// ---------------- twiddle tables ----------------
__global__ void init_tables_kernel(float* __restrict__ Wy, float* __restrict__ TWX,
                                   float* __restrict__ WY2) {
    int t = threadIdx.x;
    for (int i = t; i < 1024; i += 256) {
        int y = i >> 4, k = i & 15;
        int m = (k * y) & 63;
        float a = -TWOPI_F * (float)m / 64.f;
        Wy[y * 32 + 2 * k]     = cosf(a);
        Wy[y * 32 + 2 * k + 1] = sinf(a);
    }
    if (t < 64) {
        float a = -TWOPI_F * (float)t / 64.f;
        TWX[2 * t]           = cosf(a);
        TWX[2 * t + 1]       = sinf(a);
        TWX[128 + 2 * t]     = cosf(a);
        TWX[128 + 2 * t + 1] = -sinf(a);
    }
    for (int i = t; i < 1024; i += 256) {
        int y = i >> 4, k = i & 15;
        int m = (k * y) & 63;
        float a = TWOPI_F * (float)m / 64.f;
        float sc = (k == 0 ? 1.f : 2.f) / 4096.f;
        WY2[y * 32 + 2 * k]     = sc * cosf(a);
        WY2[y * 32 + 2 * k + 1] = sc * sinf(a);
    }
}

// ---------------- router v4: all-heads-parallel attention ----------------
__global__ __launch_bounds__(512) void router_kernel(
    const float* __restrict__ x, const float* __restrict__ enc_w, const float* __restrict__ enc_b,
    const float* __restrict__ wqkv, const float* __restrict__ bqkv,
    const float* __restrict__ wo, const float* __restrict__ bo,
    const float* __restrict__ ln1g, const float* __restrict__ ln1b,
    const float* __restrict__ w1, const float* __restrict__ b1,
    const float* __restrict__ w2, const float* __restrict__ b2,
    const float* __restrict__ ln2g, const float* __restrict__ ln2b,
    const float* __restrict__ fcw, const float* __restrict__ fcb,
    float* __restrict__ rw)
{
    __shared__ float s[64][65];
    __shared__ float qk[64][193];
    __shared__ float scH[4][64][65];
    __shared__ float o64[64][65];
    __shared__ float feat[64];
    __shared__ float logits[8];
    int b = blockIdx.x, t = threadIdx.x;

    for (int i = t; i < 4096; i += 512) {
        int w_ = i >> 6, d = i & 63;
        s[w_][d] = x[b * 4096 + w_] * enc_w[d] + enc_b[d];
    }
    __syncthreads();

    for (int l = 0; l < 2; ++l) {
        // ---- QKV
        {
            const float* Wq = wqkv + l * 64 * 192;
            const float* Bq = bqkv + l * 192;
            int c4 = t % 48, rg = t / 48;
            if (rg < 8) {
                const float* wcol = Wq + 4 * c4;
                float4 bq = LD4(Bq + 4 * c4);
                float4 acc[8];
#pragma unroll
                for (int i = 0; i < 8; ++i) acc[i] = bq;
                int r0 = rg * 8;
#pragma unroll 8
                for (int k = 0; k < 64; ++k) {
                    float4 wv = LD4(wcol + k * 192);
#pragma unroll
                    for (int i = 0; i < 8; ++i) {
                        float sv = s[r0 + i][k];
                        acc[i].x += sv * wv.x; acc[i].y += sv * wv.y;
                        acc[i].z += sv * wv.z; acc[i].w += sv * wv.w;
                    }
                }
#pragma unroll
                for (int i = 0; i < 8; ++i) {
                    qk[r0 + i][4 * c4]     = acc[i].x;
                    qk[r0 + i][4 * c4 + 1] = acc[i].y;
                    qk[r0 + i][4 * c4 + 2] = acc[i].z;
                    qk[r0 + i][4 * c4 + 3] = acc[i].w;
                }
            }
        }
        __syncthreads();
        // ---- scores, all 4 heads at once (16384 items)
        for (int i = t; i < 16384; i += 512) {
            int h = i >> 12, q = (i >> 6) & 63, kj = i & 63;
            float acc = 0.f;
#pragma unroll
            for (int d = 0; d < 16; ++d)
                acc += qk[q][h * 16 + d] * qk[kj][64 + h * 16 + d];
            scH[h][q][kj] = acc * 0.25f;
        }
        __syncthreads();
        // ---- softmax: 256 rows (h,q) at once
        if (t < 256) {
            int h = t >> 6, q = t & 63;
            float* row = scH[h][q];
            float m = -1e30f;
            for (int j = 0; j < 64; ++j) m = fmaxf(m, row[j]);
            float sum = 0.f;
            for (int j = 0; j < 64; ++j) { float e2 = expf(row[j] - m); row[j] = e2; sum += e2; }
            float inv = 1.f / sum;
            for (int j = 0; j < 64; ++j) row[j] *= inv;
        }
        __syncthreads();
        // ---- PV, all heads (4096 items)
        for (int i = t; i < 4096; i += 512) {
            int q = i >> 6, d = i & 63, h = d >> 4;
            float acc = 0.f;
#pragma unroll 8
            for (int j = 0; j < 64; ++j) acc += scH[h][q][j] * qk[j][128 + d];
            o64[q][d] = acc;
        }
        __syncthreads();
        // ---- attn out proj + residual -> scH[0]
        {
            const float* Wo = wo + l * 4096;
            const float* Bo = bo + l * 64;
            int c4 = t & 15, rg = t >> 4;
            const float* wcol = Wo + 4 * c4;
            float4 acc0 = LD4(Bo + 4 * c4), acc1 = acc0;
            int r0 = rg * 2;
#pragma unroll 8
            for (int k = 0; k < 64; ++k) {
                float4 wv = LD4(wcol + k * 64);
                float h0 = o64[r0][k], h1 = o64[r0 + 1][k];
                acc0.x += h0 * wv.x; acc0.y += h0 * wv.y;
                acc0.z += h0 * wv.z; acc0.w += h0 * wv.w;
                acc1.x += h1 * wv.x; acc1.y += h1 * wv.y;
                acc1.z += h1 * wv.z; acc1.w += h1 * wv.w;
            }
            scH[0][r0][4 * c4]     = s[r0][4 * c4]     + acc0.x;
            scH[0][r0][4 * c4 + 1] = s[r0][4 * c4 + 1] + acc0.y;
            scH[0][r0][4 * c4 + 2] = s[r0][4 * c4 + 2] + acc0.z;
            scH[0][r0][4 * c4 + 3] = s[r0][4 * c4 + 3] + acc0.w;
            scH[0][r0 + 1][4 * c4]     = s[r0 + 1][4 * c4]     + acc1.x;
            scH[0][r0 + 1][4 * c4 + 1] = s[r0 + 1][4 * c4 + 1] + acc1.y;
            scH[0][r0 + 1][4 * c4 + 2] = s[r0 + 1][4 * c4 + 2] + acc1.z;
            scH[0][r0 + 1][4 * c4 + 3] = s[r0 + 1][4 * c4 + 3] + acc1.w;
        }
        __syncthreads();
        if (t < 64) {  // LN1: scH[0] -> s
            float m = 0.f;
            for (int j = 0; j < 64; ++j) m += scH[0][t][j];
            m *= (1.f / 64.f);
            float v = 0.f;
            for (int j = 0; j < 64; ++j) { float d = scH[0][t][j] - m; v += d * d; }
            v *= (1.f / 64.f);
            float inv = rsqrtf(v + 1e-5f);
            for (int j = 0; j < 64; ++j)
                s[t][j] = (scH[0][t][j] - m) * inv * ln1g[l * 64 + j] + ln1b[l * 64 + j];
        }
        __syncthreads();
        // ---- FFN1 + relu (hidden: qk cols 0..191, o64 cols 0..63)
        {
            const float* W1 = w1 + l * 64 * 256;
            const float* B1 = b1 + l * 256;
            int c4 = t & 63, rg = t >> 6;
            const float* wcol = W1 + 4 * c4;
            float4 b1v = LD4(B1 + 4 * c4);
            float4 acc[8];
#pragma unroll
            for (int i = 0; i < 8; ++i) acc[i] = b1v;
            int r0 = rg * 8;
#pragma unroll 4
            for (int k = 0; k < 64; ++k) {
                float4 wv = LD4(wcol + k * 256);
#pragma unroll
                for (int i = 0; i < 8; ++i) {
                    float sv = s[r0 + i][k];
                    acc[i].x += sv * wv.x; acc[i].y += sv * wv.y;
                    acc[i].z += sv * wv.z; acc[i].w += sv * wv.w;
                }
            }
#pragma unroll
            for (int i = 0; i < 8; ++i) {
                float a0 = fmaxf(acc[i].x, 0.f), a1 = fmaxf(acc[i].y, 0.f);
                float a2 = fmaxf(acc[i].z, 0.f), a3 = fmaxf(acc[i].w, 0.f);
                if (c4 < 48) {
                    qk[r0 + i][4 * c4] = a0; qk[r0 + i][4 * c4 + 1] = a1;
                    qk[r0 + i][4 * c4 + 2] = a2; qk[r0 + i][4 * c4 + 3] = a3;
                } else {
                    int c = 4 * c4 - 192;
                    o64[r0 + i][c] = a0; o64[r0 + i][c + 1] = a1;
                    o64[r0 + i][c + 2] = a2; o64[r0 + i][c + 3] = a3;
                }
            }
        }
        __syncthreads();
        // ---- FFN2 + residual -> scH[0]
        {
            const float* W2 = w2 + l * 256 * 64;
            const float* B2 = b2 + l * 64;
            int c4 = t & 15, rg = t >> 4;
            const float* wcol = W2 + 4 * c4;
            float4 acc0 = LD4(B2 + 4 * c4), acc1 = acc0;
            int r0 = rg * 2;
#pragma unroll 8
            for (int k = 0; k < 192; ++k) {
                float4 wv = LD4(wcol + k * 64);
                float h0 = qk[r0][k], h1 = qk[r0 + 1][k];
                acc0.x += h0 * wv.x; acc0.y += h0 * wv.y;
                acc0.z += h0 * wv.z; acc0.w += h0 * wv.w;
                acc1.x += h1 * wv.x; acc1.y += h1 * wv.y;
                acc1.z += h1 * wv.z; acc1.w += h1 * wv.w;
            }
#pragma unroll 8
            for (int k = 192; k < 256; ++k) {
                float4 wv = LD4(wcol + k * 64);
                float h0 = o64[r0][k - 192], h1 = o64[r0 + 1][k - 192];
                acc0.x += h0 * wv.x; acc0.y += h0 * wv.y;
                acc0.z += h0 * wv.z; acc0.w += h0 * wv.w;
                acc1.x += h1 * wv.x; acc1.y += h1 * wv.y;
                acc1.z += h1 * wv.z; acc1.w += h1 * wv.w;
            }
            scH[0][r0][4 * c4]     = s[r0][4 * c4]     + acc0.x;
            scH[0][r0][4 * c4 + 1] = s[r0][4 * c4 + 1] + acc0.y;
            scH[0][r0][4 * c4 + 2] = s[r0][4 * c4 + 2] + acc0.z;
            scH[0][r0][4 * c4 + 3] = s[r0][4 * c4 + 3] + acc0.w;
            scH[0][r0 + 1][4 * c4]     = s[r0 + 1][4 * c4]     + acc1.x;
            scH[0][r0 + 1][4 * c4 + 1] = s[r0 + 1][4 * c4 + 1] + acc1.y;
            scH[0][r0 + 1][4 * c4 + 2] = s[r0 + 1][4 * c4 + 2] + acc1.z;
            scH[0][r0 + 1][4 * c4 + 3] = s[r0 + 1][4 * c4 + 3] + acc1.w;
        }
        __syncthreads();
        if (t < 64) {  // LN2: scH[0] -> s
            float m = 0.f;
            for (int j = 0; j < 64; ++j) m += scH[0][t][j];
            m *= (1.f / 64.f);
            float v = 0.f;
            for (int j = 0; j < 64; ++j) { float d = scH[0][t][j] - m; v += d * d; }
            v *= (1.f / 64.f);
            float inv = rsqrtf(v + 1e-5f);
            for (int j = 0; j < 64; ++j)
                s[t][j] = (scH[0][t][j] - m) * inv * ln2g[l * 64 + j] + ln2b[l * 64 + j];
        }
        __syncthreads();
    }
    if (t < 64) {
        float m = -1e30f;
        for (int r = 0; r < 64; ++r) m = fmaxf(m, s[r][t]);
        feat[t] = m;
    }
    __syncthreads();
    if (t < 8) {
        float acc = fcb[t];
        for (int k = 0; k < 64; ++k) acc += feat[k] * fcw[k * 8 + t];
        logits[t] = acc;
    }
    __syncthreads();
    if (t == 0) {
        int i0 = 0;
        for (int j = 1; j < 8; ++j) if (logits[j] > logits[i0]) i0 = j;
        int i1 = -1;
        for (int j = 0; j < 8; ++j) {
            if (j == i0) continue;
            if (i1 < 0 || logits[j] > logits[i1]) i1 = j;
        }
        float e1 = expf(logits[i1] - logits[i0]);
        float w0 = 1.f / (1.f + e1);
        float w1v = e1 / (1.f + e1);
        for (int j = 0; j < 8; ++j) rw[b * 8 + j] = 0.f;
        rw[b * 8 + i0] = w0;
        rw[b * 8 + i1] = w1v;
    }
}

// ---------------- build pairs + balanced chunk table ----------------
__global__ void build_pairs_kernel(const float* __restrict__ rw, int* __restrict__ pair_b,
                                   int* __restrict__ pair_e, float* __restrict__ pair_w,
                                   int* __restrict__ estart, int* __restrict__ chunk_e,
                                   int* __restrict__ chunk_p0, int* __restrict__ chunk_np) {
    __shared__ float r[256];
    __shared__ int cnt[8], off[9];
    int t = threadIdx.x;
    for (int i = t; i < 256; i += 64) r[i] = rw[i];
    if (t < 64) { pair_b[t] = 0; pair_e[t] = 0; pair_w[t] = 0.f; }
    __syncthreads();
    if (t < 8) {
        int c = 0;
        for (int b = 0; b < 32; ++b) if (r[b * 8 + t] != 0.f) ++c;
        cnt[t] = c;
    }
    __syncthreads();
    if (t == 0) {
        int a = 0;
        for (int e = 0; e < 8; ++e) { off[e] = a; a += cnt[e]; }
        off[8] = a;
        for (int e = 0; e <= 8; ++e) estart[e] = off[e];
        int nc = 0;
        for (int e = 0; e < 8; ++e) {
            for (int s = off[e]; s < off[e + 1]; s += 8) {
                int np = off[e + 1] - s; if (np > 8) np = 8;
                chunk_e[nc] = e; chunk_p0[nc] = s; chunk_np[nc] = np; ++nc;
            }
        }
        for (int c = nc; c < 16; ++c) { chunk_e[c] = 0; chunk_p0[c] = 0; chunk_np[c] = 0; }
    }
    __syncthreads();
    if (t < 8) {
        int n = off[t];
        for (int b = 0; b < 32; ++b) {
            float w = r[b * 8 + t];
            if (w != 0.f) { pair_b[n] = b; pair_e[n] = t; pair_w[n] = w; ++n; }
        }
    }
}

// ---------------- fused forward DFT v3 (generic, reads h) ----------------
__global__ __launch_bounds__(256) void fwdft_kernel(const float* __restrict__ h,
    const float* __restrict__ Wy, const float* __restrict__ TWX, float* __restrict__ F) {
    __shared__ float ht[64][68];
    __shared__ float gt[64][36];
    __shared__ float wy[2048];
    __shared__ float tw64[128];
    int bid = blockIdx.x;
    int t = threadIdx.x;
    const float* src = h + (size_t)bid * 4096;
    for (int i = t; i < 1024; i += 256) {
        float4 v = *(const float4*)(src + i * 4);
        int x = (i * 4) >> 6, y = (i * 4) & 63;
        *(float4*)(&ht[x][y]) = v;
    }
    for (int i = t; i < 512; i += 256) *(float4*)(&wy[i * 4]) = *(const float4*)(Wy + i * 4);
    if (t < 32) *(float4*)(&tw64[t * 4]) = LD4(TWX + t * 4);
    __syncthreads();
    {
        int xx = t >> 2, kq = t & 3;
        float gr0 = 0.f, gi0 = 0.f, gr1 = 0.f, gi1 = 0.f;
        float gr2 = 0.f, gi2 = 0.f, gr3 = 0.f, gi3 = 0.f;
#pragma unroll 4
        for (int y = 0; y < 64; ++y) {
            float hv = ht[xx][y];
            float4 w0 = *(const float4*)(&wy[y * 32 + kq * 8]);
            float4 w1 = *(const float4*)(&wy[y * 32 + kq * 8 + 4]);
            gr0 += hv * w0.x; gi0 += hv * w0.y;
            gr1 += hv * w0.z; gi1 += hv * w0.w;
            gr2 += hv * w1.x; gi2 += hv * w1.y;
            gr3 += hv * w1.z; gi3 += hv * w1.w;
        }
        *(float4*)(&gt[xx][kq * 8])     = make_float4(gr0, gi0, gr1, gi1);
        *(float4*)(&gt[xx][kq * 8 + 4]) = make_float4(gr2, gi2, gr3, gi3);
    }
    __syncthreads();
    {
        int kxm = t & 31, kyq = t >> 5;
        int kx = kxm < 16 ? kxm : kxm + 32;
        float ar0 = 0.f, ai0 = 0.f, ar1 = 0.f, ai1 = 0.f;
        int idx = 0;
#pragma unroll 4
        for (int xx = 0; xx < 64; ++xx) {
            float c_ = tw64[2 * idx], s_ = tw64[2 * idx + 1];
            float4 g = *(const float4*)(&gt[xx][kyq * 4]);
            ar0 += g.x * c_ - g.y * s_;  ai0 += g.x * s_ + g.y * c_;
            ar1 += g.z * c_ - g.w * s_;  ai1 += g.z * s_ + g.w * c_;
            idx = (idx + kx) & 63;
        }
        float* fb = F + (size_t)bid * 1024 + kxm * 32 + kyq * 4;
        *(float4*)(fb) = make_float4(ar0, ai0, ar1, ai1);
    }
}

// ---------------- fwdft l=0 variant: computes lift on the fly from x ----------------
__global__ __launch_bounds__(256) void fwdft_x_kernel(const float* __restrict__ x,
    const float* __restrict__ lw, const float* __restrict__ lb,
    const int* __restrict__ pair_b, const int* __restrict__ pair_e,
    const float* __restrict__ Wy, const float* __restrict__ TWX, float* __restrict__ F) {
    __shared__ float ht[64][68];
    __shared__ float gt[64][36];
    __shared__ float wy[2048];
    __shared__ float tw64[128];
    int bid = blockIdx.x;
    int t = threadIdx.x;
    int p = bid >> 6, ci = bid & 63;
    int e = pair_e[p], b = pair_b[p];
    float lwv = lw[e * 64 + ci];
    float lbv = lb[e * 64 + ci];
    const float* src = x + (size_t)b * 4096;
    for (int i = t; i < 1024; i += 256) {
        float4 v = *(const float4*)(src + i * 4);
        v.x = v.x * lwv + lbv; v.y = v.y * lwv + lbv;
        v.z = v.z * lwv + lbv; v.w = v.w * lwv + lbv;
        int xx = (i * 4) >> 6, y = (i * 4) & 63;
        *(float4*)(&ht[xx][y]) = v;
    }
    for (int i = t; i < 512; i += 256) *(float4*)(&wy[i * 4]) = *(const float4*)(Wy + i * 4);
    if (t < 32) *(float4*)(&tw64[t * 4]) = LD4(TWX + t * 4);
    __syncthreads();
    {
        int xx = t >> 2, kq = t & 3;
        float gr0 = 0.f, gi0 = 0.f, gr1 = 0.f, gi1 = 0.f;
        float gr2 = 0.f, gi2 = 0.f, gr3 = 0.f, gi3 = 0.f;
#pragma unroll 4
        for (int y = 0; y < 64; ++y) {
            float hv = ht[xx][y];
            float4 w0 = *(const float4*)(&wy[y * 32 + kq * 8]);
            float4 w1 = *(const float4*)(&wy[y * 32 + kq * 8 + 4]);
            gr0 += hv * w0.x; gi0 += hv * w0.y;
            gr1 += hv * w0.z; gi1 += hv * w0.w;
            gr2 += hv * w1.x; gi2 += hv * w1.y;
            gr3 += hv * w1.z; gi3 += hv * w1.w;
        }
        *(float4*)(&gt[xx][kq * 8])     = make_float4(gr0, gi0, gr1, gi1);
        *(float4*)(&gt[xx][kq * 8 + 4]) = make_float4(gr2, gi2, gr3, gi3);
    }
    __syncthreads();
    {
        int kxm = t & 31, kyq = t >> 5;
        int kx = kxm < 16 ? kxm : kxm + 32;
        float ar0 = 0.f, ai0 = 0.f, ar1 = 0.f, ai1 = 0.f;
        int idx = 0;
#pragma unroll 4
        for (int xx = 0; xx < 64; ++xx) {
            float c_ = tw64[2 * idx], s_ = tw64[2 * idx + 1];
            float4 g = *(const float4*)(&gt[xx][kyq * 4]);
            ar0 += g.x * c_ - g.y * s_;  ai0 += g.x * s_ + g.y * c_;
            ar1 += g.z * c_ - g.w * s_;  ai1 += g.z * s_ + g.w * c_;
            idx = (idx + kx) & 63;
        }
        float* fb = F + (size_t)bid * 1024 + kxm * 32 + kyq * 4;
        *(float4*)(fb) = make_float4(ar0, ai0, ar1, ai1);
    }
}

// ---------------- spectral v11: chunk-balanced (R14 proven) ----------------
__global__ __launch_bounds__(256) void spectral_kernel(
    const float* __restrict__ F, float* __restrict__ FoA, float* __restrict__ FoB,
    const float* __restrict__ w1, const float* __restrict__ w2,
    const int* __restrict__ chunk_e, const int* __restrict__ chunk_p0,
    const int* __restrict__ chunk_np, int l)
{
    int c = blockIdx.x;
    int np = chunk_np[c];
    if (np == 0) return;
    int e = chunk_e[c], p0 = chunk_p0[c];
    int z = blockIdx.z;
    int wsel = z & 1, cih = (z >> 1) & 1, mq = z >> 2;
    int t = threadIdx.x;
    int co = blockIdx.y * 4 + (t >> 6);
    int lane = t & 63;
    int moff = mq * 256 + lane * 4;

    const float* wbase = (wsel == 0 ? w1 : w2) + (size_t)(e * 4 + l) * 2097152;
    const float* Wc  = wbase + (size_t)(cih * 32) * 32768 + (size_t)co * 512 + moff;
    const float* Fc0 = F + (size_t)p0 * 65536 + (size_t)(cih * 32) * 1024 + wsel * 512 + moff;
    float* Fob = (cih ? FoB : FoA) + (size_t)p0 * 65536 + (size_t)co * 1024 + wsel * 512 + moff;

    float4 acc[8];
#pragma unroll
    for (int p = 0; p < 8; ++p) acc[p] = make_float4(0.f, 0.f, 0.f, 0.f);
    const float* Wp = Wc;
    const float* Fp = Fc0;
    for (int ci = 0; ci < 32; ++ci) {
        float4 wv = LD4(Wp);
#pragma unroll
        for (int p = 0; p < 8; ++p) {
            float4 fv = LD4(Fp + (size_t)p * 65536);
            acc[p].x += fv.x * wv.x - fv.y * wv.y;
            acc[p].y += fv.x * wv.y + fv.y * wv.x;
            acc[p].z += fv.z * wv.z - fv.w * wv.w;
            acc[p].w += fv.z * wv.w + fv.w * wv.z;
        }
        Wp += 32768;
        Fp += 1024;
    }
#pragma unroll
    for (int p = 0; p < 8; ++p) {
        if (p < np)
            *(float4*)(Fob + (size_t)p * 65536) = acc[p];
    }
}

// ---------------- conv1x1 v2 (generic, reads src) ----------------
__global__ __launch_bounds__(256) void conv1x1_kernel(
    const float* __restrict__ src, float* __restrict__ dst,
    const float* __restrict__ Wall, const float* __restrict__ Ball,
    const int* __restrict__ pair_e, int wmul, int wadd, int do_gelu)
{
    __shared__ float ws[64][68];
    __shared__ float bs[64];
    int p = blockIdx.x, tile = blockIdx.y, t = threadIdx.x;
    int e = pair_e[p];
    int widx = e * wmul + wadd;
    const float* W = Wall + (size_t)widx * 4096;
    for (int i = t; i < 1024; i += 256) {
        float4 v = LD4(W + i * 4);
        int ci = (i * 4) >> 6, co = (i * 4) & 63;
        *(float4*)(&ws[ci][co]) = v;
    }
    if (t < 64) bs[t] = Ball[widx * 64 + t];
    __syncthreads();

    int xy4 = t & 63, cog = t >> 6;
    const float* sb = src + (size_t)p * 262144 + tile * 256 + xy4 * 4;
    float4 acc[16];
#pragma unroll
    for (int j = 0; j < 16; ++j) {
        float bv = bs[cog * 16 + j];
        acc[j] = make_float4(bv, bv, bv, bv);
    }
    for (int ci = 0; ci < 64; ++ci) {
        float4 sv = LD4(sb + (size_t)ci * 4096);
        float4 w0 = *(const float4*)(&ws[ci][cog * 16]);
        float4 w1 = *(const float4*)(&ws[ci][cog * 16 + 4]);
        float4 w2 = *(const float4*)(&ws[ci][cog * 16 + 8]);
        float4 w3 = *(const float4*)(&ws[ci][cog * 16 + 12]);
        float wr[16] = {w0.x, w0.y, w0.z, w0.w, w1.x, w1.y, w1.z, w1.w,
                        w2.x, w2.y, w2.z, w2.w, w3.x, w3.y, w3.z, w3.w};
#pragma unroll
        for (int j = 0; j < 16; ++j) {
            float w = wr[j];
            acc[j].x += sv.x * w; acc[j].y += sv.y * w;
            acc[j].z += sv.z * w; acc[j].w += sv.w * w;
        }
    }
    float* d = dst + (size_t)p * 262144 + (size_t)(cog * 16) * 4096 + tile * 256 + xy4 * 4;
#pragma unroll
    for (int j = 0; j < 16; ++j) {
        float4 v = acc[j];
        if (do_gelu) {
            v.x = gelu_f(v.x); v.y = gelu_f(v.y);
            v.z = gelu_f(v.z); v.w = gelu_f(v.w);
        }
        *(float4*)(d + (size_t)j * 4096) = v;
    }
}

// ---------------- conv1x1 l=0 variant: lift fused (reads x, 16KB/block) ----------------
__global__ __launch_bounds__(256) void conv1x1_x_kernel(
    const float* __restrict__ x, float* __restrict__ dst,
    const float* __restrict__ Wall, const float* __restrict__ Ball,
    const float* __restrict__ lw, const float* __restrict__ lb,
    const int* __restrict__ pair_b, const int* __restrict__ pair_e)
{
    __shared__ float ws[64][68];
    __shared__ float bs[64];
    __shared__ float lws[64];
    __shared__ float lbs[64];
    int p = blockIdx.x, tile = blockIdx.y, t = threadIdx.x;
    int e = pair_e[p], b = pair_b[p];
    int widx = e * 4;   // skw layer 0
    const float* W = Wall + (size_t)widx * 4096;
    for (int i = t; i < 1024; i += 256) {
        float4 v = LD4(W + i * 4);
        int ci = (i * 4) >> 6, co = (i * 4) & 63;
        *(float4*)(&ws[ci][co]) = v;
    }
    if (t < 64) {
        bs[t]  = Ball[widx * 64 + t];
        lws[t] = lw[e * 64 + t];
        lbs[t] = lb[e * 64 + t];
    }
    __syncthreads();

    int xy4 = t & 63, cog = t >> 6;
    float4 xv = LD4(x + (size_t)b * 4096 + tile * 256 + xy4 * 4);
    float4 acc[16];
#pragma unroll
    for (int j = 0; j < 16; ++j) {
        float bv = bs[cog * 16 + j];
        acc[j] = make_float4(bv, bv, bv, bv);
    }
    for (int ci = 0; ci < 64; ++ci) {
        float lwv = lws[ci], lbv = lbs[ci];
        float4 sv = make_float4(xv.x * lwv + lbv, xv.y * lwv + lbv,
                                xv.z * lwv + lbv, xv.w * lwv + lbv);
        float4 w0 = *(const float4*)(&ws[ci][cog * 16]);
        float4 w1 = *(const float4*)(&ws[ci][cog * 16 + 4]);
        float4 w2 = *(const float4*)(&ws[ci][cog * 16 + 8]);
        float4 w3 = *(const float4*)(&ws[ci][cog * 16 + 12]);
        float wr[16] = {w0.x, w0.y, w0.z, w0.w, w1.x, w1.y, w1.z, w1.w,
                        w2.x, w2.y, w2.z, w2.w, w3.x, w3.y, w3.z, w3.w};
#pragma unroll
        for (int j = 0; j < 16; ++j) {
            float w = wr[j];
            acc[j].x += sv.x * w; acc[j].y += sv.y * w;
            acc[j].z += sv.z * w; acc[j].w += sv.w * w;
        }
    }
    float* d = dst + (size_t)p * 262144 + (size_t)(cog * 16) * 4096 + tile * 256 + xy4 * 4;
#pragma unroll
    for (int j = 0; j < 16; ++j)
        *(float4*)(d + (size_t)j * 4096) = acc[j];
}

// ---------------- fused proj1+gelu+proj2 + weighted accumulate ----------------
__global__ __launch_bounds__(256) void projfused_kernel(
    const float* __restrict__ src, const float* __restrict__ p1w,
    const float* __restrict__ p1b, const float* __restrict__ p2w,
    const float* __restrict__ p2b, const int* __restrict__ pair_b,
    const int* __restrict__ pair_e, const float* __restrict__ pw,
    float* __restrict__ out)
{
    __shared__ float ws[64][68];
    __shared__ float bs[64];
    __shared__ float w2s[64];
    __shared__ float4 red[4][64];
    int p = blockIdx.x, tile = blockIdx.y, t = threadIdx.x;
    int e = pair_e[p];
    const float* W = p1w + (size_t)e * 4096;
    for (int i = t; i < 1024; i += 256) {
        float4 v = LD4(W + i * 4);
        int ci = (i * 4) >> 6, co = (i * 4) & 63;
        *(float4*)(&ws[ci][co]) = v;
    }
    if (t < 64) { bs[t] = p1b[e * 64 + t]; w2s[t] = p2w[e * 64 + t]; }
    __syncthreads();

    int xy4 = t & 63, cog = t >> 6;
    const float* sb = src + (size_t)p * 262144 + tile * 256 + xy4 * 4;
    float4 acc[16];
#pragma unroll
    for (int j = 0; j < 16; ++j) {
        float bv = bs[cog * 16 + j];
        acc[j] = make_float4(bv, bv, bv, bv);
    }
    for (int ci = 0; ci < 64; ++ci) {
        float4 sv = LD4(sb + (size_t)ci * 4096);
        float4 w0 = *(const float4*)(&ws[ci][cog * 16]);
        float4 w1 = *(const float4*)(&ws[ci][cog * 16 + 4]);
        float4 w2 = *(const float4*)(&ws[ci][cog * 16 + 8]);
        float4 w3 = *(const float4*)(&ws[ci][cog * 16 + 12]);
        float wr[16] = {w0.x, w0.y, w0.z, w0.w, w1.x, w1.y, w1.z, w1.w,
                        w2.x, w2.y, w2.z, w2.w, w3.x, w3.y, w3.z, w3.w};
#pragma unroll
        for (int j = 0; j < 16; ++j) {
            float w = wr[j];
            acc[j].x += sv.x * w; acc[j].y += sv.y * w;
            acc[j].z += sv.z * w; acc[j].w += sv.w * w;
        }
    }
    float4 part = make_float4(0.f, 0.f, 0.f, 0.f);
#pragma unroll
    for (int j = 0; j < 16; ++j) {
        float w = w2s[cog * 16 + j];
        part.x += gelu_f(acc[j].x) * w;
        part.y += gelu_f(acc[j].y) * w;
        part.z += gelu_f(acc[j].z) * w;
        part.w += gelu_f(acc[j].w) * w;
    }
    red[cog][xy4] = part;
    __syncthreads();
    if (t < 64) {
        float4 s0 = red[0][t], s1 = red[1][t], s2 = red[2][t], s3 = red[3][t];
        float wgt = pw[p];
        float b2 = p2b[e];
        int b = pair_b[p];
        float* ob = out + (size_t)b * 4096 + tile * 256 + t * 4;
        atomicAdd(ob,     wgt * (s0.x + s1.x + s2.x + s3.x + b2));
        atomicAdd(ob + 1, wgt * (s0.y + s1.y + s2.y + s3.y + b2));
        atomicAdd(ob + 2, wgt * (s0.z + s1.z + s2.z + s3.z + b2));
        atomicAdd(ob + 3, wgt * (s0.w + s1.w + s2.w + s3.w + b2));
    }
}

// ---------------- inverse DFT v3: one (p,co) per block ----------------
__global__ __launch_bounds__(256) void inv_kernel(
    const float* __restrict__ FoA, const float* __restrict__ FoB,
    const float* __restrict__ WY2, const float* __restrict__ TWX,
    float* __restrict__ dst_h, int do_gelu)
{
    __shared__ float wy2[2048];
    __shared__ float twl[128];
    __shared__ float fo_s[1024];
    __shared__ float tT[64][36];
    __shared__ float ot[64][66];
    int t = threadIdx.x;
    for (int i = t; i < 512; i += 256) *(float4*)(&wy2[i * 4]) = *(const float4*)(WY2 + i * 4);
    if (t < 32) *(float4*)(&twl[t * 4]) = LD4(TWX + 128 + t * 4);
    int wid = blockIdx.x;
    int p = wid >> 6, co = wid & 63;
    const float* fA = FoA + (size_t)p * 65536 + (size_t)co * 1024;
    const float* fB = FoB + (size_t)p * 65536 + (size_t)co * 1024;
    {
        float4 a = LD4(fA + t * 4);
        float4 b = LD4(fB + t * 4);
        *(float4*)(&fo_s[t * 4]) = make_float4(a.x + b.x, a.y + b.y, a.z + b.z, a.w + b.w);
    }
    __syncthreads();
    {
        int xx = t & 63, kq = t >> 6;
        float Tr0 = 0.f, Ti0 = 0.f, Tr1 = 0.f, Ti1 = 0.f;
        float Tr2 = 0.f, Ti2 = 0.f, Tr3 = 0.f, Ti3 = 0.f;
#pragma unroll 4
        for (int kxm = 0; kxm < 32; ++kxm) {
            int kx = kxm < 16 ? kxm : kxm + 32;
            int idx = (kx * xx) & 63;
            float c_ = twl[2 * idx], s_ = twl[2 * idx + 1];
            float4 f0 = *(const float4*)(&fo_s[kxm * 32 + kq * 8]);
            float4 f1 = *(const float4*)(&fo_s[kxm * 32 + kq * 8 + 4]);
            Tr0 += f0.x * c_ - f0.y * s_;  Ti0 += f0.x * s_ + f0.y * c_;
            Tr1 += f0.z * c_ - f0.w * s_;  Ti1 += f0.z * s_ + f0.w * c_;
            Tr2 += f1.x * c_ - f1.y * s_;  Ti2 += f1.x * s_ + f1.y * c_;
            Tr3 += f1.z * c_ - f1.w * s_;  Ti3 += f1.z * s_ + f1.w * c_;
        }
        *(float4*)(&tT[xx][kq * 8])     = make_float4(Tr0, Ti0, Tr1, Ti1);
        *(float4*)(&tT[xx][kq * 8 + 4]) = make_float4(Tr2, Ti2, Tr3, Ti3);
    }
    __syncthreads();
    {
        int xx = t & 63, yq = t >> 6;
        float Trr[16], Tii[16];
#pragma unroll
        for (int q = 0; q < 8; ++q) {
            float4 v = *(const float4*)(&tT[xx][q * 4]);
            Trr[q * 2] = v.x; Tii[q * 2] = v.y;
            Trr[q * 2 + 1] = v.z; Tii[q * 2 + 1] = v.w;
        }
        for (int j = 0; j < 16; ++j) {
            int y = yq * 16 + j;
            const float* wr = &wy2[y * 32];
            float acc = 0.f;
#pragma unroll
            for (int k = 0; k < 16; ++k)
                acc += Trr[k] * wr[2 * k] - Tii[k] * wr[2 * k + 1];
            ot[xx][y] = acc;
        }
    }
    __syncthreads();
    {
        float* base = dst_h + (size_t)p * 262144 + (size_t)co * 4096;
        for (int r = 0; r < 16; ++r) {
            int gidx = r * 256 + t;
            int xx = gidx >> 6, y = gidx & 63;
            float v = base[gidx] + ot[xx][y];
            if (do_gelu) v = gelu_f(v);
            base[gidx] = v;
        }
    }
}

// ---------------- launch ----------------
extern "C" void kernel_launch(void* const* d_in, const int* in_sizes, int n_in,
                              void* d_out, int out_size, void* d_ws, size_t ws_size,
                              hipStream_t stream) {
    const float* x    = (const float*)d_in[0];
    const float* encw = (const float*)d_in[1];
    const float* encb = (const float*)d_in[2];
    const float* wqkv = (const float*)d_in[3];
    const float* bqkv = (const float*)d_in[4];
    const float* wo   = (const float*)d_in[5];
    const float* bo   = (const float*)d_in[6];
    const float* ln1g = (const float*)d_in[7];
    const float* ln1b = (const float*)d_in[8];
    const float* fw1  = (const float*)d_in[9];
    const float* fb1  = (const float*)d_in[10];
    const float* fw2  = (const float*)d_in[11];
    const float* fb2  = (const float*)d_in[12];
    const float* ln2g = (const float*)d_in[13];
    const float* ln2b = (const float*)d_in[14];
    const float* fcw  = (const float*)d_in[15];
    const float* fcb  = (const float*)d_in[16];
    const float* lw   = (const float*)d_in[17];
    const float* lb   = (const float*)d_in[18];
    const float* sw1  = (const float*)d_in[19];
    const float* sw2  = (const float*)d_in[20];
    const float* skw  = (const float*)d_in[21];
    const float* skb  = (const float*)d_in[22];
    const float* p1w  = (const float*)d_in[23];
    const float* p1b  = (const float*)d_in[24];
    const float* p2w  = (const float*)d_in[25];
    const float* p2b  = (const float*)d_in[26];
    float* out = (float*)d_out;

    float* wsf    = (float*)d_ws;
    float* rw     = wsf;               // 256
    float* pair_w = wsf + 256;         // 64
    int*   ipart  = (int*)(wsf + 320); // 192 ints
    int* pair_b   = ipart;             // 64
    int* pair_e   = ipart + 64;        // 64
    int* estart   = ipart + 128;       // 9
    int* chunk_e  = ipart + 137;       // 16
    int* chunk_p0 = ipart + 153;       // 16
    int* chunk_np = ipart + 169;       // 16
    float* Wy  = wsf + 512;            // 2048
    float* TWX = wsf + 2560;           // 256 used
    float* WY2 = wsf + 6656;           // 2048
    float* hA  = wsf + 16384;                       // 64 * 262144
    float* hB  = hA + (size_t)64 * 262144;          // 64 * 262144
    float* F   = hB + (size_t)64 * 262144;          // 64 * 65536
    float* FoA = F + (size_t)64 * 65536;            // 64 * 65536
    float* FoB = FoA + (size_t)64 * 65536;          // 64 * 65536
    size_t need = (16384 + 2ull * 64 * 262144 + 64ull * 65536 + 64ull * 131072) * 4;
    if (ws_size < need) return;

    hipMemsetAsync(d_out, 0, (size_t)out_size * sizeof(float), stream);
    init_tables_kernel<<<1, 256, 0, stream>>>(Wy, TWX, WY2);
    router_kernel<<<32, 512, 0, stream>>>(x, encw, encb, wqkv, bqkv, wo, bo, ln1g, ln1b,
                                          fw1, fb1, fw2, fb2, ln2g, ln2b, fcw, fcb, rw);
    build_pairs_kernel<<<1, 64, 0, stream>>>(rw, pair_b, pair_e, pair_w, estart,
                                             chunk_e, chunk_p0, chunk_np);
    for (int l = 0; l < 4; ++l) {
        float* cur = (l & 1) ? hB : hA;   // valid for l>=1
        float* nxt = (l & 1) ? hA : hB;
        if (l == 0) {
            fwdft_x_kernel<<<4096, 256, 0, stream>>>(x, lw, lb, pair_b, pair_e, Wy, TWX, F);
        } else {
            fwdft_kernel<<<4096, 256, 0, stream>>>(cur, Wy, TWX, F);
        }
        spectral_kernel<<<dim3(16, 16, 8), 256, 0, stream>>>(F, FoA, FoB, sw1, sw2,
                                                             chunk_e, chunk_p0, chunk_np, l);
        if (l == 0) {
            conv1x1_x_kernel<<<dim3(64, 16), 256, 0, stream>>>(x, nxt, skw, skb,
                                                               lw, lb, pair_b, pair_e);
        } else {
            conv1x1_kernel<<<dim3(64, 16), 256, 0, stream>>>(cur, nxt, skw, skb, pair_e, 4, l, 0);
        }
        inv_kernel<<<4096, 256, 0, stream>>>(FoA, FoB, WY2, TWX, nxt, (l < 3) ? 1 : 0);
    }
    projfused_kernel<<<dim3(64, 16), 256, 0, stream>>>(hA, p1w, p1b, p2w, p2b,
                                                       pair_b, pair_e, pair_w, out);
}

// Round 18
// 1247.436 us; speedup vs baseline: 9.1099x; 1.0423x over previous
//
#include <hip/hip_runtime.h>
#include <math.h>

#define TWOPI_F 6.283185307179586f
#define LD4(p) (*(const float4*)(p))

__device__ __forceinline__ float gelu_f(float v) {
    float u = 0.7978845608028654f * (v + 0.044715f * v * v * v);
    return 0.5f * v * (1.f + tanhf(u));
}

// ---------------- twiddle tables ----------------
__global__ void init_tables_kernel(float* __restrict__ Wy, float* __restrict__ TWX,
                                   float* __restrict__ WY2) {
    int t = threadIdx.x;
    for (int i = t; i < 1024; i += 256) {
        int y = i >> 4, k = i & 15;
        int m = (k * y) & 63;
        float a = -TWOPI_F * (float)m / 64.f;
        Wy[y * 32 + 2 * k]     = cosf(a);
        Wy[y * 32 + 2 * k + 1] = sinf(a);
    }
    if (t < 64) {
        float a = -TWOPI_F * (float)t / 64.f;
        TWX[2 * t]           = cosf(a);
        TWX[2 * t + 1]       = sinf(a);
        TWX[128 + 2 * t]     = cosf(a);
        TWX[128 + 2 * t + 1] = -sinf(a);
    }
    for (int i = t; i < 1024; i += 256) {
        int y = i >> 4, k = i & 15;
        int m = (k * y) & 63;
        float a = TWOPI_F * (float)m / 64.f;
        float sc = (k == 0 ? 1.f : 2.f) / 4096.f;
        WY2[y * 32 + 2 * k]     = sc * cosf(a);
        WY2[y * 32 + 2 * k + 1] = sc * sinf(a);
    }
}

// ---------------- router v4: all-heads-parallel attention ----------------
__global__ __launch_bounds__(512) void router_kernel(
    const float* __restrict__ x, const float* __restrict__ enc_w, const float* __restrict__ enc_b,
    const float* __restrict__ wqkv, const float* __restrict__ bqkv,
    const float* __restrict__ wo, const float* __restrict__ bo,
    const float* __restrict__ ln1g, const float* __restrict__ ln1b,
    const float* __restrict__ w1, const float* __restrict__ b1,
    const float* __restrict__ w2, const float* __restrict__ b2,
    const float* __restrict__ ln2g, const float* __restrict__ ln2b,
    const float* __restrict__ fcw, const float* __restrict__ fcb,
    float* __restrict__ rw)
{
    __shared__ float s[64][65];
    __shared__ float qk[64][193];
    __shared__ float scH[4][64][65];
    __shared__ float o64[64][65];
    __shared__ float feat[64];
    __shared__ float logits[8];
    int b = blockIdx.x, t = threadIdx.x;

    for (int i = t; i < 4096; i += 512) {
        int w_ = i >> 6, d = i & 63;
        s[w_][d] = x[b * 4096 + w_] * enc_w[d] + enc_b[d];
    }
    __syncthreads();

    for (int l = 0; l < 2; ++l) {
        {
            const float* Wq = wqkv + l * 64 * 192;
            const float* Bq = bqkv + l * 192;
            int c4 = t % 48, rg = t / 48;
            if (rg < 8) {
                const float* wcol = Wq + 4 * c4;
                float4 bq = LD4(Bq + 4 * c4);
                float4 acc[8];
#pragma unroll
                for (int i = 0; i < 8; ++i) acc[i] = bq;
                int r0 = rg * 8;
#pragma unroll 8
                for (int k = 0; k < 64; ++k) {
                    float4 wv = LD4(wcol + k * 192);
#pragma unroll
                    for (int i = 0; i < 8; ++i) {
                        float sv = s[r0 + i][k];
                        acc[i].x += sv * wv.x; acc[i].y += sv * wv.y;
                        acc[i].z += sv * wv.z; acc[i].w += sv * wv.w;
                    }
                }
#pragma unroll
                for (int i = 0; i < 8; ++i) {
                    qk[r0 + i][4 * c4]     = acc[i].x;
                    qk[r0 + i][4 * c4 + 1] = acc[i].y;
                    qk[r0 + i][4 * c4 + 2] = acc[i].z;
                    qk[r0 + i][4 * c4 + 3] = acc[i].w;
                }
            }
        }
        __syncthreads();
        for (int i = t; i < 16384; i += 512) {
            int h = i >> 12, q = (i >> 6) & 63, kj = i & 63;
            float acc = 0.f;
#pragma unroll
            for (int d = 0; d < 16; ++d)
                acc += qk[q][h * 16 + d] * qk[kj][64 + h * 16 + d];
            scH[h][q][kj] = acc * 0.25f;
        }
        __syncthreads();
        if (t < 256) {
            int h = t >> 6, q = t & 63;
            float* row = scH[h][q];
            float m = -1e30f;
            for (int j = 0; j < 64; ++j) m = fmaxf(m, row[j]);
            float sum = 0.f;
            for (int j = 0; j < 64; ++j) { float e2 = expf(row[j] - m); row[j] = e2; sum += e2; }
            float inv = 1.f / sum;
            for (int j = 0; j < 64; ++j) row[j] *= inv;
        }
        __syncthreads();
        for (int i = t; i < 4096; i += 512) {
            int q = i >> 6, d = i & 63, h = d >> 4;
            float acc = 0.f;
#pragma unroll 8
            for (int j = 0; j < 64; ++j) acc += scH[h][q][j] * qk[j][128 + d];
            o64[q][d] = acc;
        }
        __syncthreads();
        {
            const float* Wo = wo + l * 4096;
            const float* Bo = bo + l * 64;
            int c4 = t & 15, rg = t >> 4;
            const float* wcol = Wo + 4 * c4;
            float4 acc0 = LD4(Bo + 4 * c4), acc1 = acc0;
            int r0 = rg * 2;
#pragma unroll 8
            for (int k = 0; k < 64; ++k) {
                float4 wv = LD4(wcol + k * 64);
                float h0 = o64[r0][k], h1 = o64[r0 + 1][k];
                acc0.x += h0 * wv.x; acc0.y += h0 * wv.y;
                acc0.z += h0 * wv.z; acc0.w += h0 * wv.w;
                acc1.x += h1 * wv.x; acc1.y += h1 * wv.y;
                acc1.z += h1 * wv.z; acc1.w += h1 * wv.w;
            }
            scH[0][r0][4 * c4]     = s[r0][4 * c4]     + acc0.x;
            scH[0][r0][4 * c4 + 1] = s[r0][4 * c4 + 1] + acc0.y;
            scH[0][r0][4 * c4 + 2] = s[r0][4 * c4 + 2] + acc0.z;
            scH[0][r0][4 * c4 + 3] = s[r0][4 * c4 + 3] + acc0.w;
            scH[0][r0 + 1][4 * c4]     = s[r0 + 1][4 * c4]     + acc1.x;
            scH[0][r0 + 1][4 * c4 + 1] = s[r0 + 1][4 * c4 + 1] + acc1.y;
            scH[0][r0 + 1][4 * c4 + 2] = s[r0 + 1][4 * c4 + 2] + acc1.z;
            scH[0][r0 + 1][4 * c4 + 3] = s[r0 + 1][4 * c4 + 3] + acc1.w;
        }
        __syncthreads();
        if (t < 64) {
            float m = 0.f;
            for (int j = 0; j < 64; ++j) m += scH[0][t][j];
            m *= (1.f / 64.f);
            float v = 0.f;
            for (int j = 0; j < 64; ++j) { float d = scH[0][t][j] - m; v += d * d; }
            v *= (1.f / 64.f);
            float inv = rsqrtf(v + 1e-5f);
            for (int j = 0; j < 64; ++j)
                s[t][j] = (scH[0][t][j] - m) * inv * ln1g[l * 64 + j] + ln1b[l * 64 + j];
        }
        __syncthreads();
        {
            const float* W1 = w1 + l * 64 * 256;
            const float* B1 = b1 + l * 256;
            int c4 = t & 63, rg = t >> 6;
            const float* wcol = W1 + 4 * c4;
            float4 b1v = LD4(B1 + 4 * c4);
            float4 acc[8];
#pragma unroll
            for (int i = 0; i < 8; ++i) acc[i] = b1v;
            int r0 = rg * 8;
#pragma unroll 4
            for (int k = 0; k < 64; ++k) {
                float4 wv = LD4(wcol + k * 256);
#pragma unroll
                for (int i = 0; i < 8; ++i) {
                    float sv = s[r0 + i][k];
                    acc[i].x += sv * wv.x; acc[i].y += sv * wv.y;
                    acc[i].z += sv * wv.z; acc[i].w += sv * wv.w;
                }
            }
#pragma unroll
            for (int i = 0; i < 8; ++i) {
                float a0 = fmaxf(acc[i].x, 0.f), a1 = fmaxf(acc[i].y, 0.f);
                float a2 = fmaxf(acc[i].z, 0.f), a3 = fmaxf(acc[i].w, 0.f);
                if (c4 < 48) {
                    qk[r0 + i][4 * c4] = a0; qk[r0 + i][4 * c4 + 1] = a1;
                    qk[r0 + i][4 * c4 + 2] = a2; qk[r0 + i][4 * c4 + 3] = a3;
                } else {
                    int c = 4 * c4 - 192;
                    o64[r0 + i][c] = a0; o64[r0 + i][c + 1] = a1;
                    o64[r0 + i][c + 2] = a2; o64[r0 + i][c + 3] = a3;
                }
            }
        }
        __syncthreads();
        {
            const float* W2 = w2 + l * 256 * 64;
            const float* B2 = b2 + l * 64;
            int c4 = t & 15, rg = t >> 4;
            const float* wcol = W2 + 4 * c4;
            float4 acc0 = LD4(B2 + 4 * c4), acc1 = acc0;
            int r0 = rg * 2;
#pragma unroll 8
            for (int k = 0; k < 192; ++k) {
                float4 wv = LD4(wcol + k * 64);
                float h0 = qk[r0][k], h1 = qk[r0 + 1][k];
                acc0.x += h0 * wv.x; acc0.y += h0 * wv.y;
                acc0.z += h0 * wv.z; acc0.w += h0 * wv.w;
                acc1.x += h1 * wv.x; acc1.y += h1 * wv.y;
                acc1.z += h1 * wv.z; acc1.w += h1 * wv.w;
            }
#pragma unroll 8
            for (int k = 192; k < 256; ++k) {
                float4 wv = LD4(wcol + k * 64);
                float h0 = o64[r0][k - 192], h1 = o64[r0 + 1][k - 192];
                acc0.x += h0 * wv.x; acc0.y += h0 * wv.y;
                acc0.z += h0 * wv.z; acc0.w += h0 * wv.w;
                acc1.x += h1 * wv.x; acc1.y += h1 * wv.y;
                acc1.z += h1 * wv.z; acc1.w += h1 * wv.w;
            }
            scH[0][r0][4 * c4]     = s[r0][4 * c4]     + acc0.x;
            scH[0][r0][4 * c4 + 1] = s[r0][4 * c4 + 1] + acc0.y;
            scH[0][r0][4 * c4 + 2] = s[r0][4 * c4 + 2] + acc0.z;
            scH[0][r0][4 * c4 + 3] = s[r0][4 * c4 + 3] + acc0.w;
            scH[0][r0 + 1][4 * c4]     = s[r0 + 1][4 * c4]     + acc1.x;
            scH[0][r0 + 1][4 * c4 + 1] = s[r0 + 1][4 * c4 + 1] + acc1.y;
            scH[0][r0 + 1][4 * c4 + 2] = s[r0 + 1][4 * c4 + 2] + acc1.z;
            scH[0][r0 + 1][4 * c4 + 3] = s[r0 + 1][4 * c4 + 3] + acc1.w;
        }
        __syncthreads();
        if (t < 64) {
            float m = 0.f;
            for (int j = 0; j < 64; ++j) m += scH[0][t][j];
            m *= (1.f / 64.f);
            float v = 0.f;
            for (int j = 0; j < 64; ++j) { float d = scH[0][t][j] - m; v += d * d; }
            v *= (1.f / 64.f);
            float inv = rsqrtf(v + 1e-5f);
            for (int j = 0; j < 64; ++j)
                s[t][j] = (scH[0][t][j] - m) * inv * ln2g[l * 64 + j] + ln2b[l * 64 + j];
        }
        __syncthreads();
    }
    if (t < 64) {
        float m = -1e30f;
        for (int r = 0; r < 64; ++r) m = fmaxf(m, s[r][t]);
        feat[t] = m;
    }
    __syncthreads();
    if (t < 8) {
        float acc = fcb[t];
        for (int k = 0; k < 64; ++k) acc += feat[k] * fcw[k * 8 + t];
        logits[t] = acc;
    }
    __syncthreads();
    if (t == 0) {
        int i0 = 0;
        for (int j = 1; j < 8; ++j) if (logits[j] > logits[i0]) i0 = j;
        int i1 = -1;
        for (int j = 0; j < 8; ++j) {
            if (j == i0) continue;
            if (i1 < 0 || logits[j] > logits[i1]) i1 = j;
        }
        float e1 = expf(logits[i1] - logits[i0]);
        float w0 = 1.f / (1.f + e1);
        float w1v = e1 / (1.f + e1);
        for (int j = 0; j < 8; ++j) rw[b * 8 + j] = 0.f;
        rw[b * 8 + i0] = w0;
        rw[b * 8 + i1] = w1v;
    }
}

// ---------------- build pairs + balanced chunk table ----------------
__global__ void build_pairs_kernel(const float* __restrict__ rw, int* __restrict__ pair_b,
                                   int* __restrict__ pair_e, float* __restrict__ pair_w,
                                   int* __restrict__ estart, int* __restrict__ chunk_e,
                                   int* __restrict__ chunk_p0, int* __restrict__ chunk_np) {
    __shared__ float r[256];
    __shared__ int cnt[8], off[9];
    int t = threadIdx.x;
    for (int i = t; i < 256; i += 64) r[i] = rw[i];
    if (t < 64) { pair_b[t] = 0; pair_e[t] = 0; pair_w[t] = 0.f; }
    __syncthreads();
    if (t < 8) {
        int c = 0;
        for (int b = 0; b < 32; ++b) if (r[b * 8 + t] != 0.f) ++c;
        cnt[t] = c;
    }
    __syncthreads();
    if (t == 0) {
        int a = 0;
        for (int e = 0; e < 8; ++e) { off[e] = a; a += cnt[e]; }
        off[8] = a;
        for (int e = 0; e <= 8; ++e) estart[e] = off[e];
        int nc = 0;
        for (int e = 0; e < 8; ++e) {
            for (int s = off[e]; s < off[e + 1]; s += 8) {
                int np = off[e + 1] - s; if (np > 8) np = 8;
                chunk_e[nc] = e; chunk_p0[nc] = s; chunk_np[nc] = np; ++nc;
            }
        }
        for (int c = nc; c < 16; ++c) { chunk_e[c] = 0; chunk_p0[c] = 0; chunk_np[c] = 0; }
    }
    __syncthreads();
    if (t < 8) {
        int n = off[t];
        for (int b = 0; b < 32; ++b) {
            float w = r[b * 8 + t];
            if (w != 0.f) { pair_b[n] = b; pair_e[n] = t; pair_w[n] = w; ++n; }
        }
    }
}

// ---------------- merged fwdft + skip-conv (generic, l>=1) ----------------
// grid 5120: blocks [0,4096) = fwdft of (p,ci); [4096,5120) = conv1x1 (p, tile).
// Roles are independent: both read h; fwdft writes F, conv writes dst.
__global__ __launch_bounds__(256) void fwdft_conv_kernel(
    const float* __restrict__ h, const float* __restrict__ Wy,
    const float* __restrict__ TWX, float* __restrict__ F,
    float* __restrict__ dst, const float* __restrict__ skw,
    const float* __restrict__ skb, const int* __restrict__ pair_e, int l)
{
    __shared__ __align__(16) char smem[35328];
    int t = threadIdx.x;
    if (blockIdx.x < 4096) {
        // ---- fwdft role ----
        float (*ht)[68] = (float(*)[68])(smem);            // 17408 B
        float (*gt)[36] = (float(*)[36])(smem + 17408);    //  9216 B
        float* wy   = (float*)(smem + 26624);              //  8192 B
        float* tw64 = (float*)(smem + 34816);              //   512 B
        int bid = blockIdx.x;
        const float* src = h + (size_t)bid * 4096;
        for (int i = t; i < 1024; i += 256) {
            float4 v = LD4(src + i * 4);
            int xx = (i * 4) >> 6, y = (i * 4) & 63;
            *(float4*)(&ht[xx][y]) = v;
        }
        for (int i = t; i < 512; i += 256) *(float4*)(&wy[i * 4]) = LD4(Wy + i * 4);
        if (t < 32) *(float4*)(&tw64[t * 4]) = LD4(TWX + t * 4);
        __syncthreads();
        {
            int xx = t >> 2, kq = t & 3;
            float gr0 = 0.f, gi0 = 0.f, gr1 = 0.f, gi1 = 0.f;
            float gr2 = 0.f, gi2 = 0.f, gr3 = 0.f, gi3 = 0.f;
#pragma unroll 4
            for (int y = 0; y < 64; ++y) {
                float hv = ht[xx][y];
                float4 w0 = *(const float4*)(&wy[y * 32 + kq * 8]);
                float4 w1 = *(const float4*)(&wy[y * 32 + kq * 8 + 4]);
                gr0 += hv * w0.x; gi0 += hv * w0.y;
                gr1 += hv * w0.z; gi1 += hv * w0.w;
                gr2 += hv * w1.x; gi2 += hv * w1.y;
                gr3 += hv * w1.z; gi3 += hv * w1.w;
            }
            *(float4*)(&gt[xx][kq * 8])     = make_float4(gr0, gi0, gr1, gi1);
            *(float4*)(&gt[xx][kq * 8 + 4]) = make_float4(gr2, gi2, gr3, gi3);
        }
        __syncthreads();
        {
            int kxm = t & 31, kyq = t >> 5;
            int kx = kxm < 16 ? kxm : kxm + 32;
            float ar0 = 0.f, ai0 = 0.f, ar1 = 0.f, ai1 = 0.f;
            int idx = 0;
#pragma unroll 4
            for (int xx = 0; xx < 64; ++xx) {
                float c_ = tw64[2 * idx], s_ = tw64[2 * idx + 1];
                float4 g = *(const float4*)(&gt[xx][kyq * 4]);
                ar0 += g.x * c_ - g.y * s_;  ai0 += g.x * s_ + g.y * c_;
                ar1 += g.z * c_ - g.w * s_;  ai1 += g.z * s_ + g.w * c_;
                idx = (idx + kx) & 63;
            }
            float* fb = F + (size_t)bid * 1024 + kxm * 32 + kyq * 4;
            *(float4*)(fb) = make_float4(ar0, ai0, ar1, ai1);
        }
    } else {
        // ---- conv1x1 role ----
        float (*ws)[68] = (float(*)[68])(smem);            // 17408 B
        float* bs = (float*)(smem + 17408);                //   256 B
        int idx = blockIdx.x - 4096;
        int p = idx >> 4, tile = idx & 15;
        int e = pair_e[p];
        int widx = e * 4 + l;
        const float* W = skw + (size_t)widx * 4096;
        for (int i = t; i < 1024; i += 256) {
            float4 v = LD4(W + i * 4);
            int ci = (i * 4) >> 6, co = (i * 4) & 63;
            *(float4*)(&ws[ci][co]) = v;
        }
        if (t < 64) bs[t] = skb[widx * 64 + t];
        __syncthreads();

        int xy4 = t & 63, cog = t >> 6;
        const float* sb = h + (size_t)p * 262144 + tile * 256 + xy4 * 4;
        float4 acc[16];
#pragma unroll
        for (int j = 0; j < 16; ++j) {
            float bv = bs[cog * 16 + j];
            acc[j] = make_float4(bv, bv, bv, bv);
        }
        for (int ci = 0; ci < 64; ++ci) {
            float4 sv = LD4(sb + (size_t)ci * 4096);
            float4 w0 = *(const float4*)(&ws[ci][cog * 16]);
            float4 w1 = *(const float4*)(&ws[ci][cog * 16 + 4]);
            float4 w2 = *(const float4*)(&ws[ci][cog * 16 + 8]);
            float4 w3 = *(const float4*)(&ws[ci][cog * 16 + 12]);
            float wr[16] = {w0.x, w0.y, w0.z, w0.w, w1.x, w1.y, w1.z, w1.w,
                            w2.x, w2.y, w2.z, w2.w, w3.x, w3.y, w3.z, w3.w};
#pragma unroll
            for (int j = 0; j < 16; ++j) {
                float w = wr[j];
                acc[j].x += sv.x * w; acc[j].y += sv.y * w;
                acc[j].z += sv.z * w; acc[j].w += sv.w * w;
            }
        }
        float* d = dst + (size_t)p * 262144 + (size_t)(cog * 16) * 4096 + tile * 256 + xy4 * 4;
#pragma unroll
        for (int j = 0; j < 16; ++j)
            *(float4*)(d + (size_t)j * 4096) = acc[j];
    }
}

// ---------------- merged fwdft_x + conv_x (l=0, lift fused from x) ----------------
__global__ __launch_bounds__(256) void fwdftx_convx_kernel(
    const float* __restrict__ x, const float* __restrict__ lw,
    const float* __restrict__ lb, const int* __restrict__ pair_b,
    const int* __restrict__ pair_e, const float* __restrict__ Wy,
    const float* __restrict__ TWX, float* __restrict__ F,
    float* __restrict__ dst, const float* __restrict__ skw,
    const float* __restrict__ skb)
{
    __shared__ __align__(16) char smem[35328];
    int t = threadIdx.x;
    if (blockIdx.x < 4096) {
        float (*ht)[68] = (float(*)[68])(smem);
        float (*gt)[36] = (float(*)[36])(smem + 17408);
        float* wy   = (float*)(smem + 26624);
        float* tw64 = (float*)(smem + 34816);
        int bid = blockIdx.x;
        int p = bid >> 6, ci = bid & 63;
        int e = pair_e[p], b = pair_b[p];
        float lwv = lw[e * 64 + ci];
        float lbv = lb[e * 64 + ci];
        const float* src = x + (size_t)b * 4096;
        for (int i = t; i < 1024; i += 256) {
            float4 v = LD4(src + i * 4);
            v.x = v.x * lwv + lbv; v.y = v.y * lwv + lbv;
            v.z = v.z * lwv + lbv; v.w = v.w * lwv + lbv;
            int xx = (i * 4) >> 6, y = (i * 4) & 63;
            *(float4*)(&ht[xx][y]) = v;
        }
        for (int i = t; i < 512; i += 256) *(float4*)(&wy[i * 4]) = LD4(Wy + i * 4);
        if (t < 32) *(float4*)(&tw64[t * 4]) = LD4(TWX + t * 4);
        __syncthreads();
        {
            int xx = t >> 2, kq = t & 3;
            float gr0 = 0.f, gi0 = 0.f, gr1 = 0.f, gi1 = 0.f;
            float gr2 = 0.f, gi2 = 0.f, gr3 = 0.f, gi3 = 0.f;
#pragma unroll 4
            for (int y = 0; y < 64; ++y) {
                float hv = ht[xx][y];
                float4 w0 = *(const float4*)(&wy[y * 32 + kq * 8]);
                float4 w1 = *(const float4*)(&wy[y * 32 + kq * 8 + 4]);
                gr0 += hv * w0.x; gi0 += hv * w0.y;
                gr1 += hv * w0.z; gi1 += hv * w0.w;
                gr2 += hv * w1.x; gi2 += hv * w1.y;
                gr3 += hv * w1.z; gi3 += hv * w1.w;
            }
            *(float4*)(&gt[xx][kq * 8])     = make_float4(gr0, gi0, gr1, gi1);
            *(float4*)(&gt[xx][kq * 8 + 4]) = make_float4(gr2, gi2, gr3, gi3);
        }
        __syncthreads();
        {
            int kxm = t & 31, kyq = t >> 5;
            int kx = kxm < 16 ? kxm : kxm + 32;
            float ar0 = 0.f, ai0 = 0.f, ar1 = 0.f, ai1 = 0.f;
            int idx = 0;
#pragma unroll 4
            for (int xx = 0; xx < 64; ++xx) {
                float c_ = tw64[2 * idx], s_ = tw64[2 * idx + 1];
                float4 g = *(const float4*)(&gt[xx][kyq * 4]);
                ar0 += g.x * c_ - g.y * s_;  ai0 += g.x * s_ + g.y * c_;
                ar1 += g.z * c_ - g.w * s_;  ai1 += g.z * s_ + g.w * c_;
                idx = (idx + kx) & 63;
            }
            float* fb = F + (size_t)bid * 1024 + kxm * 32 + kyq * 4;
            *(float4*)(fb) = make_float4(ar0, ai0, ar1, ai1);
        }
    } else {
        float (*ws)[68] = (float(*)[68])(smem);
        float* bs  = (float*)(smem + 17408);
        float* lws = (float*)(smem + 17664);
        float* lbs = (float*)(smem + 17920);
        int idx = blockIdx.x - 4096;
        int p = idx >> 4, tile = idx & 15;
        int e = pair_e[p], b = pair_b[p];
        int widx = e * 4;
        const float* W = skw + (size_t)widx * 4096;
        for (int i = t; i < 1024; i += 256) {
            float4 v = LD4(W + i * 4);
            int ci = (i * 4) >> 6, co = (i * 4) & 63;
            *(float4*)(&ws[ci][co]) = v;
        }
        if (t < 64) {
            bs[t]  = skb[widx * 64 + t];
            lws[t] = lw[e * 64 + t];
            lbs[t] = lb[e * 64 + t];
        }
        __syncthreads();

        int xy4 = t & 63, cog = t >> 6;
        float4 xv = LD4(x + (size_t)b * 4096 + tile * 256 + xy4 * 4);
        float4 acc[16];
#pragma unroll
        for (int j = 0; j < 16; ++j) {
            float bv = bs[cog * 16 + j];
            acc[j] = make_float4(bv, bv, bv, bv);
        }
        for (int ci = 0; ci < 64; ++ci) {
            float lwv = lws[ci], lbv = lbs[ci];
            float4 sv = make_float4(xv.x * lwv + lbv, xv.y * lwv + lbv,
                                    xv.z * lwv + lbv, xv.w * lwv + lbv);
            float4 w0 = *(const float4*)(&ws[ci][cog * 16]);
            float4 w1 = *(const float4*)(&ws[ci][cog * 16 + 4]);
            float4 w2 = *(const float4*)(&ws[ci][cog * 16 + 8]);
            float4 w3 = *(const float4*)(&ws[ci][cog * 16 + 12]);
            float wr[16] = {w0.x, w0.y, w0.z, w0.w, w1.x, w1.y, w1.z, w1.w,
                            w2.x, w2.y, w2.z, w2.w, w3.x, w3.y, w3.z, w3.w};
#pragma unroll
            for (int j = 0; j < 16; ++j) {
                float w = wr[j];
                acc[j].x += sv.x * w; acc[j].y += sv.y * w;
                acc[j].z += sv.z * w; acc[j].w += sv.w * w;
            }
        }
        float* d = dst + (size_t)p * 262144 + (size_t)(cog * 16) * 4096 + tile * 256 + xy4 * 4;
#pragma unroll
        for (int j = 0; j < 16; ++j)
            *(float4*)(d + (size_t)j * 4096) = acc[j];
    }
}

// ---------------- spectral v11: chunk-balanced (R14 proven) ----------------
__global__ __launch_bounds__(256) void spectral_kernel(
    const float* __restrict__ F, float* __restrict__ FoA, float* __restrict__ FoB,
    const float* __restrict__ w1, const float* __restrict__ w2,
    const int* __restrict__ chunk_e, const int* __restrict__ chunk_p0,
    const int* __restrict__ chunk_np, int l)
{
    int c = blockIdx.x;
    int np = chunk_np[c];
    if (np == 0) return;
    int e = chunk_e[c], p0 = chunk_p0[c];
    int z = blockIdx.z;
    int wsel = z & 1, cih = (z >> 1) & 1, mq = z >> 2;
    int t = threadIdx.x;
    int co = blockIdx.y * 4 + (t >> 6);
    int lane = t & 63;
    int moff = mq * 256 + lane * 4;

    const float* wbase = (wsel == 0 ? w1 : w2) + (size_t)(e * 4 + l) * 2097152;
    const float* Wc  = wbase + (size_t)(cih * 32) * 32768 + (size_t)co * 512 + moff;
    const float* Fc0 = F + (size_t)p0 * 65536 + (size_t)(cih * 32) * 1024 + wsel * 512 + moff;
    float* Fob = (cih ? FoB : FoA) + (size_t)p0 * 65536 + (size_t)co * 1024 + wsel * 512 + moff;

    float4 acc[8];
#pragma unroll
    for (int p = 0; p < 8; ++p) acc[p] = make_float4(0.f, 0.f, 0.f, 0.f);
    const float* Wp = Wc;
    const float* Fp = Fc0;
    for (int ci = 0; ci < 32; ++ci) {
        float4 wv = LD4(Wp);
#pragma unroll
        for (int p = 0; p < 8; ++p) {
            float4 fv = LD4(Fp + (size_t)p * 65536);
            acc[p].x += fv.x * wv.x - fv.y * wv.y;
            acc[p].y += fv.x * wv.y + fv.y * wv.x;
            acc[p].z += fv.z * wv.z - fv.w * wv.w;
            acc[p].w += fv.z * wv.w + fv.w * wv.z;
        }
        Wp += 32768;
        Fp += 1024;
    }
#pragma unroll
    for (int p = 0; p < 8; ++p) {
        if (p < np)
            *(float4*)(Fob + (size_t)p * 65536) = acc[p];
    }
}

// ---------------- fused proj1+gelu+proj2 + weighted accumulate ----------------
__global__ __launch_bounds__(256) void projfused_kernel(
    const float* __restrict__ src, const float* __restrict__ p1w,
    const float* __restrict__ p1b, const float* __restrict__ p2w,
    const float* __restrict__ p2b, const int* __restrict__ pair_b,
    const int* __restrict__ pair_e, const float* __restrict__ pw,
    float* __restrict__ out)
{
    __shared__ float ws[64][68];
    __shared__ float bs[64];
    __shared__ float w2s[64];
    __shared__ float4 red[4][64];
    int p = blockIdx.x, tile = blockIdx.y, t = threadIdx.x;
    int e = pair_e[p];
    const float* W = p1w + (size_t)e * 4096;
    for (int i = t; i < 1024; i += 256) {
        float4 v = LD4(W + i * 4);
        int ci = (i * 4) >> 6, co = (i * 4) & 63;
        *(float4*)(&ws[ci][co]) = v;
    }
    if (t < 64) { bs[t] = p1b[e * 64 + t]; w2s[t] = p2w[e * 64 + t]; }
    __syncthreads();

    int xy4 = t & 63, cog = t >> 6;
    const float* sb = src + (size_t)p * 262144 + tile * 256 + xy4 * 4;
    float4 acc[16];
#pragma unroll
    for (int j = 0; j < 16; ++j) {
        float bv = bs[cog * 16 + j];
        acc[j] = make_float4(bv, bv, bv, bv);
    }
    for (int ci = 0; ci < 64; ++ci) {
        float4 sv = LD4(sb + (size_t)ci * 4096);
        float4 w0 = *(const float4*)(&ws[ci][cog * 16]);
        float4 w1 = *(const float4*)(&ws[ci][cog * 16 + 4]);
        float4 w2 = *(const float4*)(&ws[ci][cog * 16 + 8]);
        float4 w3 = *(const float4*)(&ws[ci][cog * 16 + 12]);
        float wr[16] = {w0.x, w0.y, w0.z, w0.w, w1.x, w1.y, w1.z, w1.w,
                        w2.x, w2.y, w2.z, w2.w, w3.x, w3.y, w3.z, w3.w};
#pragma unroll
        for (int j = 0; j < 16; ++j) {
            float w = wr[j];
            acc[j].x += sv.x * w; acc[j].y += sv.y * w;
            acc[j].z += sv.z * w; acc[j].w += sv.w * w;
        }
    }
    float4 part = make_float4(0.f, 0.f, 0.f, 0.f);
#pragma unroll
    for (int j = 0; j < 16; ++j) {
        float w = w2s[cog * 16 + j];
        part.x += gelu_f(acc[j].x) * w;
        part.y += gelu_f(acc[j].y) * w;
        part.z += gelu_f(acc[j].z) * w;
        part.w += gelu_f(acc[j].w) * w;
    }
    red[cog][xy4] = part;
    __syncthreads();
    if (t < 64) {
        float4 s0 = red[0][t], s1 = red[1][t], s2 = red[2][t], s3 = red[3][t];
        float wgt = pw[p];
        float b2 = p2b[e];
        int b = pair_b[p];
        float* ob = out + (size_t)b * 4096 + tile * 256 + t * 4;
        atomicAdd(ob,     wgt * (s0.x + s1.x + s2.x + s3.x + b2));
        atomicAdd(ob + 1, wgt * (s0.y + s1.y + s2.y + s3.y + b2));
        atomicAdd(ob + 2, wgt * (s0.z + s1.z + s2.z + s3.z + b2));
        atomicAdd(ob + 3, wgt * (s0.w + s1.w + s2.w + s3.w + b2));
    }
}

// ---------------- inverse DFT v3: one (p,co) per block ----------------
__global__ __launch_bounds__(256) void inv_kernel(
    const float* __restrict__ FoA, const float* __restrict__ FoB,
    const float* __restrict__ WY2, const float* __restrict__ TWX,
    float* __restrict__ dst_h, int do_gelu)
{
    __shared__ float wy2[2048];
    __shared__ float twl[128];
    __shared__ float fo_s[1024];
    __shared__ float tT[64][36];
    __shared__ float ot[64][66];
    int t = threadIdx.x;
    for (int i = t; i < 512; i += 256) *(float4*)(&wy2[i * 4]) = LD4(WY2 + i * 4);
    if (t < 32) *(float4*)(&twl[t * 4]) = LD4(TWX + 128 + t * 4);
    int wid = blockIdx.x;
    int p = wid >> 6, co = wid & 63;
    const float* fA = FoA + (size_t)p * 65536 + (size_t)co * 1024;
    const float* fB = FoB + (size_t)p * 65536 + (size_t)co * 1024;
    {
        float4 a = LD4(fA + t * 4);
        float4 b = LD4(fB + t * 4);
        *(float4*)(&fo_s[t * 4]) = make_float4(a.x + b.x, a.y + b.y, a.z + b.z, a.w + b.w);
    }
    __syncthreads();
    {
        int xx = t & 63, kq = t >> 6;
        float Tr0 = 0.f, Ti0 = 0.f, Tr1 = 0.f, Ti1 = 0.f;
        float Tr2 = 0.f, Ti2 = 0.f, Tr3 = 0.f, Ti3 = 0.f;
#pragma unroll 4
        for (int kxm = 0; kxm < 32; ++kxm) {
            int kx = kxm < 16 ? kxm : kxm + 32;
            int idx = (kx * xx) & 63;
            float c_ = twl[2 * idx], s_ = twl[2 * idx + 1];
            float4 f0 = *(const float4*)(&fo_s[kxm * 32 + kq * 8]);
            float4 f1 = *(const float4*)(&fo_s[kxm * 32 + kq * 8 + 4]);
            Tr0 += f0.x * c_ - f0.y * s_;  Ti0 += f0.x * s_ + f0.y * c_;
            Tr1 += f0.z * c_ - f0.w * s_;  Ti1 += f0.z * s_ + f0.w * c_;
            Tr2 += f1.x * c_ - f1.y * s_;  Ti2 += f1.x * s_ + f1.y * c_;
            Tr3 += f1.z * c_ - f1.w * s_;  Ti3 += f1.z * s_ + f1.w * c_;
        }
        *(float4*)(&tT[xx][kq * 8])     = make_float4(Tr0, Ti0, Tr1, Ti1);
        *(float4*)(&tT[xx][kq * 8 + 4]) = make_float4(Tr2, Ti2, Tr3, Ti3);
    }
    __syncthreads();
    {
        int xx = t & 63, yq = t >> 6;
        float Trr[16], Tii[16];
#pragma unroll
        for (int q = 0; q < 8; ++q) {
            float4 v = *(const float4*)(&tT[xx][q * 4]);
            Trr[q * 2] = v.x; Tii[q * 2] = v.y;
            Trr[q * 2 + 1] = v.z; Tii[q * 2 + 1] = v.w;
        }
        for (int j = 0; j < 16; ++j) {
            int y = yq * 16 + j;
            const float* wr = &wy2[y * 32];
            float acc = 0.f;
#pragma unroll
            for (int k = 0; k < 16; ++k)
                acc += Trr[k] * wr[2 * k] - Tii[k] * wr[2 * k + 1];
            ot[xx][y] = acc;
        }
    }
    __syncthreads();
    {
        float* base = dst_h + (size_t)p * 262144 + (size_t)co * 4096;
        for (int r = 0; r < 16; ++r) {
            int gidx = r * 256 + t;
            int xx = gidx >> 6, y = gidx & 63;
            float v = base[gidx] + ot[xx][y];
            if (do_gelu) v = gelu_f(v);
            base[gidx] = v;
        }
    }
}

// ---------------- launch ----------------
extern "C" void kernel_launch(void* const* d_in, const int* in_sizes, int n_in,
                              void* d_out, int out_size, void* d_ws, size_t ws_size,
                              hipStream_t stream) {
    const float* x    = (const float*)d_in[0];
    const float* encw = (const float*)d_in[1];
    const float* encb = (const float*)d_in[2];
    const float* wqkv = (const float*)d_in[3];
    const float* bqkv = (const float*)d_in[4];
    const float* wo   = (const float*)d_in[5];
    const float* bo   = (const float*)d_in[6];
    const float* ln1g = (const float*)d_in[7];
    const float* ln1b = (const float*)d_in[8];
    const float* fw1  = (const float*)d_in[9];
    const float* fb1  = (const float*)d_in[10];
    const float* fw2  = (const float*)d_in[11];
    const float* fb2  = (const float*)d_in[12];
    const float* ln2g = (const float*)d_in[13];
    const float* ln2b = (const float*)d_in[14];
    const float* fcw  = (const float*)d_in[15];
    const float* fcb  = (const float*)d_in[16];
    const float* lw   = (const float*)d_in[17];
    const float* lb   = (const float*)d_in[18];
    const float* sw1  = (const float*)d_in[19];
    const float* sw2  = (const float*)d_in[20];
    const float* skw  = (const float*)d_in[21];
    const float* skb  = (const float*)d_in[22];
    const float* p1w  = (const float*)d_in[23];
    const float* p1b  = (const float*)d_in[24];
    const float* p2w  = (const float*)d_in[25];
    const float* p2b  = (const float*)d_in[26];
    float* out = (float*)d_out;

    float* wsf    = (float*)d_ws;
    float* rw     = wsf;               // 256
    float* pair_w = wsf + 256;         // 64
    int*   ipart  = (int*)(wsf + 320); // 192 ints
    int* pair_b   = ipart;             // 64
    int* pair_e   = ipart + 64;        // 64
    int* estart   = ipart + 128;       // 9
    int* chunk_e  = ipart + 137;       // 16
    int* chunk_p0 = ipart + 153;       // 16
    int* chunk_np = ipart + 169;       // 16
    float* Wy  = wsf + 512;            // 2048
    float* TWX = wsf + 2560;           // 256 used
    float* WY2 = wsf + 6656;           // 2048
    float* hA  = wsf + 16384;                       // 64 * 262144
    float* hB  = hA + (size_t)64 * 262144;          // 64 * 262144
    float* F   = hB + (size_t)64 * 262144;          // 64 * 65536
    float* FoA = F + (size_t)64 * 65536;            // 64 * 65536
    float* FoB = FoA + (size_t)64 * 65536;          // 64 * 65536
    size_t need = (16384 + 2ull * 64 * 262144 + 64ull * 65536 + 64ull * 131072) * 4;
    if (ws_size < need) return;

    hipMemsetAsync(d_out, 0, (size_t)out_size * sizeof(float), stream);
    init_tables_kernel<<<1, 256, 0, stream>>>(Wy, TWX, WY2);
    router_kernel<<<32, 512, 0, stream>>>(x, encw, encb, wqkv, bqkv, wo, bo, ln1g, ln1b,
                                          fw1, fb1, fw2, fb2, ln2g, ln2b, fcw, fcb, rw);
    build_pairs_kernel<<<1, 64, 0, stream>>>(rw, pair_b, pair_e, pair_w, estart,
                                             chunk_e, chunk_p0, chunk_np);
    for (int l = 0; l < 4; ++l) {
        float* cur = (l & 1) ? hB : hA;   // valid for l>=1
        float* nxt = (l & 1) ? hA : hB;
        if (l == 0) {
            fwdftx_convx_kernel<<<5120, 256, 0, stream>>>(x, lw, lb, pair_b, pair_e,
                                                          Wy, TWX, F, nxt, skw, skb);
        } else {
            fwdft_conv_kernel<<<5120, 256, 0, stream>>>(cur, Wy, TWX, F, nxt,
                                                        skw, skb, pair_e, l);
        }
        spectral_kernel<<<dim3(16, 16, 8), 256, 0, stream>>>(F, FoA, FoB, sw1, sw2,
                                                             chunk_e, chunk_p0, chunk_np, l);
        inv_kernel<<<4096, 256, 0, stream>>>(FoA, FoB, WY2, TWX, nxt, (l < 3) ? 1 : 0);
    }
    projfused_kernel<<<dim3(64, 16), 256, 0, stream>>>(hA, p1w, p1b, p2w, p2b,
                                                       pair_b, pair_e, pair_w, out);
}